// Round 10
// baseline (369.506 us; speedup 1.0000x reference)
//
#include <hip/hip_runtime.h>
#include <math.h>

#define NHW   9216     // 96*96
#define NROWS 36864    // NHW*4

typedef _Float16 f16;
typedef _Float16 f16x8 __attribute__((ext_vector_type(8)));
typedef float    f32x4 __attribute__((ext_vector_type(4)));

__device__ __forceinline__ float softplusf(float x) {
    return fmaxf(x, 0.f) + log1pf(expf(-fabsf(x)));
}

// ---------------- positional encoding ctx[hw][128] ----------------
__global__ __launch_bounds__(256) void ctx_kernel(float* __restrict__ ctx) {
    int e = blockIdx.x * 256 + threadIdx.x;
    if (e >= NHW * 128) return;
    int c  = e & 127;
    int hw = e >> 7;
    int i = hw / 96, j = hw % 96;
    int pos = (c < 64) ? i : j;
    int cc = c & 63;
    int k = cc >> 1;
    float invf = powf(10000.f, -(float)k / 32.f);
    float v = (float)pos * invf;
    ctx[e] = (cc & 1) ? cosf(v) : sinf(v);
}

// ---------------- spatial_norm -> z[row][16], row = (i*96+j)*4+b ----------------
__global__ __launch_bounds__(256) void snorm_kernel(const float* __restrict__ x,
                                                    float* __restrict__ z) {
    int e = blockIdx.x * 256 + threadIdx.x;
    if (e >= NROWS * 16) return;
    int j = e % 96;
    int i = (e / 96) % 96;
    int s = (e / 9216) % 16;
    int b = e / (9216 * 16);
    float sum = 0.f;
    const float* xb = x + (size_t)((b * 16 + s) * 3) * 192 * 192;
    #pragma unroll
    for (int c = 0; c < 3; ++c) {
        const float* xc = xb + (size_t)c * 192 * 192;
        #pragma unroll
        for (int dh = -1; dh <= 1; ++dh) {
            int hh = 2 * i + dh;
            if (hh < 0 || hh >= 192) continue;
            const float* xr = xc + hh * 192;
            #pragma unroll
            for (int dw = -1; dw <= 1; ++dw) {
                int ww = 2 * j + dw;
                if (ww < 0 || ww >= 192) continue;
                float v = xr[ww];
                sum += v * v;
            }
        }
    }
    int row = (i * 96 + j) * 4 + b;
    z[(size_t)row * 16 + s] = sqrtf(sum);
}

// ---------------- knots helper ----------------
__device__ __forceinline__ void knots8(const float* __restrict__ u, float* c, float* w) {
    float mx = u[0];
    #pragma unroll
    for (int k = 1; k < 8; ++k) mx = fmaxf(mx, u[k]);
    float e[8]; float s = 0.f;
    #pragma unroll
    for (int k = 0; k < 8; ++k) { e[k] = expf(u[k] - mx); s += e[k]; }
    float inv = 1.f / s;
    c[0] = -3.f;
    float cum = 0.f;
    #pragma unroll
    for (int k = 0; k < 8; ++k) {
        float v = 0.001f + 0.992f * e[k] * inv;
        cum += v;
        c[k + 1] = cum * 6.f - 3.f;
    }
    c[8] = 3.f;
    #pragma unroll
    for (int k = 0; k < 8; ++k) w[k] = c[k + 1] - c[k];
}

// ---------------- prep: id-spline knots + fused LU matrix + logq const ----------------
__global__ __launch_bounds__(64) void prep_kernel(const float* __restrict__ sp_uw,
                                                  const float* __restrict__ sp_uh,
                                                  const float* __restrict__ sp_ud,
                                                  const float* __restrict__ lu_lower,
                                                  const float* __restrict__ lu_upper,
                                                  const float* __restrict__ lu_udiag,
                                                  const int*   __restrict__ lu_perm,
                                                  float* __restrict__ idk,
                                                  float* __restrict__ Mlu,
                                                  float* __restrict__ luc) {
    int t = threadIdx.x;
    if (t < 32) {
        int s = t >> 3, dim = t & 7;
        float* o = idk + (s * 8 + dim) * 48;
        float c[9], w[8];
        knots8(sp_uw + s * 64 + dim * 8, c, w);
        #pragma unroll
        for (int k = 0; k < 9; ++k) o[k] = c[k];
        #pragma unroll
        for (int k = 0; k < 8; ++k) o[9 + k] = w[k];
        knots8(sp_uh + s * 64 + dim * 8, c, w);
        #pragma unroll
        for (int k = 0; k < 9; ++k) o[17 + k] = c[k];
        #pragma unroll
        for (int k = 0; k < 8; ++k) o[26 + k] = w[k];
        o[34] = 1.f; o[42] = 1.f;
        #pragma unroll
        for (int k = 0; k < 7; ++k) o[35 + k] = 0.001f + softplusf(sp_ud[s * 56 + dim * 7 + k]);
    }
    {
        int s = t >> 4, d = t & 15;
        const float* L  = lu_lower + s * 256;
        const float* U  = lu_upper + s * 256;
        const float* ud = lu_udiag + s * 16;
        const int*   pm = lu_perm + s * 16;
        for (int c = 0; c < 16; ++c) {
            float m = 0.f;
            if (c > d)       m += U[d * 16 + c];
            else if (c == d) m += softplusf(ud[d]) + 0.001f;
            for (int e = 0; e < d && e <= c; ++e) {
                float u = (c > e) ? U[e * 16 + c] : (softplusf(ud[e]) + 0.001f);
                m += L[d * 16 + e] * u;
            }
            Mlu[s * 256 + d * 16 + pm[c]] = m;
        }
    }
    if (t == 0) {
        float c0 = 0.f;
        for (int k = 0; k < 64; ++k)
            c0 += logf(softplusf(lu_udiag[k]) + 0.001f);
        luc[0] = c0;
    }
}

// ---------------- one-time weight pack kernel ----------------
__global__ __launch_bounds__(256) void pack_kernel(
    const float* __restrict__ sp_bW1, const float* __restrict__ sp_bW2,
    const float* __restrict__ made_bW1, const float* __restrict__ made_bW2,
    const float* __restrict__ sp_Wout, const float* __restrict__ made_Wout,
    const float* __restrict__ sp_Win, const float* __restrict__ made_W0,
    const float* __restrict__ sp_bCW, const float* __restrict__ made_ctxW,
    const float* __restrict__ made_bCW,
    const float* __restrict__ sp_bin, const float* __restrict__ sp_bCb,
    const float* __restrict__ made_ctxb, const float* __restrict__ made_b0,
    const float* __restrict__ made_bCb,
    f16* __restrict__ fW1f, f16* __restrict__ fW2f,
    f16* __restrict__ mW1f, f16* __restrict__ mW2f,
    f16* __restrict__ fWoutf, f16* __restrict__ mWoutf,
    f16* __restrict__ finf, f16* __restrict__ minf,
    f16* __restrict__ cfrag, float* __restrict__ cpb)
{
    int cat = blockIdx.y;
    int e = blockIdx.x * 256 + threadIdx.x;
    switch (cat) {
    case 0: if (e < 8 * 16384) {
        int mtx = e >> 14, f = e & 16383;
        int nt = f >> 11, ks = (f >> 9) & 3, l = (f >> 3) & 63, j = f & 7;
        int n = nt * 16 + (l & 15), k = ks * 32 + ((l >> 4) & 3) * 8 + j;
        fW1f[e] = (f16)sp_bW1[mtx * 16384 + n * 128 + k];
    } break;
    case 1: if (e < 8 * 16384) {
        int mtx = e >> 14, f = e & 16383;
        int nt = f >> 11, ks = (f >> 9) & 3, l = (f >> 3) & 63, j = f & 7;
        int n = nt * 16 + (l & 15), k = ks * 32 + ((l >> 4) & 3) * 8 + j;
        fW2f[e] = (f16)sp_bW2[mtx * 16384 + n * 128 + k];
    } break;
    case 2: if (e < 2 * 16384) {
        int mtx = e >> 14, f = e & 16383;
        int nt = f >> 11, ks = (f >> 9) & 3, l = (f >> 3) & 63, j = f & 7;
        int n = nt * 16 + (l & 15), k = ks * 32 + ((l >> 4) & 3) * 8 + j;
        mW1f[e] = ((n % 15) >= (k % 15)) ? (f16)made_bW1[mtx * 16384 + n * 128 + k] : (f16)0.f;
    } break;
    case 3: if (e < 2 * 16384) {
        int mtx = e >> 14, f = e & 16383;
        int nt = f >> 11, ks = (f >> 9) & 3, l = (f >> 3) & 63, j = f & 7;
        int n = nt * 16 + (l & 15), k = ks * 32 + ((l >> 4) & 3) * 8 + j;
        mW2f[e] = ((n % 15) >= (k % 15)) ? (f16)made_bW2[mtx * 16384 + n * 128 + k] : (f16)0.f;
    } break;
    case 4: if (e < 4 * 24576) {
        int s = e / 24576, f = e % 24576;
        int nt = f >> 11, ks = (f >> 9) & 3, l = (f >> 3) & 63, j = f & 7;
        int n = nt * 16 + (l & 15), k = ks * 32 + ((l >> 4) & 3) * 8 + j;
        fWoutf[e] = (n < 184) ? (f16)sp_Wout[s * 23552 + n * 128 + k] : (f16)0.f;
    } break;
    case 5: if (e < 4096) {
        int f = e;
        int nt = f >> 11, ks = (f >> 9) & 3, l = (f >> 3) & 63, j = f & 7;
        int n = nt * 16 + (l & 15), k = ks * 32 + ((l >> 4) & 3) * 8 + j;
        mWoutf[e] = (((n & 15) > (k % 15)) && n < 32) ? (f16)made_Wout[n * 128 + k] : (f16)0.f;
    } break;
    case 6: if (e < 4 * 4096) {
        int s = e >> 12, f = e & 4095;
        int nt = f >> 9, l = (f >> 3) & 63, j = f & 7;
        int n = nt * 16 + (l & 15), k = ((l >> 4) & 3) * 8 + j;
        finf[e] = (k < 8) ? (f16)sp_Win[s * 17408 + n * 136 + k] : (f16)0.f;
    } break;
    case 7: if (e < 4096) {
        int f = e;
        int nt = f >> 9, l = (f >> 3) & 63, j = f & 7;
        int n = nt * 16 + (l & 15), k = ((l >> 4) & 3) * 8 + j;
        minf[e] = (k < 16 && (n % 15) >= k) ? (f16)made_W0[n * 16 + k] : (f16)0.f;
    } break;
    case 8: if (e < 5 * 49152) {
        int s = e / 49152, f = e % 49152;
        int nt = f >> 11, ks = (f >> 9) & 3, l = (f >> 3) & 63, j = f & 7;
        int n = nt * 16 + (l & 15), k = ks * 32 + ((l >> 4) & 3) * 8 + j;
        float v;
        if (s < 4) {
            if (n < 128)      v = sp_Win[s * 17408 + n * 136 + 8 + k];
            else if (n < 256) v = sp_bCW[(size_t)(s * 2 + 0) * 16384 + (n - 128) * 128 + k];
            else              v = sp_bCW[(size_t)(s * 2 + 1) * 16384 + (n - 256) * 128 + k];
        } else {
            if (n < 128)      v = made_ctxW[n * 128 + k];
            else if (n < 256) v = made_bCW[(n - 128) * 128 + k];
            else              v = made_bCW[16384 + (n - 256) * 128 + k];
        }
        cfrag[e] = (f16)v;
    } break;
    case 9: if (e < 5 * 384) {
        int s = e / 384, n = e % 384;
        float v;
        if (s < 4) {
            if (n < 128)      v = sp_bin[s * 128 + n];
            else if (n < 256) v = sp_bCb[(s * 2 + 0) * 128 + (n - 128)];
            else              v = sp_bCb[(s * 2 + 1) * 128 + (n - 256)];
        } else {
            if (n < 128)      v = made_ctxb[n] + made_b0[n];
            else if (n < 256) v = made_bCb[n - 128];
            else              v = made_bCb[128 + (n - 256)];
        }
        cpb[e] = v;
    } break;
    }
}

// ---------------- ctx-chain MFMA: ctxoutf[s][hw][384] (n>=128 sigmoided), f16 ----------------
__global__ __launch_bounds__(256) void ctx_mfma(
    const float* __restrict__ ctx, const f16* __restrict__ cfrag,
    const float* __restrict__ cpb, f16* __restrict__ ctxoutf)
{
    __shared__ alignas(16) f16 cS[16][136];
    const int tid = threadIdx.x, w = tid >> 6, l = tid & 63;
    const int m0 = blockIdx.x * 16;
    const int s  = blockIdx.y;
    const int lr = l & 15, lq = l >> 4;
    #pragma unroll
    for (int it = 0; it < 2; ++it) {
        int e = tid + it * 256;
        int r = e >> 5, c4 = (e & 31) * 4;
        float4 v = *(const float4*)(ctx + (size_t)(m0 + r) * 128 + c4);
        cS[r][c4 + 0] = (f16)v.x; cS[r][c4 + 1] = (f16)v.y;
        cS[r][c4 + 2] = (f16)v.z; cS[r][c4 + 3] = (f16)v.w;
    }
    __syncthreads();
    const f32x4 vzero = {0.f, 0.f, 0.f, 0.f};
    f32x4 acc[6];
    #pragma unroll
    for (int q = 0; q < 6; ++q) acc[q] = vzero;
    const f16* wb = cfrag + (size_t)s * 49152;
    #pragma unroll
    for (int ks = 0; ks < 4; ++ks) {
        f16x8 a = *(const f16x8*)&cS[lr][ks * 32 + lq * 8];
        #pragma unroll
        for (int q = 0; q < 6; ++q) {
            int g = w * 6 + q;
            f16x8 b = *(const f16x8*)(wb + (size_t)((g * 4 + ks) * 64 + l) * 8);
            acc[q] = __builtin_amdgcn_mfma_f32_16x16x32_f16(a, b, acc[q], 0, 0, 0);
        }
    }
    #pragma unroll
    for (int q = 0; q < 6; ++q) {
        int g = w * 6 + q, n = g * 16 + lr;
        float bias = cpb[s * 384 + n];
        #pragma unroll
        for (int r = 0; r < 4; ++r) {
            float val = acc[q][r] + bias;
            if (n >= 128) val = 1.f / (1.f + expf(-val));
            ctxoutf[(size_t)s * NHW * 384 + (size_t)(m0 + lq * 4 + r) * 384 + n] = (f16)val;
        }
    }
}

// ---------------- tiled f32 GEMM (encoder): C = post(A @ W^T + bias) ----------------
template<int POST>   // 0 store, 2 silu
__global__ __launch_bounds__(256) void gemm_k(
    const float* __restrict__ A, int lda,
    const float* __restrict__ W, int ldw,
    const float* __restrict__ bias,
    float* __restrict__ C, int ldc,
    int M, int N, int K)
{
    __shared__ alignas(16) float As[16][68];
    __shared__ alignas(16) float Ws[16][68];
    const int tid = threadIdx.x;
    const int m0 = blockIdx.x * 64;
    const int n0 = blockIdx.y * 64;
    const int tm = (tid >> 4) << 2;
    const int tn = (tid & 15) << 2;
    const int srow = tid >> 2;
    const int skq  = (tid & 3) << 2;

    float acc[4][4] = {{0.f,0.f,0.f,0.f},{0.f,0.f,0.f,0.f},{0.f,0.f,0.f,0.f},{0.f,0.f,0.f,0.f}};

    for (int k0 = 0; k0 < K; k0 += 16) {
        float4 av = *(const float4*)(A + (size_t)(m0 + srow) * lda + k0 + skq);
        As[skq + 0][srow] = av.x; As[skq + 1][srow] = av.y;
        As[skq + 2][srow] = av.z; As[skq + 3][srow] = av.w;
        int wn = n0 + srow;
        float4 wv = make_float4(0.f, 0.f, 0.f, 0.f);
        if (wn < N) wv = *(const float4*)(W + (size_t)wn * ldw + k0 + skq);
        Ws[skq + 0][srow] = wv.x; Ws[skq + 1][srow] = wv.y;
        Ws[skq + 2][srow] = wv.z; Ws[skq + 3][srow] = wv.w;
        __syncthreads();
        #pragma unroll
        for (int kk = 0; kk < 16; ++kk) {
            float4 a4 = *(const float4*)&As[kk][tm];
            float4 w4 = *(const float4*)&Ws[kk][tn];
            float aa[4] = {a4.x, a4.y, a4.z, a4.w};
            float wwv[4] = {w4.x, w4.y, w4.z, w4.w};
            #pragma unroll
            for (int q = 0; q < 4; ++q)
                #pragma unroll
                for (int r = 0; r < 4; ++r)
                    acc[q][r] = fmaf(aa[q], wwv[r], acc[q][r]);
        }
        __syncthreads();
    }
    #pragma unroll
    for (int q = 0; q < 4; ++q) {
        int m = m0 + tm + q;
        #pragma unroll
        for (int r = 0; r < 4; ++r) {
            int n = n0 + tn + r;
            if (n < N) {
                float val = acc[q][r] + bias[n];
                float* cp = C + (size_t)m * ldc + n;
                if (POST == 0) *cp = val;
                else           *cp = val / (1.f + expf(-val));
            }
        }
    }
}

// ---------------- rational-quadratic spline ----------------
__device__ __forceinline__ void rqs_core(float x, const float* cw, const float* wd,
                                         const float* ch, const float* hg, const float* dd,
                                         float& y, float& ld) {
    bool inside = (x >= -3.f) && (x <= 3.f);
    float xc = fminf(fmaxf(x, -3.f), 3.f);
    float cwk = cw[0], wk = wd[0], chk = ch[0], hk = hg[0], d0 = dd[0], d1 = dd[1];
    #pragma unroll
    for (int k = 1; k < 8; ++k) {
        if (xc >= cw[k]) { cwk = cw[k]; wk = wd[k]; chk = ch[k]; hk = hg[k]; d0 = dd[k]; d1 = dd[k + 1]; }
    }
    float dl = hk / wk;
    float th = (xc - cwk) / wk;
    float t1 = th * (1.f - th);
    float den = dl + (d0 + d1 - 2.f * dl) * t1;
    float yy = chk + hk * (dl * th * th + d0 * t1) / den;
    float om = 1.f - th;
    float dnum = dl * dl * (d1 * th * th + 2.f * dl * t1 + d0 * om * om);
    float lld = logf(dnum) - 2.f * logf(den);
    y  = inside ? yy : x;
    ld = inside ? lld : 0.f;
}

__device__ __forceinline__ void rqs1(float x,
                                     const float* __restrict__ uw,
                                     const float* __restrict__ uh,
                                     const float* __restrict__ ud,
                                     float& y, float& ld) {
    float cw[9], wd[8], ch[9], hg[8], dd[9];
    knots8(uw, cw, wd);
    knots8(uh, ch, hg);
    dd[0] = 1.f; dd[8] = 1.f;
    #pragma unroll
    for (int k = 0; k < 7; ++k) dd[k + 1] = 0.001f + softplusf(ud[k]);
    rqs_core(x, cw, wd, ch, hg, dd, y, ld);
}

__device__ __forceinline__ void rqs1_pre(float x, const float* __restrict__ kn,
                                         float& y, float& ld) {
    float cw[9], wd[8], ch[9], hg[8], dd[9];
    #pragma unroll
    for (int k = 0; k < 9; ++k) cw[k] = kn[k];
    #pragma unroll
    for (int k = 0; k < 8; ++k) wd[k] = kn[9 + k];
    #pragma unroll
    for (int k = 0; k < 9; ++k) ch[k] = kn[17 + k];
    #pragma unroll
    for (int k = 0; k < 8; ++k) hg[k] = kn[26 + k];
    #pragma unroll
    for (int k = 0; k < 9; ++k) dd[k] = kn[34 + k];
    rqs_core(x, cw, wd, ch, hg, dd, y, ld);
}

// ---------------- fully merged two-tile pipeline kernel ----------------
// One block = 32 rows (two 16-row MFMA tiles) through 4x(LU->MLP->spline)+MADE->head.
// Every weight B-fragment load feeds 2 MFMAs (tile A + B): L2 traffic halved,
// 2x independent MFMA chains per phase. Gate/thw loads hoisted to phase start.
__global__ __launch_bounds__(256, 4) void mega_all(
    const float* __restrict__ zg,
    const f16*  __restrict__ ctxoutf,   // [5][9216][384]
    const f16*  __restrict__ finf,      // [4][4096]
    const f16*  __restrict__ minf,      // [4096]
    const f16*  __restrict__ fW1f,      // [4][2][16384]
    const f16*  __restrict__ fW2f,
    const f16*  __restrict__ mW1f,      // [2][16384]
    const f16*  __restrict__ mW2f,
    const f16*  __restrict__ fWoutf,    // [4][24576]
    const f16*  __restrict__ mWoutf,    // [4096]
    const float* __restrict__ sp_bb1,   // [4][2][128]
    const float* __restrict__ sp_bb2,
    const float* __restrict__ made_bb1, // [2][128]
    const float* __restrict__ made_bb2,
    const float* __restrict__ sp_bout,  // [4][184]
    const float* __restrict__ made_bout,// [32]
    const float* __restrict__ Mlu,      // [4][16][16]
    const float* __restrict__ lu_bias,  // [4][16]
    const float* __restrict__ idk,      // [4][8][48]
    const float* __restrict__ luc,      // [1]
    const float* __restrict__ ehw,      // [9216][32]
    float* __restrict__ out)            // [4][9216]
{
    __shared__ alignas(16) f16 tS[2][16][136];
    __shared__ alignas(16) f16 uS[2][16][136];
    __shared__ alignas(16) f16 zS[2][16][32];
    __shared__ alignas(16) f16 pS[2][16][196];
    __shared__ float z2[2][2][16][16];   // [tile][phase][row][dim]
    __shared__ float zF[2][16][16];
    __shared__ float lqS[2][16];
    const int tid = threadIdx.x;
    const int w   = tid >> 6;
    const int l   = tid & 63;
    const int lr  = l & 15;
    const int lqw = l >> 4;
    const int m0  = blockIdx.x * 32;
    const int hwqA = (m0 >> 2) + lqw;
    const int hwqB = hwqA + 4;
    const int nt0 = w * 2;
    const int r2  = tid >> 4, d2 = tid & 15;
    const f32x4 vzero = {0.f, 0.f, 0.f, 0.f};

    #pragma unroll
    for (int t2 = 0; t2 < 2; ++t2)
        z2[t2][0][r2][d2] = zg[(size_t)(m0 + t2 * 16 + r2) * 16 + d2];
    if (tid < 32) lqS[tid >> 4][tid & 15] = luc[0];
    __syncthreads();

    for (int i = 3; i >= 0; --i) {
        const f16* cof = ctxoutf + (size_t)i * NHW * 384;
        const f16* cbA = cof + (size_t)hwqA * 384;
        const f16* cbB = cof + (size_t)hwqB * 384;
        // hoist thw loads (used in P2, issued here)
        f16 thA0 = cbA[(nt0 + 0) * 16 + lr], thA1 = cbA[(nt0 + 1) * 16 + lr];
        f16 thB0 = cbB[(nt0 + 0) * 16 + lr], thB1 = cbB[(nt0 + 1) * 16 + lr];
        // ---- P1: fused-LU matvec + zS staging (both tiles) ----
        {
            const float* Mr = Mlu + i * 256 + d2 * 16;
            float bv = lu_bias[i * 16 + d2];
            #pragma unroll
            for (int t2 = 0; t2 < 2; ++t2) {
                float acc = bv;
                #pragma unroll
                for (int j = 0; j < 16; ++j) acc = fmaf(Mr[j], z2[t2][0][r2][j], acc);
                z2[t2][1][r2][d2] = acc;
                if ((d2 & 1) == 0) zS[t2][r2][d2 >> 1] = (f16)acc;
                if (d2 < 12) { zS[t2][r2][8 + d2] = (f16)0.f; zS[t2][r2][20 + d2] = (f16)0.f; }
            }
        }
        __syncthreads();
        // ---- P2: input MFMA (b shared across tiles) ----
        float tReg[2][2][4];
        {
            f16x8 aA = *(const f16x8*)&zS[0][lr][lqw * 8];
            f16x8 aB = *(const f16x8*)&zS[1][lr][lqw * 8];
            const f16* infp = finf + i * 4096;
            f16x8 b0 = *(const f16x8*)(infp + ((nt0 + 0) * 64 + l) * 8);
            f16x8 b1 = *(const f16x8*)(infp + ((nt0 + 1) * 64 + l) * 8);
            float tA0 = (float)thA0, tA1 = (float)thA1, tB0 = (float)thB0, tB1 = (float)thB1;
            f32x4 cA0 = {tA0, tA0, tA0, tA0}, cA1 = {tA1, tA1, tA1, tA1};
            f32x4 cB0 = {tB0, tB0, tB0, tB0}, cB1 = {tB1, tB1, tB1, tB1};
            cA0 = __builtin_amdgcn_mfma_f32_16x16x32_f16(aA, b0, cA0, 0, 0, 0);
            cB0 = __builtin_amdgcn_mfma_f32_16x16x32_f16(aB, b0, cB0, 0, 0, 0);
            cA1 = __builtin_amdgcn_mfma_f32_16x16x32_f16(aA, b1, cA1, 0, 0, 0);
            cB1 = __builtin_amdgcn_mfma_f32_16x16x32_f16(aB, b1, cB1, 0, 0, 0);
            #pragma unroll
            for (int r = 0; r < 4; ++r) {
                tReg[0][0][r] = cA0[r]; tS[0][lqw * 4 + r][(nt0 + 0) * 16 + lr] = (f16)fmaxf(cA0[r], 0.f);
                tReg[0][1][r] = cA1[r]; tS[0][lqw * 4 + r][(nt0 + 1) * 16 + lr] = (f16)fmaxf(cA1[r], 0.f);
                tReg[1][0][r] = cB0[r]; tS[1][lqw * 4 + r][(nt0 + 0) * 16 + lr] = (f16)fmaxf(cB0[r], 0.f);
                tReg[1][1][r] = cB1[r]; tS[1][lqw * 4 + r][(nt0 + 1) * 16 + lr] = (f16)fmaxf(cB1[r], 0.f);
            }
        }
        __syncthreads();
        // ---- residual blocks ----
        #pragma unroll
        for (int blk = 0; blk < 2; ++blk) {
            // hoist gate loads for this blk
            f16 gA0 = cbA[128 + blk * 128 + (nt0 + 0) * 16 + lr];
            f16 gA1 = cbA[128 + blk * 128 + (nt0 + 1) * 16 + lr];
            f16 gB0 = cbB[128 + blk * 128 + (nt0 + 0) * 16 + lr];
            f16 gB1 = cbB[128 + blk * 128 + (nt0 + 1) * 16 + lr];
            f32x4 acc[2][2];
            acc[0][0] = vzero; acc[0][1] = vzero; acc[1][0] = vzero; acc[1][1] = vzero;
            const f16* w1 = fW1f + (size_t)i * 32768 + (size_t)blk * 16384;
            #pragma unroll
            for (int ks = 0; ks < 4; ++ks) {
                f16x8 aA = *(const f16x8*)&tS[0][lr][ks * 32 + lqw * 8];
                f16x8 aB = *(const f16x8*)&tS[1][lr][ks * 32 + lqw * 8];
                const f16* wb = w1 + (ks * 64 + l) * 8;
                f16x8 b0 = *(const f16x8*)(wb + (nt0 + 0) * 2048);
                f16x8 b1 = *(const f16x8*)(wb + (nt0 + 1) * 2048);
                acc[0][0] = __builtin_amdgcn_mfma_f32_16x16x32_f16(aA, b0, acc[0][0], 0, 0, 0);
                acc[1][0] = __builtin_amdgcn_mfma_f32_16x16x32_f16(aB, b0, acc[1][0], 0, 0, 0);
                acc[0][1] = __builtin_amdgcn_mfma_f32_16x16x32_f16(aA, b1, acc[0][1], 0, 0, 0);
                acc[1][1] = __builtin_amdgcn_mfma_f32_16x16x32_f16(aB, b1, acc[1][1], 0, 0, 0);
            }
            {
                const float* bb1p = sp_bb1 + i * 256 + blk * 128;
                float bi0 = bb1p[(nt0 + 0) * 16 + lr];
                float bi1 = bb1p[(nt0 + 1) * 16 + lr];
                #pragma unroll
                for (int t2 = 0; t2 < 2; ++t2)
                    #pragma unroll
                    for (int r = 0; r < 4; ++r) {
                        uS[t2][lqw * 4 + r][(nt0 + 0) * 16 + lr] = (f16)fmaxf(acc[t2][0][r] + bi0, 0.f);
                        uS[t2][lqw * 4 + r][(nt0 + 1) * 16 + lr] = (f16)fmaxf(acc[t2][1][r] + bi1, 0.f);
                    }
            }
            __syncthreads();
            acc[0][0] = vzero; acc[0][1] = vzero; acc[1][0] = vzero; acc[1][1] = vzero;
            const f16* w2 = fW2f + (size_t)i * 32768 + (size_t)blk * 16384;
            #pragma unroll
            for (int ks = 0; ks < 4; ++ks) {
                f16x8 aA = *(const f16x8*)&uS[0][lr][ks * 32 + lqw * 8];
                f16x8 aB = *(const f16x8*)&uS[1][lr][ks * 32 + lqw * 8];
                const f16* wb = w2 + (ks * 64 + l) * 8;
                f16x8 b0 = *(const f16x8*)(wb + (nt0 + 0) * 2048);
                f16x8 b1 = *(const f16x8*)(wb + (nt0 + 1) * 2048);
                acc[0][0] = __builtin_amdgcn_mfma_f32_16x16x32_f16(aA, b0, acc[0][0], 0, 0, 0);
                acc[1][0] = __builtin_amdgcn_mfma_f32_16x16x32_f16(aB, b0, acc[1][0], 0, 0, 0);
                acc[0][1] = __builtin_amdgcn_mfma_f32_16x16x32_f16(aA, b1, acc[0][1], 0, 0, 0);
                acc[1][1] = __builtin_amdgcn_mfma_f32_16x16x32_f16(aB, b1, acc[1][1], 0, 0, 0);
            }
            {
                const float* bb2p = sp_bb2 + i * 256 + blk * 128;
                float bi0 = bb2p[(nt0 + 0) * 16 + lr];
                float bi1 = bb2p[(nt0 + 1) * 16 + lr];
                float g00 = (float)gA0, g01 = (float)gA1, g10 = (float)gB0, g11 = (float)gB1;
                #pragma unroll
                for (int r = 0; r < 4; ++r) {
                    tReg[0][0][r] += (acc[0][0][r] + bi0) * g00;
                    tReg[0][1][r] += (acc[0][1][r] + bi1) * g01;
                    tReg[1][0][r] += (acc[1][0][r] + bi0) * g10;
                    tReg[1][1][r] += (acc[1][1][r] + bi1) * g11;
                    if (blk == 0) {
                        tS[0][lqw * 4 + r][(nt0 + 0) * 16 + lr] = (f16)fmaxf(tReg[0][0][r], 0.f);
                        tS[0][lqw * 4 + r][(nt0 + 1) * 16 + lr] = (f16)fmaxf(tReg[0][1][r], 0.f);
                        tS[1][lqw * 4 + r][(nt0 + 0) * 16 + lr] = (f16)fmaxf(tReg[1][0][r], 0.f);
                        tS[1][lqw * 4 + r][(nt0 + 1) * 16 + lr] = (f16)fmaxf(tReg[1][1][r], 0.f);
                    } else {
                        tS[0][lqw * 4 + r][(nt0 + 0) * 16 + lr] = (f16)tReg[0][0][r];
                        tS[0][lqw * 4 + r][(nt0 + 1) * 16 + lr] = (f16)tReg[0][1][r];
                        tS[1][lqw * 4 + r][(nt0 + 0) * 16 + lr] = (f16)tReg[1][0][r];
                        tS[1][lqw * 4 + r][(nt0 + 1) * 16 + lr] = (f16)tReg[1][1][r];
                    }
                }
            }
            __syncthreads();
        }
        // ---- Wout -> pS (b shared across tiles) ----
        {
            f32x4 po[2][3];
            #pragma unroll
            for (int t2 = 0; t2 < 2; ++t2)
                #pragma unroll
                for (int q = 0; q < 3; ++q) po[t2][q] = vzero;
            const f16* wo = fWoutf + (size_t)i * 24576;
            #pragma unroll
            for (int ks = 0; ks < 4; ++ks) {
                f16x8 aA = *(const f16x8*)&tS[0][lr][ks * 32 + lqw * 8];
                f16x8 aB = *(const f16x8*)&tS[1][lr][ks * 32 + lqw * 8];
                const f16* wb = wo + (ks * 64 + l) * 8;
                #pragma unroll
                for (int q = 0; q < 3; ++q) {
                    f16x8 b = *(const f16x8*)(wb + (w + q * 4) * 2048);
                    po[0][q] = __builtin_amdgcn_mfma_f32_16x16x32_f16(aA, b, po[0][q], 0, 0, 0);
                    po[1][q] = __builtin_amdgcn_mfma_f32_16x16x32_f16(aB, b, po[1][q], 0, 0, 0);
                }
            }
            const float* bo = sp_bout + i * 184;
            #pragma unroll
            for (int q = 0; q < 3; ++q) {
                int n = (w + q * 4) * 16 + lr;
                if (n < 184) {
                    float bv = bo[n];
                    #pragma unroll
                    for (int r = 0; r < 4; ++r) {
                        pS[0][lqw * 4 + r][n] = (f16)(po[0][q][r] + bv);
                        pS[1][lqw * 4 + r][n] = (f16)(po[1][q][r] + bv);
                    }
                }
            }
        }
        __syncthreads();
        // ---- spline (both tiles; wave-uniform task split: 8 tr + 8 id groups) ----
        {
            const int task = tid >> 4, rw = tid & 15;
            #pragma unroll
            for (int t2 = 0; t2 < 2; ++t2) {
                float y, ldv;
                if (task < 8) {
                    const int dim = task;
                    const float is = 0.08838834764831845f;
                    float uw[8], uh[8], udv[7];
                    const f16* pr = &pS[t2][rw][dim * 23];
                    #pragma unroll
                    for (int k = 0; k < 8; ++k) { uw[k] = (float)pr[k] * is; uh[k] = (float)pr[8 + k] * is; }
                    #pragma unroll
                    for (int k = 0; k < 7; ++k) udv[k] = (float)pr[16 + k];
                    float x = z2[t2][1][rw][2 * dim + 1];
                    rqs1(x, uw, uh, udv, y, ldv);
                    z2[t2][0][rw][2 * dim + 1] = y;
                } else {
                    const int dim = task - 8;
                    float x = z2[t2][1][rw][2 * dim];
                    rqs1_pre(x, idk + i * 384 + dim * 48, y, ldv);
                    z2[t2][0][rw][2 * dim] = y;
                }
                zF[t2][task & 7] [rw] = 0.f;  // placeholder overwritten below (avoid garbage)
                zF[t2][task >= 8 ? (task - 8) : task][rw] = 0.f;
                // store per-task partial in a unique slot: use task row directly
                ((float*)zF)[ (t2 * 16 + task) * 16 + rw ] = ldv;
            }
        }
        __syncthreads();
        if (tid < 32) {
            int t2 = tid >> 4, rw = tid & 15;
            float s = 0.f;
            #pragma unroll
            for (int t = 0; t < 16; ++t) s += ((float*)zF)[(t2 * 16 + t) * 16 + rw];
            lqS[t2][rw] += s;
        }
        __syncthreads();
    }

    // ---- MADE stage ----
    #pragma unroll
    for (int t2 = 0; t2 < 2; ++t2) {
        zS[t2][r2][d2] = (f16)z2[t2][0][r2][d2];
        zS[t2][r2][16 + d2] = (f16)0.f;
    }
    __syncthreads();
    {
        const f16* cof = ctxoutf + (size_t)4 * NHW * 384;
        const f16* cbA = cof + (size_t)hwqA * 384;
        const f16* cbB = cof + (size_t)hwqB * 384;
        float tReg[2][2][4];
        {
            f16x8 aA = *(const f16x8*)&zS[0][lr][lqw * 8];
            f16x8 aB = *(const f16x8*)&zS[1][lr][lqw * 8];
            f16x8 b0 = *(const f16x8*)(minf + ((nt0 + 0) * 64 + l) * 8);
            f16x8 b1 = *(const f16x8*)(minf + ((nt0 + 1) * 64 + l) * 8);
            float tA0 = (float)cbA[(nt0 + 0) * 16 + lr], tA1 = (float)cbA[(nt0 + 1) * 16 + lr];
            float tB0 = (float)cbB[(nt0 + 0) * 16 + lr], tB1 = (float)cbB[(nt0 + 1) * 16 + lr];
            f32x4 cA0 = {tA0, tA0, tA0, tA0}, cA1 = {tA1, tA1, tA1, tA1};
            f32x4 cB0 = {tB0, tB0, tB0, tB0}, cB1 = {tB1, tB1, tB1, tB1};
            cA0 = __builtin_amdgcn_mfma_f32_16x16x32_f16(aA, b0, cA0, 0, 0, 0);
            cB0 = __builtin_amdgcn_mfma_f32_16x16x32_f16(aB, b0, cB0, 0, 0, 0);
            cA1 = __builtin_amdgcn_mfma_f32_16x16x32_f16(aA, b1, cA1, 0, 0, 0);
            cB1 = __builtin_amdgcn_mfma_f32_16x16x32_f16(aB, b1, cB1, 0, 0, 0);
            #pragma unroll
            for (int r = 0; r < 4; ++r) {
                tReg[0][0][r] = cA0[r]; tS[0][lqw * 4 + r][(nt0 + 0) * 16 + lr] = (f16)fmaxf(cA0[r], 0.f);
                tReg[0][1][r] = cA1[r]; tS[0][lqw * 4 + r][(nt0 + 1) * 16 + lr] = (f16)fmaxf(cA1[r], 0.f);
                tReg[1][0][r] = cB0[r]; tS[1][lqw * 4 + r][(nt0 + 0) * 16 + lr] = (f16)fmaxf(cB0[r], 0.f);
                tReg[1][1][r] = cB1[r]; tS[1][lqw * 4 + r][(nt0 + 1) * 16 + lr] = (f16)fmaxf(cB1[r], 0.f);
            }
        }
        __syncthreads();
        #pragma unroll
        for (int blk = 0; blk < 2; ++blk) {
            f16 gA0 = cbA[128 + blk * 128 + (nt0 + 0) * 16 + lr];
            f16 gA1 = cbA[128 + blk * 128 + (nt0 + 1) * 16 + lr];
            f16 gB0 = cbB[128 + blk * 128 + (nt0 + 0) * 16 + lr];
            f16 gB1 = cbB[128 + blk * 128 + (nt0 + 1) * 16 + lr];
            f32x4 acc[2][2];
            acc[0][0] = vzero; acc[0][1] = vzero; acc[1][0] = vzero; acc[1][1] = vzero;
            const f16* w1 = mW1f + (size_t)blk * 16384;
            #pragma unroll
            for (int ks = 0; ks < 4; ++ks) {
                f16x8 aA = *(const f16x8*)&tS[0][lr][ks * 32 + lqw * 8];
                f16x8 aB = *(const f16x8*)&tS[1][lr][ks * 32 + lqw * 8];
                const f16* wb = w1 + (ks * 64 + l) * 8;
                f16x8 b0 = *(const f16x8*)(wb + (nt0 + 0) * 2048);
                f16x8 b1 = *(const f16x8*)(wb + (nt0 + 1) * 2048);
                acc[0][0] = __builtin_amdgcn_mfma_f32_16x16x32_f16(aA, b0, acc[0][0], 0, 0, 0);
                acc[1][0] = __builtin_amdgcn_mfma_f32_16x16x32_f16(aB, b0, acc[1][0], 0, 0, 0);
                acc[0][1] = __builtin_amdgcn_mfma_f32_16x16x32_f16(aA, b1, acc[0][1], 0, 0, 0);
                acc[1][1] = __builtin_amdgcn_mfma_f32_16x16x32_f16(aB, b1, acc[1][1], 0, 0, 0);
            }
            {
                const float* bb1p = made_bb1 + blk * 128;
                float bi0 = bb1p[(nt0 + 0) * 16 + lr];
                float bi1 = bb1p[(nt0 + 1) * 16 + lr];
                #pragma unroll
                for (int t2 = 0; t2 < 2; ++t2)
                    #pragma unroll
                    for (int r = 0; r < 4; ++r) {
                        uS[t2][lqw * 4 + r][(nt0 + 0) * 16 + lr] = (f16)fmaxf(acc[t2][0][r] + bi0, 0.f);
                        uS[t2][lqw * 4 + r][(nt0 + 1) * 16 + lr] = (f16)fmaxf(acc[t2][1][r] + bi1, 0.f);
                    }
            }
            __syncthreads();
            acc[0][0] = vzero; acc[0][1] = vzero; acc[1][0] = vzero; acc[1][1] = vzero;
            const f16* w2 = mW2f + (size_t)blk * 16384;
            #pragma unroll
            for (int ks = 0; ks < 4; ++ks) {
                f16x8 aA = *(const f16x8*)&uS[0][lr][ks * 32 + lqw * 8];
                f16x8 aB = *(const f16x8*)&uS[1][lr][ks * 32 + lqw * 8];
                const f16* wb = w2 + (ks * 64 + l) * 8;
                f16x8 b0 = *(const f16x8*)(wb + (nt0 + 0) * 2048);
                f16x8 b1 = *(const f16x8*)(wb + (nt0 + 1) * 2048);
                acc[0][0] = __builtin_amdgcn_mfma_f32_16x16x32_f16(aA, b0, acc[0][0], 0, 0, 0);
                acc[1][0] = __builtin_amdgcn_mfma_f32_16x16x32_f16(aB, b0, acc[1][0], 0, 0, 0);
                acc[0][1] = __builtin_amdgcn_mfma_f32_16x16x32_f16(aA, b1, acc[0][1], 0, 0, 0);
                acc[1][1] = __builtin_amdgcn_mfma_f32_16x16x32_f16(aB, b1, acc[1][1], 0, 0, 0);
            }
            {
                const float* bb2p = made_bb2 + blk * 128;
                float bi0 = bb2p[(nt0 + 0) * 16 + lr];
                float bi1 = bb2p[(nt0 + 1) * 16 + lr];
                float g00 = (float)gA0, g01 = (float)gA1, g10 = (float)gB0, g11 = (float)gB1;
                #pragma unroll
                for (int r = 0; r < 4; ++r) {
                    tReg[0][0][r] += (acc[0][0][r] + bi0) * g00;
                    tReg[0][1][r] += (acc[0][1][r] + bi1) * g01;
                    tReg[1][0][r] += (acc[1][0][r] + bi0) * g10;
                    tReg[1][1][r] += (acc[1][1][r] + bi1) * g11;
                    if (blk == 0) {
                        tS[0][lqw * 4 + r][(nt0 + 0) * 16 + lr] = (f16)fmaxf(tReg[0][0][r], 0.f);
                        tS[0][lqw * 4 + r][(nt0 + 1) * 16 + lr] = (f16)fmaxf(tReg[0][1][r], 0.f);
                        tS[1][lqw * 4 + r][(nt0 + 0) * 16 + lr] = (f16)fmaxf(tReg[1][0][r], 0.f);
                        tS[1][lqw * 4 + r][(nt0 + 1) * 16 + lr] = (f16)fmaxf(tReg[1][1][r], 0.f);
                    } else {
                        tS[0][lqw * 4 + r][(nt0 + 0) * 16 + lr] = (f16)tReg[0][0][r];
                        tS[0][lqw * 4 + r][(nt0 + 1) * 16 + lr] = (f16)tReg[0][1][r];
                        tS[1][lqw * 4 + r][(nt0 + 0) * 16 + lr] = (f16)tReg[1][0][r];
                        tS[1][lqw * 4 + r][(nt0 + 1) * 16 + lr] = (f16)tReg[1][1][r];
                    }
                }
            }
            __syncthreads();
        }
        // Wout (32 cols/tile): waves 0-1 -> tile A, waves 2-3 -> tile B
        {
            const int t2 = w >> 1, nt = w & 1;
            f32x4 po = vzero;
            #pragma unroll
            for (int ks = 0; ks < 4; ++ks) {
                f16x8 a = *(const f16x8*)&tS[t2][lr][ks * 32 + lqw * 8];
                f16x8 b = *(const f16x8*)(mWoutf + (ks * 64 + l) * 8 + nt * 2048);
                po = __builtin_amdgcn_mfma_f32_16x16x32_f16(a, b, po, 0, 0, 0);
            }
            int n = nt * 16 + lr;
            float bias = made_bout[n];
            #pragma unroll
            for (int r = 0; r < 4; ++r)
                pS[t2][lqw * 4 + r][n] = (f16)(po[r] + bias);
        }
    }
    __syncthreads();
    // ---- Gaussian head (both tiles) ----
    {
        const int rw = tid >> 4, d = tid & 15;
        #pragma unroll
        for (int t2 = 0; t2 < 2; ++t2) {
            const int gm = m0 + t2 * 16 + rw, hw = gm >> 2, b = gm & 3;
            float ar0 = (float)pS[t2][rw][2 * d];
            float ar1 = (float)pS[t2][rw][2 * d + 1];
            float s = softplusf(ar0) + 0.001f;
            float zn = s * z2[t2][0][rw][d] + ar1;
            float ls   = ehw[(size_t)hw * 32 + 16 + d];
            float mean = ehw[(size_t)hw * 32 + d];
            float diff = (zn - mean) * expf(-ls);
            float g = logf(s) - ls - 0.5f * diff * diff;
            g += __shfl_xor(g, 1);
            g += __shfl_xor(g, 2);
            g += __shfl_xor(g, 4);
            g += __shfl_xor(g, 8);
            if (d == 0)
                out[(size_t)b * NHW + hw] = lqS[t2][rw] + g - 14.703016531274762f;
        }
    }
}

extern "C" void kernel_launch(void* const* d_in, const int* in_sizes, int n_in,
                              void* d_out, int out_size, void* d_ws, size_t ws_size,
                              hipStream_t stream) {
    (void)in_sizes; (void)n_in; (void)out_size; (void)ws_size;
    const float* x         = (const float*)d_in[0];
    const float* made_W0   = (const float*)d_in[1];
    const float* made_b0   = (const float*)d_in[2];
    const float* made_ctxW = (const float*)d_in[3];
    const float* made_ctxb = (const float*)d_in[4];
    const float* made_bW1  = (const float*)d_in[5];
    const float* made_bb1  = (const float*)d_in[6];
    const float* made_bW2  = (const float*)d_in[7];
    const float* made_bb2  = (const float*)d_in[8];
    const float* made_bCW  = (const float*)d_in[9];
    const float* made_bCb  = (const float*)d_in[10];
    const float* made_Wout = (const float*)d_in[11];
    const float* made_bout = (const float*)d_in[12];
    const float* sp_Win    = (const float*)d_in[13];
    const float* sp_bin    = (const float*)d_in[14];
    const float* sp_bW1    = (const float*)d_in[15];
    const float* sp_bb1    = (const float*)d_in[16];
    const float* sp_bW2    = (const float*)d_in[17];
    const float* sp_bb2    = (const float*)d_in[18];
    const float* sp_bCW    = (const float*)d_in[19];
    const float* sp_bCb    = (const float*)d_in[20];
    const float* sp_Wout   = (const float*)d_in[21];
    const float* sp_bout   = (const float*)d_in[22];
    const float* sp_uw     = (const float*)d_in[23];
    const float* sp_uh     = (const float*)d_in[24];
    const float* sp_ud     = (const float*)d_in[25];
    const float* lu_lower  = (const float*)d_in[26];
    const float* lu_upper  = (const float*)d_in[27];
    const float* lu_udiag  = (const float*)d_in[28];
    const float* lu_bias   = (const float*)d_in[29];
    const int*   lu_perm   = (const int*)d_in[30];
    const float* enc_W1    = (const float*)d_in[31];
    const float* enc_b1    = (const float*)d_in[32];
    const float* enc_W2    = (const float*)d_in[33];
    const float* enc_b2    = (const float*)d_in[34];
    float* out = (float*)d_out;

    float* ws      = (float*)d_ws;
    float* ctx     = ws;                               // 9216*128 f32
    float* z       = ctx     + (size_t)NHW * 128;      // 36864*16
    float* thw_enc = z       + (size_t)NROWS * 16;     // 9216*128
    float* ehw     = thw_enc + (size_t)NHW * 128;      // 9216*32
    float* cpb     = ehw     + (size_t)NHW * 32;       // 5*384
    float* idk     = cpb     + 5 * 384;                // 4*8*48
    float* Mlu     = idk     + 1536;                   // 4*256
    float* luc     = Mlu     + 1024;                   // 1 (pad 16)
    f16*   ctxoutf = (f16*)(luc + 16);                 // 5*9216*384 f16
    f16*   fW1f    = ctxoutf + (size_t)5 * NHW * 384;  // 8*16384
    f16*   fW2f    = fW1f    + 8 * 16384;              // 8*16384
    f16*   mW1f    = fW2f    + 8 * 16384;              // 2*16384
    f16*   mW2f    = mW1f    + 2 * 16384;              // 2*16384
    f16*   fWoutf  = mW2f    + 2 * 16384;              // 4*24576
    f16*   mWoutf  = fWoutf  + 4 * 24576;              // 4096
    f16*   finf    = mWoutf  + 4096;                   // 4*4096
    f16*   minf    = finf    + 4 * 4096;               // 4096
    f16*   cfrag   = minf    + 4096;                   // 5*49152

    dim3 B(256);
    pack_kernel<<<dim3(960, 10), B, 0, stream>>>(
        sp_bW1, sp_bW2, made_bW1, made_bW2, sp_Wout, made_Wout, sp_Win, made_W0,
        sp_bCW, made_ctxW, made_bCW, sp_bin, sp_bCb, made_ctxb, made_b0, made_bCb,
        fW1f, fW2f, mW1f, mW2f, fWoutf, mWoutf, finf, minf, cfrag, cpb);
    ctx_kernel<<<4608, B, 0, stream>>>(ctx);
    snorm_kernel<<<2304, B, 0, stream>>>(x, z);
    prep_kernel<<<1, 64, 0, stream>>>(sp_uw, sp_uh, sp_ud, lu_lower, lu_upper,
                                      lu_udiag, lu_perm, idk, Mlu, luc);

    // ctx-dependent precomputes
    ctx_mfma<<<dim3(576, 5), B, 0, stream>>>(ctx, cfrag, cpb, ctxoutf);
    gemm_k<2><<<dim3(144, 2), B, 0, stream>>>(ctx, 128, enc_W1, 128, enc_b1, thw_enc, 128, NHW, 128, 128);
    gemm_k<0><<<dim3(144, 1), B, 0, stream>>>(thw_enc, 128, enc_W2, 128, enc_b2, ehw, 32, NHW, 32, 128);

    // the entire per-row pipeline in one kernel (two 16-row tiles per block)
    mega_all<<<1152, B, 0, stream>>>(z, ctxoutf, finf, minf,
                                     fW1f, fW2f, mW1f, mW2f, fWoutf, mWoutf,
                                     sp_bb1, sp_bb2, made_bb1, made_bb2,
                                     sp_bout, made_bout,
                                     Mlu, lu_bias, idk, luc, ehw, out);
}

// Round 11
// 343.794 us; speedup vs baseline: 1.0748x; 1.0748x over previous
//
#include <hip/hip_runtime.h>
#include <math.h>

#define NHW   9216     // 96*96
#define NROWS 36864    // NHW*4

typedef _Float16 f16;
typedef _Float16 f16x8 __attribute__((ext_vector_type(8)));
typedef float    f32x4 __attribute__((ext_vector_type(4)));

__device__ __forceinline__ float softplusf(float x) {
    return fmaxf(x, 0.f) + log1pf(expf(-fabsf(x)));
}

// ---------------- positional encoding ctx[hw][128] ----------------
__global__ __launch_bounds__(256) void ctx_kernel(float* __restrict__ ctx) {
    int e = blockIdx.x * 256 + threadIdx.x;
    if (e >= NHW * 128) return;
    int c  = e & 127;
    int hw = e >> 7;
    int i = hw / 96, j = hw % 96;
    int pos = (c < 64) ? i : j;
    int cc = c & 63;
    int k = cc >> 1;
    float invf = exp2f((float)k * -0.4152410118609203f);  // 10000^(-k/32)
    float v = (float)pos * invf;
    ctx[e] = (cc & 1) ? cosf(v) : sinf(v);
}

// ---------------- spatial_norm -> z[row][16], row = (i*96+j)*4+b ----------------
__global__ __launch_bounds__(256) void snorm_kernel(const float* __restrict__ x,
                                                    float* __restrict__ z) {
    int e = blockIdx.x * 256 + threadIdx.x;
    if (e >= NROWS * 16) return;
    int j = e % 96;
    int i = (e / 96) % 96;
    int s = (e / 9216) % 16;
    int b = e / (9216 * 16);
    float sum = 0.f;
    const float* xb = x + (size_t)((b * 16 + s) * 3) * 192 * 192;
    #pragma unroll
    for (int c = 0; c < 3; ++c) {
        const float* xc = xb + (size_t)c * 192 * 192;
        #pragma unroll
        for (int dh = -1; dh <= 1; ++dh) {
            int hh = 2 * i + dh;
            if (hh < 0 || hh >= 192) continue;
            const float* xr = xc + hh * 192;
            #pragma unroll
            for (int dw = -1; dw <= 1; ++dw) {
                int ww = 2 * j + dw;
                if (ww < 0 || ww >= 192) continue;
                float v = xr[ww];
                sum += v * v;
            }
        }
    }
    int row = (i * 96 + j) * 4 + b;
    z[(size_t)row * 16 + s] = sqrtf(sum);
}

// ---------------- knots helper ----------------
__device__ __forceinline__ void knots8(const float* __restrict__ u, float* c, float* w) {
    float mx = u[0];
    #pragma unroll
    for (int k = 1; k < 8; ++k) mx = fmaxf(mx, u[k]);
    float e[8]; float s = 0.f;
    #pragma unroll
    for (int k = 0; k < 8; ++k) { e[k] = expf(u[k] - mx); s += e[k]; }
    float inv = 1.f / s;
    c[0] = -3.f;
    float cum = 0.f;
    #pragma unroll
    for (int k = 0; k < 8; ++k) {
        float v = 0.001f + 0.992f * e[k] * inv;
        cum += v;
        c[k + 1] = cum * 6.f - 3.f;
    }
    c[8] = 3.f;
    #pragma unroll
    for (int k = 0; k < 8; ++k) w[k] = c[k + 1] - c[k];
}

// ---------------- prep: id-knots + LU folding (Weff/MluT/beff frags) + luc ----------------
// idk[4][8][48]; weffF[4][4096] f16 (input frags, K=32 pad, raw-z x Weff);
// mlutF[4][512] f16 (z_lu = z @ Mlu^T frags); beff[4][128] f32; luc[1].
__global__ __launch_bounds__(256) void prep_kernel(const float* __restrict__ sp_uw,
                                                   const float* __restrict__ sp_uh,
                                                   const float* __restrict__ sp_ud,
                                                   const float* __restrict__ sp_Win,
                                                   const float* __restrict__ lu_lower,
                                                   const float* __restrict__ lu_upper,
                                                   const float* __restrict__ lu_udiag,
                                                   const int*   __restrict__ lu_perm,
                                                   float* __restrict__ idk,
                                                   f16*   __restrict__ weffF,
                                                   f16*   __restrict__ mlutF,
                                                   float* __restrict__ beff,
                                                   float* __restrict__ luc) {
    __shared__ float sMlu[4][16][16];
    int t = threadIdx.x;
    if (t < 64) {
        int s = t >> 4, d = t & 15;
        const float* L  = lu_lower + s * 256;
        const float* U  = lu_upper + s * 256;
        const float* ud = lu_udiag + s * 16;
        const int*   pm = lu_perm + s * 16;
        for (int c = 0; c < 16; ++c) {
            float m = 0.f;
            if (c > d)       m += U[d * 16 + c];
            else if (c == d) m += softplusf(ud[d]) + 0.001f;
            for (int e = 0; e < d && e <= c; ++e) {
                float u = (c > e) ? U[e * 16 + c] : (softplusf(ud[e]) + 0.001f);
                m += L[d * 16 + e] * u;
            }
            sMlu[s][d][pm[c]] = m;
        }
    } else if (t < 96) {
        int tt = t - 64;
        int s = tt >> 3, dim = tt & 7;
        float* o = idk + (s * 8 + dim) * 48;
        float c[9], w[8];
        knots8(sp_uw + s * 64 + dim * 8, c, w);
        #pragma unroll
        for (int k = 0; k < 9; ++k) o[k] = c[k];
        #pragma unroll
        for (int k = 0; k < 8; ++k) o[9 + k] = w[k];
        knots8(sp_uh + s * 64 + dim * 8, c, w);
        #pragma unroll
        for (int k = 0; k < 9; ++k) o[17 + k] = c[k];
        #pragma unroll
        for (int k = 0; k < 8; ++k) o[26 + k] = w[k];
        o[34] = 1.f; o[42] = 1.f;
        #pragma unroll
        for (int k = 0; k < 7; ++k) o[35 + k] = 0.001f + softplusf(sp_ud[s * 56 + dim * 7 + k]);
    } else if (t == 96) {
        float c0 = 0.f;
        for (int k = 0; k < 64; ++k)
            c0 += logf(softplusf(lu_udiag[k]) + 0.001f);
        luc[0] = c0;
    }
    __syncthreads();
    // weffF: 4 steps x 4096
    for (int e = t; e < 4 * 4096; e += 256) {
        int s = e >> 12, f = e & 4095;
        int nt = f >> 9, l = (f >> 3) & 63, j = f & 7;
        int n = nt * 16 + (l & 15), k = ((l >> 4) & 3) * 8 + j;
        float v = 0.f;
        if (k < 16) {
            #pragma unroll
            for (int p = 0; p < 8; ++p)
                v += sMlu[s][2 * p][k] * sp_Win[s * 17408 + n * 136 + p];
        }
        weffF[e] = (f16)v;
    }
    // mlutF: 4 x 512
    for (int e = t; e < 4 * 512; e += 256) {
        int s = e >> 9, f = e & 511;
        int l = f >> 3, j = f & 7;
        int n = l & 15, k = (l >> 4) * 8 + j;
        mlutF[e] = (k < 16) ? (f16)sMlu[s][n][k] : (f16)0.f;
    }
    // beff: 4 x 128
    for (int e = t; e < 4 * 128; e += 256) {
        int s = e >> 7, n = e & 127;
        float v = 0.f;
        #pragma unroll
        for (int p = 0; p < 8; ++p)
            v += lu_lower[0] * 0.f + 0.f;  // placeholder no-op (keeps structure clear)
        v = 0.f;
        #pragma unroll
        for (int p = 0; p < 8; ++p)
            v += sp_Win[s * 17408 + n * 136 + p] * 0.f;
        // real computation (lu_bias folded): beff[s][n] = sum_p lu_bias[s][2p]*Win[s][n][p]
        beff[e] = v;  // overwritten below
    }
    __syncthreads();
    // (recompute beff properly with lu_bias passed via lu_lower? -- need lu_bias pointer)
}

// beff needs lu_bias; separate tiny kernel to keep prep signature clean
__global__ __launch_bounds__(256) void beff_kernel(const float* __restrict__ sp_Win,
                                                   const float* __restrict__ lu_bias,
                                                   float* __restrict__ beff) {
    int e = blockIdx.x * 256 + threadIdx.x;
    if (e >= 4 * 128) return;
    int s = e >> 7, n = e & 127;
    float v = 0.f;
    #pragma unroll
    for (int p = 0; p < 8; ++p)
        v += lu_bias[s * 16 + 2 * p] * sp_Win[s * 17408 + n * 136 + p];
    beff[e] = v;
}

// ---------------- one-time weight pack kernel ----------------
__global__ __launch_bounds__(256) void pack_kernel(
    const float* __restrict__ sp_bW1, const float* __restrict__ sp_bW2,
    const float* __restrict__ made_bW1, const float* __restrict__ made_bW2,
    const float* __restrict__ sp_Wout, const float* __restrict__ made_Wout,
    const float* __restrict__ sp_Win, const float* __restrict__ made_W0,
    const float* __restrict__ sp_bCW, const float* __restrict__ made_ctxW,
    const float* __restrict__ made_bCW,
    const float* __restrict__ sp_bin, const float* __restrict__ sp_bCb,
    const float* __restrict__ made_ctxb, const float* __restrict__ made_b0,
    const float* __restrict__ made_bCb,
    f16* __restrict__ fW1f, f16* __restrict__ fW2f,
    f16* __restrict__ mW1f, f16* __restrict__ mW2f,
    f16* __restrict__ fWoutf, f16* __restrict__ mWoutf,
    f16* __restrict__ minf,
    f16* __restrict__ cfrag, float* __restrict__ cpb)
{
    int cat = blockIdx.y;
    int e = blockIdx.x * 256 + threadIdx.x;
    switch (cat) {
    case 0: if (e < 8 * 16384) {
        int mtx = e >> 14, f = e & 16383;
        int nt = f >> 11, ks = (f >> 9) & 3, l = (f >> 3) & 63, j = f & 7;
        int n = nt * 16 + (l & 15), k = ks * 32 + ((l >> 4) & 3) * 8 + j;
        fW1f[e] = (f16)sp_bW1[mtx * 16384 + n * 128 + k];
    } break;
    case 1: if (e < 8 * 16384) {
        int mtx = e >> 14, f = e & 16383;
        int nt = f >> 11, ks = (f >> 9) & 3, l = (f >> 3) & 63, j = f & 7;
        int n = nt * 16 + (l & 15), k = ks * 32 + ((l >> 4) & 3) * 8 + j;
        fW2f[e] = (f16)sp_bW2[mtx * 16384 + n * 128 + k];
    } break;
    case 2: if (e < 2 * 16384) {
        int mtx = e >> 14, f = e & 16383;
        int nt = f >> 11, ks = (f >> 9) & 3, l = (f >> 3) & 63, j = f & 7;
        int n = nt * 16 + (l & 15), k = ks * 32 + ((l >> 4) & 3) * 8 + j;
        mW1f[e] = ((n % 15) >= (k % 15)) ? (f16)made_bW1[mtx * 16384 + n * 128 + k] : (f16)0.f;
    } break;
    case 3: if (e < 2 * 16384) {
        int mtx = e >> 14, f = e & 16383;
        int nt = f >> 11, ks = (f >> 9) & 3, l = (f >> 3) & 63, j = f & 7;
        int n = nt * 16 + (l & 15), k = ks * 32 + ((l >> 4) & 3) * 8 + j;
        mW2f[e] = ((n % 15) >= (k % 15)) ? (f16)made_bW2[mtx * 16384 + n * 128 + k] : (f16)0.f;
    } break;
    case 4: if (e < 4 * 24576) {
        int s = e / 24576, f = e % 24576;
        int nt = f >> 11, ks = (f >> 9) & 3, l = (f >> 3) & 63, j = f & 7;
        int n = nt * 16 + (l & 15), k = ks * 32 + ((l >> 4) & 3) * 8 + j;
        fWoutf[e] = (n < 184) ? (f16)sp_Wout[s * 23552 + n * 128 + k] : (f16)0.f;
    } break;
    case 5: if (e < 4096) {
        int f = e;
        int nt = f >> 11, ks = (f >> 9) & 3, l = (f >> 3) & 63, j = f & 7;
        int n = nt * 16 + (l & 15), k = ks * 32 + ((l >> 4) & 3) * 8 + j;
        mWoutf[e] = (((n & 15) > (k % 15)) && n < 32) ? (f16)made_Wout[n * 128 + k] : (f16)0.f;
    } break;
    case 6: if (e < 4096) {
        int f = e;
        int nt = f >> 9, l = (f >> 3) & 63, j = f & 7;
        int n = nt * 16 + (l & 15), k = ((l >> 4) & 3) * 8 + j;
        minf[e] = (k < 16 && (n % 15) >= k) ? (f16)made_W0[n * 16 + k] : (f16)0.f;
    } break;
    case 7: if (e < 5 * 49152) {
        int s = e / 49152, f = e % 49152;
        int nt = f >> 11, ks = (f >> 9) & 3, l = (f >> 3) & 63, j = f & 7;
        int n = nt * 16 + (l & 15), k = ks * 32 + ((l >> 4) & 3) * 8 + j;
        float v;
        if (s < 4) {
            if (n < 128)      v = sp_Win[s * 17408 + n * 136 + 8 + k];
            else if (n < 256) v = sp_bCW[(size_t)(s * 2 + 0) * 16384 + (n - 128) * 128 + k];
            else              v = sp_bCW[(size_t)(s * 2 + 1) * 16384 + (n - 256) * 128 + k];
        } else {
            if (n < 128)      v = made_ctxW[n * 128 + k];
            else if (n < 256) v = made_bCW[(n - 128) * 128 + k];
            else              v = made_bCW[16384 + (n - 256) * 128 + k];
        }
        cfrag[e] = (f16)v;
    } break;
    case 8: if (e < 5 * 384) {
        int s = e / 384, n = e % 384;
        float v;
        if (s < 4) {
            if (n < 128)      v = sp_bin[s * 128 + n];
            else if (n < 256) v = sp_bCb[(s * 2 + 0) * 128 + (n - 128)];
            else              v = sp_bCb[(s * 2 + 1) * 128 + (n - 256)];
        } else {
            if (n < 128)      v = made_ctxb[n] + made_b0[n];
            else if (n < 256) v = made_bCb[n - 128];
            else              v = made_bCb[128 + (n - 256)];
        }
        cpb[e] = v;
    } break;
    }
}

// ---------------- ctx-chain MFMA: ctxoutf[s][hw][384] (n>=128 sigmoided), f16 ----------------
__global__ __launch_bounds__(256) void ctx_mfma(
    const float* __restrict__ ctx, const f16* __restrict__ cfrag,
    const float* __restrict__ cpb, f16* __restrict__ ctxoutf)
{
    __shared__ alignas(16) f16 cS[16][136];
    const int tid = threadIdx.x, w = tid >> 6, l = tid & 63;
    const int m0 = blockIdx.x * 16;
    const int s  = blockIdx.y;
    const int lr = l & 15, lq = l >> 4;
    #pragma unroll
    for (int it = 0; it < 2; ++it) {
        int e = tid + it * 256;
        int r = e >> 5, c4 = (e & 31) * 4;
        float4 v = *(const float4*)(ctx + (size_t)(m0 + r) * 128 + c4);
        cS[r][c4 + 0] = (f16)v.x; cS[r][c4 + 1] = (f16)v.y;
        cS[r][c4 + 2] = (f16)v.z; cS[r][c4 + 3] = (f16)v.w;
    }
    __syncthreads();
    const f32x4 vzero = {0.f, 0.f, 0.f, 0.f};
    f32x4 acc[6];
    #pragma unroll
    for (int q = 0; q < 6; ++q) acc[q] = vzero;
    const f16* wb = cfrag + (size_t)s * 49152;
    #pragma unroll
    for (int ks = 0; ks < 4; ++ks) {
        f16x8 a = *(const f16x8*)&cS[lr][ks * 32 + lq * 8];
        #pragma unroll
        for (int q = 0; q < 6; ++q) {
            int g = w * 6 + q;
            f16x8 b = *(const f16x8*)(wb + (size_t)((g * 4 + ks) * 64 + l) * 8);
            acc[q] = __builtin_amdgcn_mfma_f32_16x16x32_f16(a, b, acc[q], 0, 0, 0);
        }
    }
    #pragma unroll
    for (int q = 0; q < 6; ++q) {
        int g = w * 6 + q, n = g * 16 + lr;
        float bias = cpb[s * 384 + n];
        #pragma unroll
        for (int r = 0; r < 4; ++r) {
            float val = acc[q][r] + bias;
            if (n >= 128) val = 1.f / (1.f + expf(-val));
            ctxoutf[(size_t)s * NHW * 384 + (size_t)(m0 + lq * 4 + r) * 384 + n] = (f16)val;
        }
    }
}

// ---------------- tiled f32 GEMM (encoder): C = post(A @ W^T + bias) ----------------
template<int POST>   // 0 store, 2 silu
__global__ __launch_bounds__(256) void gemm_k(
    const float* __restrict__ A, int lda,
    const float* __restrict__ W, int ldw,
    const float* __restrict__ bias,
    float* __restrict__ C, int ldc,
    int M, int N, int K)
{
    __shared__ alignas(16) float As[16][68];
    __shared__ alignas(16) float Ws[16][68];
    const int tid = threadIdx.x;
    const int m0 = blockIdx.x * 64;
    const int n0 = blockIdx.y * 64;
    const int tm = (tid >> 4) << 2;
    const int tn = (tid & 15) << 2;
    const int srow = tid >> 2;
    const int skq  = (tid & 3) << 2;

    float acc[4][4] = {{0.f,0.f,0.f,0.f},{0.f,0.f,0.f,0.f},{0.f,0.f,0.f,0.f},{0.f,0.f,0.f,0.f}};

    for (int k0 = 0; k0 < K; k0 += 16) {
        float4 av = *(const float4*)(A + (size_t)(m0 + srow) * lda + k0 + skq);
        As[skq + 0][srow] = av.x; As[skq + 1][srow] = av.y;
        As[skq + 2][srow] = av.z; As[skq + 3][srow] = av.w;
        int wn = n0 + srow;
        float4 wv = make_float4(0.f, 0.f, 0.f, 0.f);
        if (wn < N) wv = *(const float4*)(W + (size_t)wn * ldw + k0 + skq);
        Ws[skq + 0][srow] = wv.x; Ws[skq + 1][srow] = wv.y;
        Ws[skq + 2][srow] = wv.z; Ws[skq + 3][srow] = wv.w;
        __syncthreads();
        #pragma unroll
        for (int kk = 0; kk < 16; ++kk) {
            float4 a4 = *(const float4*)&As[kk][tm];
            float4 w4 = *(const float4*)&Ws[kk][tn];
            float aa[4] = {a4.x, a4.y, a4.z, a4.w};
            float wwv[4] = {w4.x, w4.y, w4.z, w4.w};
            #pragma unroll
            for (int q = 0; q < 4; ++q)
                #pragma unroll
                for (int r = 0; r < 4; ++r)
                    acc[q][r] = fmaf(aa[q], wwv[r], acc[q][r]);
        }
        __syncthreads();
    }
    #pragma unroll
    for (int q = 0; q < 4; ++q) {
        int m = m0 + tm + q;
        #pragma unroll
        for (int r = 0; r < 4; ++r) {
            int n = n0 + tn + r;
            if (n < N) {
                float val = acc[q][r] + bias[n];
                float* cp = C + (size_t)m * ldc + n;
                if (POST == 0) *cp = val;
                else           *cp = val / (1.f + expf(-val));
            }
        }
    }
}

// ---------------- rational-quadratic spline ----------------
__device__ __forceinline__ void rqs_core(float x, const float* cw, const float* wd,
                                         const float* ch, const float* hg, const float* dd,
                                         float& y, float& ld) {
    bool inside = (x >= -3.f) && (x <= 3.f);
    float xc = fminf(fmaxf(x, -3.f), 3.f);
    float cwk = cw[0], wk = wd[0], chk = ch[0], hk = hg[0], d0 = dd[0], d1 = dd[1];
    #pragma unroll
    for (int k = 1; k < 8; ++k) {
        if (xc >= cw[k]) { cwk = cw[k]; wk = wd[k]; chk = ch[k]; hk = hg[k]; d0 = dd[k]; d1 = dd[k + 1]; }
    }
    float dl = hk / wk;
    float th = (xc - cwk) / wk;
    float t1 = th * (1.f - th);
    float den = dl + (d0 + d1 - 2.f * dl) * t1;
    float yy = chk + hk * (dl * th * th + d0 * t1) / den;
    float om = 1.f - th;
    float dnum = dl * dl * (d1 * th * th + 2.f * dl * t1 + d0 * om * om);
    float lld = logf(dnum) - 2.f * logf(den);
    y  = inside ? yy : x;
    ld = inside ? lld : 0.f;
}

__device__ __forceinline__ void rqs1(float x,
                                     const float* __restrict__ uw,
                                     const float* __restrict__ uh,
                                     const float* __restrict__ ud,
                                     float& y, float& ld) {
    float cw[9], wd[8], ch[9], hg[8], dd[9];
    knots8(uw, cw, wd);
    knots8(uh, ch, hg);
    dd[0] = 1.f; dd[8] = 1.f;
    #pragma unroll
    for (int k = 0; k < 7; ++k) dd[k + 1] = 0.001f + softplusf(ud[k]);
    rqs_core(x, cw, wd, ch, hg, dd, y, ld);
}

__device__ __forceinline__ void rqs1_pre(float x, const float* __restrict__ kn,
                                         float& y, float& ld) {
    float cw[9], wd[8], ch[9], hg[8], dd[9];
    #pragma unroll
    for (int k = 0; k < 9; ++k) cw[k] = kn[k];
    #pragma unroll
    for (int k = 0; k < 8; ++k) wd[k] = kn[9 + k];
    #pragma unroll
    for (int k = 0; k < 9; ++k) ch[k] = kn[17 + k];
    #pragma unroll
    for (int k = 0; k < 8; ++k) hg[k] = kn[26 + k];
    #pragma unroll
    for (int k = 0; k < 9; ++k) dd[k] = kn[34 + k];
    rqs_core(x, cw, wd, ch, hg, dd, y, ld);
}

// ---------------- merged pipeline, LU folded into input MFMA ----------------
// 16-row tile per block. Per flow step: {input+zlu MFMA} {W1} {W2} {W1'} {W2'} {Wout} {spline}
// (7 barriers; no LU phase, no staging phase — spline writes next zS directly;
//  logq via LDS atomicAdd inside spline phase).
__global__ __launch_bounds__(256) void mega_all(
    const float* __restrict__ zg,
    const f16*  __restrict__ ctxoutf,   // [5][9216][384]
    const f16*  __restrict__ weffF,     // [4][4096]  input frags (raw z, K=32 pad)
    const f16*  __restrict__ mlutF,     // [4][512]   z_lu frags
    const float* __restrict__ beffv,    // [4][128]
    const f16*  __restrict__ minf,      // [4096]
    const f16*  __restrict__ fW1f,      // [4][2][16384]
    const f16*  __restrict__ fW2f,
    const f16*  __restrict__ mW1f,      // [2][16384]
    const f16*  __restrict__ mW2f,
    const f16*  __restrict__ fWoutf,    // [4][24576]
    const f16*  __restrict__ mWoutf,    // [4096]
    const float* __restrict__ sp_bb1,   // [4][2][128]
    const float* __restrict__ sp_bb2,
    const float* __restrict__ made_bb1, // [2][128]
    const float* __restrict__ made_bb2,
    const float* __restrict__ sp_bout,  // [4][184]
    const float* __restrict__ made_bout,// [32]
    const float* __restrict__ lu_bias,  // [4][16]
    const float* __restrict__ idk,      // [4][8][48]
    const float* __restrict__ luc,      // [1]
    const float* __restrict__ ehw,      // [9216][32]
    float* __restrict__ out)            // [4][9216]
{
    __shared__ alignas(16) f16 tS[16][136];
    __shared__ alignas(16) f16 uS[16][136];
    __shared__ alignas(16) f16 zS[16][32];
    __shared__ alignas(16) f16 pS[16][196];
    __shared__ float zlu[16][17];   // z_lu (pre-spline) f32
    __shared__ float zO[16][17];    // final z f32 (for Gaussian head)
    __shared__ float lqS[16];
    const int tid = threadIdx.x;
    const int w   = tid >> 6;
    const int l   = tid & 63;
    const int lr  = l & 15;
    const int lqw = l >> 4;
    const int m0  = blockIdx.x * 16;
    const int hwq = (m0 >> 2) + lqw;
    const int nt0 = w * 2;
    const int r2  = tid >> 4, d2 = tid & 15;
    const f32x4 vzero = {0.f, 0.f, 0.f, 0.f};

    // prologue: stage raw z (f16, K=32 pad), init lqS
    zS[r2][d2] = (f16)zg[(size_t)(m0 + r2) * 16 + d2];
    zS[r2][16 + d2] = (f16)0.f;
    if (tid < 16) lqS[tid] = luc[0];
    __syncthreads();

    for (int i = 3; i >= 0; --i) {
        const f16* cof = ctxoutf + (size_t)i * NHW * 384;
        const f16* cb  = cof + (size_t)hwq * 384;
        float tReg[2][4];
        // ---- input phase: t = thw + beff + z@Weff ; wave0 also z_lu = z@Mlu^T + b ----
        {
            f16x8 a = *(const f16x8*)&zS[lr][lqw * 8];
            if (w == 0) {
                float bl = lu_bias[i * 16 + lr];
                f32x4 c = {bl, bl, bl, bl};
                f16x8 b = *(const f16x8*)(mlutF + i * 512 + l * 8);
                c = __builtin_amdgcn_mfma_f32_16x16x32_f16(a, b, c, 0, 0, 0);
                #pragma unroll
                for (int r = 0; r < 4; ++r)
                    zlu[lqw * 4 + r][lr] = c[r];
            }
            const f16* wp = weffF + i * 4096;
            #pragma unroll
            for (int t = 0; t < 2; ++t) {
                int nt = nt0 + t, n = nt * 16 + lr;
                float ci = (float)cb[n] + beffv[i * 128 + n];
                f32x4 c = {ci, ci, ci, ci};
                f16x8 b = *(const f16x8*)(wp + (nt * 64 + l) * 8);
                c = __builtin_amdgcn_mfma_f32_16x16x32_f16(a, b, c, 0, 0, 0);
                #pragma unroll
                for (int r = 0; r < 4; ++r) {
                    tReg[t][r] = c[r];
                    tS[lqw * 4 + r][nt * 16 + lr] = (f16)fmaxf(c[r], 0.f);
                }
            }
        }
        __syncthreads();
        // ---- residual blocks ----
        #pragma unroll
        for (int blk = 0; blk < 2; ++blk) {
            f32x4 acc0 = vzero, acc1 = vzero;
            const f16* w1 = fW1f + (size_t)i * 32768 + (size_t)blk * 16384;
            #pragma unroll
            for (int ks = 0; ks < 4; ++ks) {
                f16x8 a = *(const f16x8*)&tS[lr][ks * 32 + lqw * 8];
                const f16* wb = w1 + (ks * 64 + l) * 8;
                acc0 = __builtin_amdgcn_mfma_f32_16x16x32_f16(a, *(const f16x8*)(wb + (nt0 + 0) * 2048), acc0, 0, 0, 0);
                acc1 = __builtin_amdgcn_mfma_f32_16x16x32_f16(a, *(const f16x8*)(wb + (nt0 + 1) * 2048), acc1, 0, 0, 0);
            }
            {
                const float* bb1p = sp_bb1 + i * 256 + blk * 128;
                float bi0 = bb1p[(nt0 + 0) * 16 + lr];
                float bi1 = bb1p[(nt0 + 1) * 16 + lr];
                #pragma unroll
                for (int r = 0; r < 4; ++r) {
                    uS[lqw * 4 + r][(nt0 + 0) * 16 + lr] = (f16)fmaxf(acc0[r] + bi0, 0.f);
                    uS[lqw * 4 + r][(nt0 + 1) * 16 + lr] = (f16)fmaxf(acc1[r] + bi1, 0.f);
                }
            }
            __syncthreads();
            acc0 = vzero; acc1 = vzero;
            const f16* w2 = fW2f + (size_t)i * 32768 + (size_t)blk * 16384;
            #pragma unroll
            for (int ks = 0; ks < 4; ++ks) {
                f16x8 a = *(const f16x8*)&uS[lr][ks * 32 + lqw * 8];
                const f16* wb = w2 + (ks * 64 + l) * 8;
                acc0 = __builtin_amdgcn_mfma_f32_16x16x32_f16(a, *(const f16x8*)(wb + (nt0 + 0) * 2048), acc0, 0, 0, 0);
                acc1 = __builtin_amdgcn_mfma_f32_16x16x32_f16(a, *(const f16x8*)(wb + (nt0 + 1) * 2048), acc1, 0, 0, 0);
            }
            {
                const float* bb2p = sp_bb2 + i * 256 + blk * 128;
                float bi0 = bb2p[(nt0 + 0) * 16 + lr];
                float bi1 = bb2p[(nt0 + 1) * 16 + lr];
                float g0 = (float)cb[128 + blk * 128 + (nt0 + 0) * 16 + lr];
                float g1 = (float)cb[128 + blk * 128 + (nt0 + 1) * 16 + lr];
                #pragma unroll
                for (int r = 0; r < 4; ++r) {
                    tReg[0][r] += (acc0[r] + bi0) * g0;
                    tReg[1][r] += (acc1[r] + bi1) * g1;
                    tS[lqw * 4 + r][(nt0 + 0) * 16 + lr] =
                        (blk == 0) ? (f16)fmaxf(tReg[0][r], 0.f) : (f16)tReg[0][r];
                    tS[lqw * 4 + r][(nt0 + 1) * 16 + lr] =
                        (blk == 0) ? (f16)fmaxf(tReg[1][r], 0.f) : (f16)tReg[1][r];
                }
            }
            __syncthreads();
        }
        // ---- Wout -> pS ----
        {
            f32x4 po0 = vzero, po1 = vzero, po2 = vzero;
            const f16* wo = fWoutf + (size_t)i * 24576;
            #pragma unroll
            for (int ks = 0; ks < 4; ++ks) {
                f16x8 a = *(const f16x8*)&tS[lr][ks * 32 + lqw * 8];
                const f16* wb = wo + (ks * 64 + l) * 8;
                po0 = __builtin_amdgcn_mfma_f32_16x16x32_f16(a, *(const f16x8*)(wb + (w + 0) * 2048), po0, 0, 0, 0);
                po1 = __builtin_amdgcn_mfma_f32_16x16x32_f16(a, *(const f16x8*)(wb + (w + 4) * 2048), po1, 0, 0, 0);
                po2 = __builtin_amdgcn_mfma_f32_16x16x32_f16(a, *(const f16x8*)(wb + (w + 8) * 2048), po2, 0, 0, 0);
            }
            const float* bo = sp_bout + i * 184;
            int n0q = (w + 0) * 16 + lr, n1q = (w + 4) * 16 + lr, n2q = (w + 8) * 16 + lr;
            float b0v = bo[n0q], b1v = bo[n1q];
            float b2v = (n2q < 184) ? bo[n2q] : 0.f;
            #pragma unroll
            for (int r = 0; r < 4; ++r) {
                pS[lqw * 4 + r][n0q] = (f16)(po0[r] + b0v);
                pS[lqw * 4 + r][n1q] = (f16)(po1[r] + b1v);
                if (n2q < 184) pS[lqw * 4 + r][n2q] = (f16)(po2[r] + b2v);
            }
        }
        __syncthreads();
        // ---- spline: writes zO (f32), zS (f16 next-step staging), logq atomic ----
        {
            const int task = tid >> 4, rw = tid & 15;
            float y, ldv;
            if (task < 8) {
                const int dim = task;
                const float is = 0.08838834764831845f;
                float uw[8], uh[8], udv[7];
                const f16* pr = &pS[rw][dim * 23];
                #pragma unroll
                for (int k = 0; k < 8; ++k) { uw[k] = (float)pr[k] * is; uh[k] = (float)pr[8 + k] * is; }
                #pragma unroll
                for (int k = 0; k < 7; ++k) udv[k] = (float)pr[16 + k];
                float x = zlu[rw][2 * dim + 1];
                rqs1(x, uw, uh, udv, y, ldv);
                zO[rw][2 * dim + 1] = y;
                zS[rw][2 * dim + 1] = (f16)y;
            } else {
                const int dim = task - 8;
                float x = zlu[rw][2 * dim];
                rqs1_pre(x, idk + i * 384 + dim * 48, y, ldv);
                zO[rw][2 * dim] = y;
                zS[rw][2 * dim] = (f16)y;
            }
            atomicAdd(&lqS[rw], ldv);
        }
        __syncthreads();
    }

    // ---- MADE stage (zS already holds final z) ----
    {
        const f16* cof = ctxoutf + (size_t)4 * NHW * 384;
        const f16* cb  = cof + (size_t)hwq * 384;
        float tReg[2][4];
        {
            f16x8 a = *(const f16x8*)&zS[lr][lqw * 8];
            #pragma unroll
            for (int t = 0; t < 2; ++t) {
                int nt = nt0 + t;
                float thw = (float)cb[nt * 16 + lr];
                f32x4 c = {thw, thw, thw, thw};
                f16x8 b = *(const f16x8*)(minf + (nt * 64 + l) * 8);
                c = __builtin_amdgcn_mfma_f32_16x16x32_f16(a, b, c, 0, 0, 0);
                #pragma unroll
                for (int r = 0; r < 4; ++r) {
                    tReg[t][r] = c[r];
                    tS[lqw * 4 + r][nt * 16 + lr] = (f16)fmaxf(c[r], 0.f);
                }
            }
        }
        __syncthreads();
        #pragma unroll
        for (int blk = 0; blk < 2; ++blk) {
            f32x4 acc0 = vzero, acc1 = vzero;
            const f16* w1 = mW1f + (size_t)blk * 16384;
            #pragma unroll
            for (int ks = 0; ks < 4; ++ks) {
                f16x8 a = *(const f16x8*)&tS[lr][ks * 32 + lqw * 8];
                const f16* wb = w1 + (ks * 64 + l) * 8;
                acc0 = __builtin_amdgcn_mfma_f32_16x16x32_f16(a, *(const f16x8*)(wb + (nt0 + 0) * 2048), acc0, 0, 0, 0);
                acc1 = __builtin_amdgcn_mfma_f32_16x16x32_f16(a, *(const f16x8*)(wb + (nt0 + 1) * 2048), acc1, 0, 0, 0);
            }
            {
                const float* bb1p = made_bb1 + blk * 128;
                float bi0 = bb1p[(nt0 + 0) * 16 + lr];
                float bi1 = bb1p[(nt0 + 1) * 16 + lr];
                #pragma unroll
                for (int r = 0; r < 4; ++r) {
                    uS[lqw * 4 + r][(nt0 + 0) * 16 + lr] = (f16)fmaxf(acc0[r] + bi0, 0.f);
                    uS[lqw * 4 + r][(nt0 + 1) * 16 + lr] = (f16)fmaxf(acc1[r] + bi1, 0.f);
                }
            }
            __syncthreads();
            acc0 = vzero; acc1 = vzero;
            const f16* w2 = mW2f + (size_t)blk * 16384;
            #pragma unroll
            for (int ks = 0; ks < 4; ++ks) {
                f16x8 a = *(const f16x8*)&uS[lr][ks * 32 + lqw * 8];
                const f16* wb = w2 + (ks * 64 + l) * 8;
                acc0 = __builtin_amdgcn_mfma_f32_16x16x32_f16(a, *(const f16x8*)(wb + (nt0 + 0) * 2048), acc0, 0, 0, 0);
                acc1 = __builtin_amdgcn_mfma_f32_16x16x32_f16(a, *(const f16x8*)(wb + (nt0 + 1) * 2048), acc1, 0, 0, 0);
            }
            {
                const float* bb2p = made_bb2 + blk * 128;
                float bi0 = bb2p[(nt0 + 0) * 16 + lr];
                float bi1 = bb2p[(nt0 + 1) * 16 + lr];
                float g0 = (float)cb[128 + blk * 128 + (nt0 + 0) * 16 + lr];
                float g1 = (float)cb[128 + blk * 128 + (nt0 + 1) * 16 + lr];
                #pragma unroll
                for (int r = 0; r < 4; ++r) {
                    tReg[0][r] += (acc0[r] + bi0) * g0;
                    tReg[1][r] += (acc1[r] + bi1) * g1;
                    tS[lqw * 4 + r][(nt0 + 0) * 16 + lr] =
                        (blk == 0) ? (f16)fmaxf(tReg[0][r], 0.f) : (f16)tReg[0][r];
                    tS[lqw * 4 + r][(nt0 + 1) * 16 + lr] =
                        (blk == 0) ? (f16)fmaxf(tReg[1][r], 0.f) : (f16)tReg[1][r];
                }
            }
            __syncthreads();
        }
        if (w < 2) {
            f32x4 po = vzero;
            #pragma unroll
            for (int ks = 0; ks < 4; ++ks) {
                f16x8 a = *(const f16x8*)&tS[lr][ks * 32 + lqw * 8];
                f16x8 b = *(const f16x8*)(mWoutf + (ks * 64 + l) * 8 + w * 2048);
                po = __builtin_amdgcn_mfma_f32_16x16x32_f16(a, b, po, 0, 0, 0);
            }
            int n = w * 16 + lr;
            float bias = made_bout[n];
            #pragma unroll
            for (int r = 0; r < 4; ++r)
                pS[lqw * 4 + r][n] = (f16)(po[r] + bias);
        }
    }
    __syncthreads();
    // ---- Gaussian head ----
    {
        const int rw = tid >> 4, d = tid & 15;
        const int gm = m0 + rw, hw = gm >> 2, b = gm & 3;
        float ar0 = (float)pS[rw][2 * d];
        float ar1 = (float)pS[rw][2 * d + 1];
        float s = softplusf(ar0) + 0.001f;
        float zn = s * zO[rw][d] + ar1;
        float ls   = ehw[(size_t)hw * 32 + 16 + d];
        float mean = ehw[(size_t)hw * 32 + d];
        float diff = (zn - mean) * expf(-ls);
        float g = logf(s) - ls - 0.5f * diff * diff;
        g += __shfl_xor(g, 1);
        g += __shfl_xor(g, 2);
        g += __shfl_xor(g, 4);
        g += __shfl_xor(g, 8);
        if (d == 0)
            out[(size_t)b * NHW + hw] = lqS[rw] + g - 14.703016531274762f;
    }
}

extern "C" void kernel_launch(void* const* d_in, const int* in_sizes, int n_in,
                              void* d_out, int out_size, void* d_ws, size_t ws_size,
                              hipStream_t stream) {
    (void)in_sizes; (void)n_in; (void)out_size; (void)ws_size;
    const float* x         = (const float*)d_in[0];
    const float* made_W0   = (const float*)d_in[1];
    const float* made_b0   = (const float*)d_in[2];
    const float* made_ctxW = (const float*)d_in[3];
    const float* made_ctxb = (const float*)d_in[4];
    const float* made_bW1  = (const float*)d_in[5];
    const float* made_bb1  = (const float*)d_in[6];
    const float* made_bW2  = (const float*)d_in[7];
    const float* made_bb2  = (const float*)d_in[8];
    const float* made_bCW  = (const float*)d_in[9];
    const float* made_bCb  = (const float*)d_in[10];
    const float* made_Wout = (const float*)d_in[11];
    const float* made_bout = (const float*)d_in[12];
    const float* sp_Win    = (const float*)d_in[13];
    const float* sp_bin    = (const float*)d_in[14];
    const float* sp_bW1    = (const float*)d_in[15];
    const float* sp_bb1    = (const float*)d_in[16];
    const float* sp_bW2    = (const float*)d_in[17];
    const float* sp_bb2    = (const float*)d_in[18];
    const float* sp_bCW    = (const float*)d_in[19];
    const float* sp_bCb    = (const float*)d_in[20];
    const float* sp_Wout   = (const float*)d_in[21];
    const float* sp_bout   = (const float*)d_in[22];
    const float* sp_uw     = (const float*)d_in[23];
    const float* sp_uh     = (const float*)d_in[24];
    const float* sp_ud     = (const float*)d_in[25];
    const float* lu_lower  = (const float*)d_in[26];
    const float* lu_upper  = (const float*)d_in[27];
    const float* lu_udiag  = (const float*)d_in[28];
    const float* lu_bias   = (const float*)d_in[29];
    const int*   lu_perm   = (const int*)d_in[30];
    const float* enc_W1    = (const float*)d_in[31];
    const float* enc_b1    = (const float*)d_in[32];
    const float* enc_W2    = (const float*)d_in[33];
    const float* enc_b2    = (const float*)d_in[34];
    float* out = (float*)d_out;

    float* ws      = (float*)d_ws;
    float* ctx     = ws;                               // 9216*128 f32
    float* z       = ctx     + (size_t)NHW * 128;      // 36864*16
    float* thw_enc = z       + (size_t)NROWS * 16;     // 9216*128
    float* ehw     = thw_enc + (size_t)NHW * 128;      // 9216*32
    float* cpb     = ehw     + (size_t)NHW * 32;       // 5*384
    float* idk     = cpb     + 5 * 384;                // 4*8*48
    float* beff    = idk     + 1536;                   // 4*128
    float* luc     = beff    + 512;                    // 1 (pad 16)
    f16*   ctxoutf = (f16*)(luc + 16);                 // 5*9216*384 f16
    f16*   fW1f    = ctxoutf + (size_t)5 * NHW * 384;  // 8*16384
    f16*   fW2f    = fW1f    + 8 * 16384;              // 8*16384
    f16*   mW1f    = fW2f    + 8 * 16384;              // 2*16384
    f16*   mW2f    = mW1f    + 2 * 16384;              // 2*16384
    f16*   fWoutf  = mW2f    + 2 * 16384;              // 4*24576
    f16*   mWoutf  = fWoutf  + 4 * 24576;              // 4096
    f16*   weffF   = mWoutf  + 4096;                   // 4*4096
    f16*   mlutF   = weffF   + 4 * 4096;               // 4*512
    f16*   minf    = mlutF   + 4 * 512;                // 4096
    f16*   cfrag   = minf    + 4096;                   // 5*49152

    dim3 B(256);
    pack_kernel<<<dim3(960, 9), B, 0, stream>>>(
        sp_bW1, sp_bW2, made_bW1, made_bW2, sp_Wout, made_Wout, sp_Win, made_W0,
        sp_bCW, made_ctxW, made_bCW, sp_bin, sp_bCb, made_ctxb, made_b0, made_bCb,
        fW1f, fW2f, mW1f, mW2f, fWoutf, mWoutf, minf, cfrag, cpb);
    ctx_kernel<<<4608, B, 0, stream>>>(ctx);
    snorm_kernel<<<2304, B, 0, stream>>>(x, z);
    prep_kernel<<<1, 256, 0, stream>>>(sp_uw, sp_uh, sp_ud, sp_Win, lu_lower, lu_upper,
                                       lu_udiag, lu_perm, idk, weffF, mlutF, beff, luc);
    beff_kernel<<<2, B, 0, stream>>>(sp_Win, lu_bias, beff);

    // ctx-dependent precomputes
    ctx_mfma<<<dim3(576, 5), B, 0, stream>>>(ctx, cfrag, cpb, ctxoutf);
    gemm_k<2><<<dim3(144, 2), B, 0, stream>>>(ctx, 128, enc_W1, 128, enc_b1, thw_enc, 128, NHW, 128, 128);
    gemm_k<0><<<dim3(144, 1), B, 0, stream>>>(thw_enc, 128, enc_W2, 128, enc_b2, ehw, 32, NHW, 32, 128);

    // merged pipeline (LU folded into input MFMA)
    mega_all<<<2304, B, 0, stream>>>(z, ctxoutf, weffF, mlutF, beff, minf,
                                     fW1f, fW2f, mW1f, mW2f, fWoutf, mWoutf,
                                     sp_bb1, sp_bb2, made_bb1, made_bb2,
                                     sp_bout, made_bout,
                                     lu_bias, idk, luc, ehw, out);
}

// Round 12
// 307.087 us; speedup vs baseline: 1.2033x; 1.1195x over previous
//
#include <hip/hip_runtime.h>
#include <math.h>

#define NHW   9216     // 96*96
#define NROWS 36864    // NHW*4

typedef _Float16 f16;
typedef _Float16 f16x8 __attribute__((ext_vector_type(8)));
typedef float    f32x4 __attribute__((ext_vector_type(4)));

__device__ __forceinline__ float softplusf(float x) {
    return fmaxf(x, 0.f) + log1pf(expf(-fabsf(x)));
}

// Barrier that drains only LDS ops (lgkmcnt) — global loads into private VGPRs
// stay in flight across it. All cross-wave communication in mega_all is via LDS,
// so this is safe; it is the CDNA analog of cp.async-style counted waits (T4).
__device__ __forceinline__ void barrier_lgkm() {
    __builtin_amdgcn_sched_barrier(0);
    asm volatile("s_waitcnt lgkmcnt(0)" ::: "memory");
    __builtin_amdgcn_s_barrier();
    __builtin_amdgcn_sched_barrier(0);
}

// ---------------- positional encoding ctx[hw][128] ----------------
__global__ __launch_bounds__(256) void ctx_kernel(float* __restrict__ ctx) {
    int e = blockIdx.x * 256 + threadIdx.x;
    if (e >= NHW * 128) return;
    int c  = e & 127;
    int hw = e >> 7;
    int i = hw / 96, j = hw % 96;
    int pos = (c < 64) ? i : j;
    int cc = c & 63;
    int k = cc >> 1;
    float invf = exp2f((float)k * -0.4152410118609203f);  // 10000^(-k/32)
    float v = (float)pos * invf;
    ctx[e] = (cc & 1) ? cosf(v) : sinf(v);
}

// ---------------- spatial_norm -> z[row][16], row = (i*96+j)*4+b ----------------
__global__ __launch_bounds__(256) void snorm_kernel(const float* __restrict__ x,
                                                    float* __restrict__ z) {
    int e = blockIdx.x * 256 + threadIdx.x;
    if (e >= NROWS * 16) return;
    int j = e % 96;
    int i = (e / 96) % 96;
    int s = (e / 9216) % 16;
    int b = e / (9216 * 16);
    float sum = 0.f;
    const float* xb = x + (size_t)((b * 16 + s) * 3) * 192 * 192;
    #pragma unroll
    for (int c = 0; c < 3; ++c) {
        const float* xc = xb + (size_t)c * 192 * 192;
        #pragma unroll
        for (int dh = -1; dh <= 1; ++dh) {
            int hh = 2 * i + dh;
            if (hh < 0 || hh >= 192) continue;
            const float* xr = xc + hh * 192;
            #pragma unroll
            for (int dw = -1; dw <= 1; ++dw) {
                int ww = 2 * j + dw;
                if (ww < 0 || ww >= 192) continue;
                float v = xr[ww];
                sum += v * v;
            }
        }
    }
    int row = (i * 96 + j) * 4 + b;
    z[(size_t)row * 16 + s] = sqrtf(sum);
}

// ---------------- knots helper ----------------
__device__ __forceinline__ void knots8(const float* __restrict__ u, float* c, float* w) {
    float mx = u[0];
    #pragma unroll
    for (int k = 1; k < 8; ++k) mx = fmaxf(mx, u[k]);
    float e[8]; float s = 0.f;
    #pragma unroll
    for (int k = 0; k < 8; ++k) { e[k] = expf(u[k] - mx); s += e[k]; }
    float inv = 1.f / s;
    c[0] = -3.f;
    float cum = 0.f;
    #pragma unroll
    for (int k = 0; k < 8; ++k) {
        float v = 0.001f + 0.992f * e[k] * inv;
        cum += v;
        c[k + 1] = cum * 6.f - 3.f;
    }
    c[8] = 3.f;
    #pragma unroll
    for (int k = 0; k < 8; ++k) w[k] = c[k + 1] - c[k];
}

// ---------------- prep: id-knots + LU folding (Weff/MluT frags) + luc ----------------
__global__ __launch_bounds__(256) void prep_kernel(const float* __restrict__ sp_uw,
                                                   const float* __restrict__ sp_uh,
                                                   const float* __restrict__ sp_ud,
                                                   const float* __restrict__ sp_Win,
                                                   const float* __restrict__ lu_lower,
                                                   const float* __restrict__ lu_upper,
                                                   const float* __restrict__ lu_udiag,
                                                   const int*   __restrict__ lu_perm,
                                                   float* __restrict__ idk,
                                                   f16*   __restrict__ weffF,
                                                   f16*   __restrict__ mlutF,
                                                   float* __restrict__ luc) {
    __shared__ float sMlu[4][16][16];
    int t = threadIdx.x;
    if (t < 64) {
        int s = t >> 4, d = t & 15;
        const float* L  = lu_lower + s * 256;
        const float* U  = lu_upper + s * 256;
        const float* ud = lu_udiag + s * 16;
        const int*   pm = lu_perm + s * 16;
        for (int c = 0; c < 16; ++c) {
            float m = 0.f;
            if (c > d)       m += U[d * 16 + c];
            else if (c == d) m += softplusf(ud[d]) + 0.001f;
            for (int e = 0; e < d && e <= c; ++e) {
                float u = (c > e) ? U[e * 16 + c] : (softplusf(ud[e]) + 0.001f);
                m += L[d * 16 + e] * u;
            }
            sMlu[s][d][pm[c]] = m;
        }
    } else if (t < 96) {
        int tt = t - 64;
        int s = tt >> 3, dim = tt & 7;
        float* o = idk + (s * 8 + dim) * 48;
        float c[9], w[8];
        knots8(sp_uw + s * 64 + dim * 8, c, w);
        #pragma unroll
        for (int k = 0; k < 9; ++k) o[k] = c[k];
        #pragma unroll
        for (int k = 0; k < 8; ++k) o[9 + k] = w[k];
        knots8(sp_uh + s * 64 + dim * 8, c, w);
        #pragma unroll
        for (int k = 0; k < 9; ++k) o[17 + k] = c[k];
        #pragma unroll
        for (int k = 0; k < 8; ++k) o[26 + k] = w[k];
        o[34] = 1.f; o[42] = 1.f;
        #pragma unroll
        for (int k = 0; k < 7; ++k) o[35 + k] = 0.001f + softplusf(sp_ud[s * 56 + dim * 7 + k]);
    } else if (t == 96) {
        float c0 = 0.f;
        for (int k = 0; k < 64; ++k)
            c0 += logf(softplusf(lu_udiag[k]) + 0.001f);
        luc[0] = c0;
    }
    __syncthreads();
    // weffF: 4 steps x 4096  (input frags: raw z -> t, Mlu folded, K=32 pad)
    for (int e = t; e < 4 * 4096; e += 256) {
        int s = e >> 12, f = e & 4095;
        int nt = f >> 9, l = (f >> 3) & 63, j = f & 7;
        int n = nt * 16 + (l & 15), k = ((l >> 4) & 3) * 8 + j;
        float v = 0.f;
        if (k < 16) {
            #pragma unroll
            for (int p = 0; p < 8; ++p)
                v += sMlu[s][2 * p][k] * sp_Win[s * 17408 + n * 136 + p];
        }
        weffF[e] = (f16)v;
    }
    // mlutF: 4 x 512  (z_lu = z @ Mlu^T frags)
    for (int e = t; e < 4 * 512; e += 256) {
        int s = e >> 9, f = e & 511;
        int l = f >> 3, j = f & 7;
        int n = l & 15, k = (l >> 4) * 8 + j;
        mlutF[e] = (k < 16) ? (f16)sMlu[s][n][k] : (f16)0.f;
    }
}

// beff[s][n] = sum_p lu_bias[s][2p] * Win[s][n][p]
__global__ __launch_bounds__(256) void beff_kernel(const float* __restrict__ sp_Win,
                                                   const float* __restrict__ lu_bias,
                                                   float* __restrict__ beff) {
    int e = blockIdx.x * 256 + threadIdx.x;
    if (e >= 4 * 128) return;
    int s = e >> 7, n = e & 127;
    float v = 0.f;
    #pragma unroll
    for (int p = 0; p < 8; ++p)
        v += lu_bias[s * 16 + 2 * p] * sp_Win[s * 17408 + n * 136 + p];
    beff[e] = v;
}

// ---------------- one-time weight pack kernel ----------------
__global__ __launch_bounds__(256) void pack_kernel(
    const float* __restrict__ sp_bW1, const float* __restrict__ sp_bW2,
    const float* __restrict__ made_bW1, const float* __restrict__ made_bW2,
    const float* __restrict__ sp_Wout, const float* __restrict__ made_Wout,
    const float* __restrict__ sp_Win, const float* __restrict__ made_W0,
    const float* __restrict__ sp_bCW, const float* __restrict__ made_ctxW,
    const float* __restrict__ made_bCW,
    const float* __restrict__ sp_bin, const float* __restrict__ sp_bCb,
    const float* __restrict__ made_ctxb, const float* __restrict__ made_b0,
    const float* __restrict__ made_bCb,
    f16* __restrict__ fW1f, f16* __restrict__ fW2f,
    f16* __restrict__ mW1f, f16* __restrict__ mW2f,
    f16* __restrict__ fWoutf, f16* __restrict__ mWoutf,
    f16* __restrict__ minf,
    f16* __restrict__ cfrag, float* __restrict__ cpb)
{
    int cat = blockIdx.y;
    int e = blockIdx.x * 256 + threadIdx.x;
    switch (cat) {
    case 0: if (e < 8 * 16384) {
        int mtx = e >> 14, f = e & 16383;
        int nt = f >> 11, ks = (f >> 9) & 3, l = (f >> 3) & 63, j = f & 7;
        int n = nt * 16 + (l & 15), k = ks * 32 + ((l >> 4) & 3) * 8 + j;
        fW1f[e] = (f16)sp_bW1[mtx * 16384 + n * 128 + k];
    } break;
    case 1: if (e < 8 * 16384) {
        int mtx = e >> 14, f = e & 16383;
        int nt = f >> 11, ks = (f >> 9) & 3, l = (f >> 3) & 63, j = f & 7;
        int n = nt * 16 + (l & 15), k = ks * 32 + ((l >> 4) & 3) * 8 + j;
        fW2f[e] = (f16)sp_bW2[mtx * 16384 + n * 128 + k];
    } break;
    case 2: if (e < 2 * 16384) {
        int mtx = e >> 14, f = e & 16383;
        int nt = f >> 11, ks = (f >> 9) & 3, l = (f >> 3) & 63, j = f & 7;
        int n = nt * 16 + (l & 15), k = ks * 32 + ((l >> 4) & 3) * 8 + j;
        mW1f[e] = ((n % 15) >= (k % 15)) ? (f16)made_bW1[mtx * 16384 + n * 128 + k] : (f16)0.f;
    } break;
    case 3: if (e < 2 * 16384) {
        int mtx = e >> 14, f = e & 16383;
        int nt = f >> 11, ks = (f >> 9) & 3, l = (f >> 3) & 63, j = f & 7;
        int n = nt * 16 + (l & 15), k = ks * 32 + ((l >> 4) & 3) * 8 + j;
        mW2f[e] = ((n % 15) >= (k % 15)) ? (f16)made_bW2[mtx * 16384 + n * 128 + k] : (f16)0.f;
    } break;
    case 4: if (e < 4 * 24576) {
        int s = e / 24576, f = e % 24576;
        int nt = f >> 11, ks = (f >> 9) & 3, l = (f >> 3) & 63, j = f & 7;
        int n = nt * 16 + (l & 15), k = ks * 32 + ((l >> 4) & 3) * 8 + j;
        fWoutf[e] = (n < 184) ? (f16)sp_Wout[s * 23552 + n * 128 + k] : (f16)0.f;
    } break;
    case 5: if (e < 4096) {
        int f = e;
        int nt = f >> 11, ks = (f >> 9) & 3, l = (f >> 3) & 63, j = f & 7;
        int n = nt * 16 + (l & 15), k = ks * 32 + ((l >> 4) & 3) * 8 + j;
        mWoutf[e] = (((n & 15) > (k % 15)) && n < 32) ? (f16)made_Wout[n * 128 + k] : (f16)0.f;
    } break;
    case 6: if (e < 4096) {
        int f = e;
        int nt = f >> 9, l = (f >> 3) & 63, j = f & 7;
        int n = nt * 16 + (l & 15), k = ((l >> 4) & 3) * 8 + j;
        minf[e] = (k < 16 && (n % 15) >= k) ? (f16)made_W0[n * 16 + k] : (f16)0.f;
    } break;
    case 7: if (e < 5 * 49152) {
        int s = e / 49152, f = e % 49152;
        int nt = f >> 11, ks = (f >> 9) & 3, l = (f >> 3) & 63, j = f & 7;
        int n = nt * 16 + (l & 15), k = ks * 32 + ((l >> 4) & 3) * 8 + j;
        float v;
        if (s < 4) {
            if (n < 128)      v = sp_Win[s * 17408 + n * 136 + 8 + k];
            else if (n < 256) v = sp_bCW[(size_t)(s * 2 + 0) * 16384 + (n - 128) * 128 + k];
            else              v = sp_bCW[(size_t)(s * 2 + 1) * 16384 + (n - 256) * 128 + k];
        } else {
            if (n < 128)      v = made_ctxW[n * 128 + k];
            else if (n < 256) v = made_bCW[(n - 128) * 128 + k];
            else              v = made_bCW[16384 + (n - 256) * 128 + k];
        }
        cfrag[e] = (f16)v;
    } break;
    case 8: if (e < 5 * 384) {
        int s = e / 384, n = e % 384;
        float v;
        if (s < 4) {
            if (n < 128)      v = sp_bin[s * 128 + n];
            else if (n < 256) v = sp_bCb[(s * 2 + 0) * 128 + (n - 128)];
            else              v = sp_bCb[(s * 2 + 1) * 128 + (n - 256)];
        } else {
            if (n < 128)      v = made_ctxb[n] + made_b0[n];
            else if (n < 256) v = made_bCb[n - 128];
            else              v = made_bCb[128 + (n - 256)];
        }
        cpb[e] = v;
    } break;
    }
}

// ---------------- ctx-chain MFMA: ctxoutf[s][hw][384] (n>=128 sigmoided), f16 ----------------
__global__ __launch_bounds__(256) void ctx_mfma(
    const float* __restrict__ ctx, const f16* __restrict__ cfrag,
    const float* __restrict__ cpb, f16* __restrict__ ctxoutf)
{
    __shared__ alignas(16) f16 cS[16][136];
    const int tid = threadIdx.x, w = tid >> 6, l = tid & 63;
    const int m0 = blockIdx.x * 16;
    const int s  = blockIdx.y;
    const int lr = l & 15, lq = l >> 4;
    #pragma unroll
    for (int it = 0; it < 2; ++it) {
        int e = tid + it * 256;
        int r = e >> 5, c4 = (e & 31) * 4;
        float4 v = *(const float4*)(ctx + (size_t)(m0 + r) * 128 + c4);
        cS[r][c4 + 0] = (f16)v.x; cS[r][c4 + 1] = (f16)v.y;
        cS[r][c4 + 2] = (f16)v.z; cS[r][c4 + 3] = (f16)v.w;
    }
    __syncthreads();
    const f32x4 vzero = {0.f, 0.f, 0.f, 0.f};
    f32x4 acc[6];
    #pragma unroll
    for (int q = 0; q < 6; ++q) acc[q] = vzero;
    const f16* wb = cfrag + (size_t)s * 49152;
    #pragma unroll
    for (int ks = 0; ks < 4; ++ks) {
        f16x8 a = *(const f16x8*)&cS[lr][ks * 32 + lq * 8];
        #pragma unroll
        for (int q = 0; q < 6; ++q) {
            int g = w * 6 + q;
            f16x8 b = *(const f16x8*)(wb + (size_t)((g * 4 + ks) * 64 + l) * 8);
            acc[q] = __builtin_amdgcn_mfma_f32_16x16x32_f16(a, b, acc[q], 0, 0, 0);
        }
    }
    #pragma unroll
    for (int q = 0; q < 6; ++q) {
        int g = w * 6 + q, n = g * 16 + lr;
        float bias = cpb[s * 384 + n];
        #pragma unroll
        for (int r = 0; r < 4; ++r) {
            float val = acc[q][r] + bias;
            if (n >= 128) val = 1.f / (1.f + expf(-val));
            ctxoutf[(size_t)s * NHW * 384 + (size_t)(m0 + lq * 4 + r) * 384 + n] = (f16)val;
        }
    }
}

// ---------------- tiled f32 GEMM (encoder): C = post(A @ W^T + bias) ----------------
template<int POST>   // 0 store, 2 silu
__global__ __launch_bounds__(256) void gemm_k(
    const float* __restrict__ A, int lda,
    const float* __restrict__ W, int ldw,
    const float* __restrict__ bias,
    float* __restrict__ C, int ldc,
    int M, int N, int K)
{
    __shared__ alignas(16) float As[16][68];
    __shared__ alignas(16) float Ws[16][68];
    const int tid = threadIdx.x;
    const int m0 = blockIdx.x * 64;
    const int n0 = blockIdx.y * 64;
    const int tm = (tid >> 4) << 2;
    const int tn = (tid & 15) << 2;
    const int srow = tid >> 2;
    const int skq  = (tid & 3) << 2;

    float acc[4][4] = {{0.f,0.f,0.f,0.f},{0.f,0.f,0.f,0.f},{0.f,0.f,0.f,0.f},{0.f,0.f,0.f,0.f}};

    for (int k0 = 0; k0 < K; k0 += 16) {
        float4 av = *(const float4*)(A + (size_t)(m0 + srow) * lda + k0 + skq);
        As[skq + 0][srow] = av.x; As[skq + 1][srow] = av.y;
        As[skq + 2][srow] = av.z; As[skq + 3][srow] = av.w;
        int wn = n0 + srow;
        float4 wv = make_float4(0.f, 0.f, 0.f, 0.f);
        if (wn < N) wv = *(const float4*)(W + (size_t)wn * ldw + k0 + skq);
        Ws[skq + 0][srow] = wv.x; Ws[skq + 1][srow] = wv.y;
        Ws[skq + 2][srow] = wv.z; Ws[skq + 3][srow] = wv.w;
        __syncthreads();
        #pragma unroll
        for (int kk = 0; kk < 16; ++kk) {
            float4 a4 = *(const float4*)&As[kk][tm];
            float4 w4 = *(const float4*)&Ws[kk][tn];
            float aa[4] = {a4.x, a4.y, a4.z, a4.w};
            float wwv[4] = {w4.x, w4.y, w4.z, w4.w};
            #pragma unroll
            for (int q = 0; q < 4; ++q)
                #pragma unroll
                for (int r = 0; r < 4; ++r)
                    acc[q][r] = fmaf(aa[q], wwv[r], acc[q][r]);
        }
        __syncthreads();
    }
    #pragma unroll
    for (int q = 0; q < 4; ++q) {
        int m = m0 + tm + q;
        #pragma unroll
        for (int r = 0; r < 4; ++r) {
            int n = n0 + tn + r;
            if (n < N) {
                float val = acc[q][r] + bias[n];
                float* cp = C + (size_t)m * ldc + n;
                if (POST == 0) *cp = val;
                else           *cp = val / (1.f + expf(-val));
            }
        }
    }
}

// ---------------- rational-quadratic spline ----------------
__device__ __forceinline__ void rqs_core(float x, const float* cw, const float* wd,
                                         const float* ch, const float* hg, const float* dd,
                                         float& y, float& ld) {
    bool inside = (x >= -3.f) && (x <= 3.f);
    float xc = fminf(fmaxf(x, -3.f), 3.f);
    float cwk = cw[0], wk = wd[0], chk = ch[0], hk = hg[0], d0 = dd[0], d1 = dd[1];
    #pragma unroll
    for (int k = 1; k < 8; ++k) {
        if (xc >= cw[k]) { cwk = cw[k]; wk = wd[k]; chk = ch[k]; hk = hg[k]; d0 = dd[k]; d1 = dd[k + 1]; }
    }
    float dl = hk / wk;
    float th = (xc - cwk) / wk;
    float t1 = th * (1.f - th);
    float den = dl + (d0 + d1 - 2.f * dl) * t1;
    float yy = chk + hk * (dl * th * th + d0 * t1) / den;
    float om = 1.f - th;
    float dnum = dl * dl * (d1 * th * th + 2.f * dl * t1 + d0 * om * om);
    float lld = logf(dnum) - 2.f * logf(den);
    y  = inside ? yy : x;
    ld = inside ? lld : 0.f;
}

__device__ __forceinline__ void rqs1(float x,
                                     const float* __restrict__ uw,
                                     const float* __restrict__ uh,
                                     const float* __restrict__ ud,
                                     float& y, float& ld) {
    float cw[9], wd[8], ch[9], hg[8], dd[9];
    knots8(uw, cw, wd);
    knots8(uh, ch, hg);
    dd[0] = 1.f; dd[8] = 1.f;
    #pragma unroll
    for (int k = 0; k < 7; ++k) dd[k + 1] = 0.001f + softplusf(ud[k]);
    rqs_core(x, cw, wd, ch, hg, dd, y, ld);
}

__device__ __forceinline__ void rqs1_pre(float x, const float* __restrict__ kn,
                                         float& y, float& ld) {
    float cw[9], wd[8], ch[9], hg[8], dd[9];
    #pragma unroll
    for (int k = 0; k < 9; ++k) cw[k] = kn[k];
    #pragma unroll
    for (int k = 0; k < 8; ++k) wd[k] = kn[9 + k];
    #pragma unroll
    for (int k = 0; k < 9; ++k) ch[k] = kn[17 + k];
    #pragma unroll
    for (int k = 0; k < 8; ++k) hg[k] = kn[26 + k];
    #pragma unroll
    for (int k = 0; k < 9; ++k) dd[k] = kn[34 + k];
    rqs_core(x, cw, wd, ch, hg, dd, y, ld);
}

// ---------------- prefetch helpers (frag buffer in registers) ----------------
__device__ __forceinline__ void load8(const f16* __restrict__ w, int nt0, int l,
                                      f16x8 B[8]) {
    #pragma unroll
    for (int q = 0; q < 2; ++q)
        #pragma unroll
        for (int ks = 0; ks < 4; ++ks)
            B[q * 4 + ks] = *(const f16x8*)(w + (nt0 + q) * 2048 + ks * 512 + l * 8);
}

__device__ __forceinline__ void gemm8(const f16 (*__restrict__ S)[136], int lr, int lqw,
                                      const f16x8 B[8], f32x4& a0, f32x4& a1) {
    #pragma unroll
    for (int ks = 0; ks < 4; ++ks) {
        f16x8 a = *(const f16x8*)&S[lr][ks * 32 + lqw * 8];
        a0 = __builtin_amdgcn_mfma_f32_16x16x32_f16(a, B[ks], a0, 0, 0, 0);
        a1 = __builtin_amdgcn_mfma_f32_16x16x32_f16(a, B[4 + ks], a1, 0, 0, 0);
    }
}

// ---------------- merged pipeline: lgkm-only barriers + cross-phase prefetch ----------------
__global__ __launch_bounds__(256) void mega_all(
    const float* __restrict__ zg,
    const f16*  __restrict__ ctxoutf,   // [5][9216][384]
    const f16*  __restrict__ weffF,     // [4][4096]
    const f16*  __restrict__ mlutF,     // [4][512]
    const float* __restrict__ beffv,    // [4][128]
    const f16*  __restrict__ minf,      // [4096]
    const f16*  __restrict__ fW1f,      // [4][2][16384]
    const f16*  __restrict__ fW2f,
    const f16*  __restrict__ mW1f,      // [2][16384]
    const f16*  __restrict__ mW2f,
    const f16*  __restrict__ fWoutf,    // [4][24576]
    const f16*  __restrict__ mWoutf,    // [4096]
    const float* __restrict__ sp_bb1,   // [4][2][128]
    const float* __restrict__ sp_bb2,
    const float* __restrict__ made_bb1, // [2][128]
    const float* __restrict__ made_bb2,
    const float* __restrict__ sp_bout,  // [4][184]
    const float* __restrict__ made_bout,// [32]
    const float* __restrict__ lu_bias,  // [4][16]
    const float* __restrict__ idk,      // [4][8][48]
    const float* __restrict__ luc,      // [1]
    const float* __restrict__ ehw,      // [9216][32]
    float* __restrict__ out)            // [4][9216]
{
    __shared__ alignas(16) f16 tS[16][136];
    __shared__ alignas(16) f16 uS[16][136];
    __shared__ alignas(16) f16 zS[16][32];
    __shared__ alignas(16) f16 pS[16][196];
    __shared__ float zlu[16][17];
    __shared__ float zO[16][17];
    __shared__ float lqS[16];
    const int tid = threadIdx.x;
    const int w   = tid >> 6;
    const int l   = tid & 63;
    const int lr  = l & 15;
    const int lqw = l >> 4;
    const int m0  = blockIdx.x * 16;
    const int hwq = (m0 >> 2) + lqw;
    const int nt0 = w * 2;
    const int r2  = tid >> 4, d2 = tid & 15;
    const f32x4 vzero = {0.f, 0.f, 0.f, 0.f};

    // prologue: stage raw z (f16, K=32 pad), init lqS
    zS[r2][d2] = (f16)zg[(size_t)(m0 + r2) * 16 + d2];
    zS[r2][16 + d2] = (f16)0.f;
    if (tid < 16) lqS[tid] = luc[0];

    // preload step-3 input frags (stay in flight across the barrier)
    f16x8 B[8];
    f16x8 bml;
    B[0] = *(const f16x8*)(weffF + 3 * 4096 + ((nt0 + 0) * 64 + l) * 8);
    B[1] = *(const f16x8*)(weffF + 3 * 4096 + ((nt0 + 1) * 64 + l) * 8);
    bml  = *(const f16x8*)(mlutF + 3 * 512 + l * 8);
    barrier_lgkm();

    for (int i = 3; i >= 0; --i) {
        const f16* cb = ctxoutf + (size_t)i * NHW * 384 + (size_t)hwq * 384;
        float tReg[2][4];
        // ---- IN: t = thw + beff + z@Weff ; wave0 also z_lu ----
        {
            f16x8 a = *(const f16x8*)&zS[lr][lqw * 8];
            if (w == 0) {
                float bl = lu_bias[i * 16 + lr];
                f32x4 c = {bl, bl, bl, bl};
                c = __builtin_amdgcn_mfma_f32_16x16x32_f16(a, bml, c, 0, 0, 0);
                #pragma unroll
                for (int r = 0; r < 4; ++r)
                    zlu[lqw * 4 + r][lr] = c[r];
            }
            #pragma unroll
            for (int t = 0; t < 2; ++t) {
                int n = (nt0 + t) * 16 + lr;
                float ci = (float)cb[n] + beffv[i * 128 + n];
                f32x4 c = {ci, ci, ci, ci};
                c = __builtin_amdgcn_mfma_f32_16x16x32_f16(a, B[t], c, 0, 0, 0);
                #pragma unroll
                for (int r = 0; r < 4; ++r) {
                    tReg[t][r] = c[r];
                    tS[lqw * 4 + r][(nt0 + t) * 16 + lr] = (f16)fmaxf(c[r], 0.f);
                }
            }
            load8(fW1f + (size_t)i * 32768, nt0, l, B);      // prefetch W1 blk0
        }
        barrier_lgkm();
        // ---- W1 blk0 ----
        {
            f32x4 a0 = vzero, a1 = vzero;
            gemm8(tS, lr, lqw, B, a0, a1);
            load8(fW2f + (size_t)i * 32768, nt0, l, B);      // prefetch W2 blk0
            const float* bb1p = sp_bb1 + i * 256;
            float bi0 = bb1p[(nt0 + 0) * 16 + lr];
            float bi1 = bb1p[(nt0 + 1) * 16 + lr];
            #pragma unroll
            for (int r = 0; r < 4; ++r) {
                uS[lqw * 4 + r][(nt0 + 0) * 16 + lr] = (f16)fmaxf(a0[r] + bi0, 0.f);
                uS[lqw * 4 + r][(nt0 + 1) * 16 + lr] = (f16)fmaxf(a1[r] + bi1, 0.f);
            }
        }
        barrier_lgkm();
        // ---- W2 blk0 ----
        {
            f32x4 a0 = vzero, a1 = vzero;
            gemm8(uS, lr, lqw, B, a0, a1);
            load8(fW1f + (size_t)i * 32768 + 16384, nt0, l, B);  // prefetch W1 blk1
            const float* bb2p = sp_bb2 + i * 256;
            float bi0 = bb2p[(nt0 + 0) * 16 + lr];
            float bi1 = bb2p[(nt0 + 1) * 16 + lr];
            float g0 = (float)cb[128 + (nt0 + 0) * 16 + lr];
            float g1 = (float)cb[128 + (nt0 + 1) * 16 + lr];
            #pragma unroll
            for (int r = 0; r < 4; ++r) {
                tReg[0][r] += (a0[r] + bi0) * g0;
                tReg[1][r] += (a1[r] + bi1) * g1;
                tS[lqw * 4 + r][(nt0 + 0) * 16 + lr] = (f16)fmaxf(tReg[0][r], 0.f);
                tS[lqw * 4 + r][(nt0 + 1) * 16 + lr] = (f16)fmaxf(tReg[1][r], 0.f);
            }
        }
        barrier_lgkm();
        // ---- W1 blk1 ----
        {
            f32x4 a0 = vzero, a1 = vzero;
            gemm8(tS, lr, lqw, B, a0, a1);
            load8(fW2f + (size_t)i * 32768 + 16384, nt0, l, B);  // prefetch W2 blk1
            const float* bb1p = sp_bb1 + i * 256 + 128;
            float bi0 = bb1p[(nt0 + 0) * 16 + lr];
            float bi1 = bb1p[(nt0 + 1) * 16 + lr];
            #pragma unroll
            for (int r = 0; r < 4; ++r) {
                uS[lqw * 4 + r][(nt0 + 0) * 16 + lr] = (f16)fmaxf(a0[r] + bi0, 0.f);
                uS[lqw * 4 + r][(nt0 + 1) * 16 + lr] = (f16)fmaxf(a1[r] + bi1, 0.f);
            }
        }
        barrier_lgkm();
        // ---- W2 blk1 ----
        {
            f32x4 a0 = vzero, a1 = vzero;
            gemm8(uS, lr, lqw, B, a0, a1);
            {   // prefetch Wout frags nt = w, w+4
                const f16* wo = fWoutf + (size_t)i * 24576;
                #pragma unroll
                for (int t2 = 0; t2 < 2; ++t2)
                    #pragma unroll
                    for (int ks = 0; ks < 4; ++ks)
                        B[t2 * 4 + ks] = *(const f16x8*)(wo + (w + t2 * 4) * 2048 + ks * 512 + l * 8);
            }
            const float* bb2p = sp_bb2 + i * 256 + 128;
            float bi0 = bb2p[(nt0 + 0) * 16 + lr];
            float bi1 = bb2p[(nt0 + 1) * 16 + lr];
            float g0 = (float)cb[256 + (nt0 + 0) * 16 + lr];
            float g1 = (float)cb[256 + (nt0 + 1) * 16 + lr];
            #pragma unroll
            for (int r = 0; r < 4; ++r) {
                tReg[0][r] += (a0[r] + bi0) * g0;
                tReg[1][r] += (a1[r] + bi1) * g1;
                tS[lqw * 4 + r][(nt0 + 0) * 16 + lr] = (f16)tReg[0][r];
                tS[lqw * 4 + r][(nt0 + 1) * 16 + lr] = (f16)tReg[1][r];
            }
        }
        barrier_lgkm();
        // ---- WOUT -> pS ----
        {
            f32x4 po0 = vzero, po1 = vzero, po2 = vzero;
            const f16* wo = fWoutf + (size_t)i * 24576;
            #pragma unroll
            for (int ks = 0; ks < 4; ++ks) {
                f16x8 a = *(const f16x8*)&tS[lr][ks * 32 + lqw * 8];
                po0 = __builtin_amdgcn_mfma_f32_16x16x32_f16(a, B[ks], po0, 0, 0, 0);
                po1 = __builtin_amdgcn_mfma_f32_16x16x32_f16(a, B[4 + ks], po1, 0, 0, 0);
                f16x8 b2 = *(const f16x8*)(wo + (w + 8) * 2048 + ks * 512 + l * 8);
                po2 = __builtin_amdgcn_mfma_f32_16x16x32_f16(a, b2, po2, 0, 0, 0);
            }
            // prefetch next stage's input frags
            if (i > 0) {
                B[0] = *(const f16x8*)(weffF + (i - 1) * 4096 + ((nt0 + 0) * 64 + l) * 8);
                B[1] = *(const f16x8*)(weffF + (i - 1) * 4096 + ((nt0 + 1) * 64 + l) * 8);
                bml  = *(const f16x8*)(mlutF + (i - 1) * 512 + l * 8);
            } else {
                B[0] = *(const f16x8*)(minf + ((nt0 + 0) * 64 + l) * 8);
                B[1] = *(const f16x8*)(minf + ((nt0 + 1) * 64 + l) * 8);
            }
            const float* bo = sp_bout + i * 184;
            int n0q = (w + 0) * 16 + lr, n1q = (w + 4) * 16 + lr, n2q = (w + 8) * 16 + lr;
            float b0v = bo[n0q], b1v = bo[n1q];
            float b2v = (n2q < 184) ? bo[n2q] : 0.f;
            #pragma unroll
            for (int r = 0; r < 4; ++r) {
                pS[lqw * 4 + r][n0q] = (f16)(po0[r] + b0v);
                pS[lqw * 4 + r][n1q] = (f16)(po1[r] + b1v);
                if (n2q < 184) pS[lqw * 4 + r][n2q] = (f16)(po2[r] + b2v);
            }
        }
        barrier_lgkm();
        // ---- SPLINE ----
        {
            const int task = tid >> 4, rw = tid & 15;
            float y, ldv;
            if (task < 8) {
                const int dim = task;
                const float is = 0.08838834764831845f;
                float uw[8], uh[8], udv[7];
                const f16* pr = &pS[rw][dim * 23];
                #pragma unroll
                for (int k = 0; k < 8; ++k) { uw[k] = (float)pr[k] * is; uh[k] = (float)pr[8 + k] * is; }
                #pragma unroll
                for (int k = 0; k < 7; ++k) udv[k] = (float)pr[16 + k];
                float x = zlu[rw][2 * dim + 1];
                rqs1(x, uw, uh, udv, y, ldv);
                zO[rw][2 * dim + 1] = y;
                zS[rw][2 * dim + 1] = (f16)y;
            } else {
                const int dim = task - 8;
                float x = zlu[rw][2 * dim];
                rqs1_pre(x, idk + i * 384 + dim * 48, y, ldv);
                zO[rw][2 * dim] = y;
                zS[rw][2 * dim] = (f16)y;
            }
            atomicAdd(&lqS[rw], ldv);
        }
        barrier_lgkm();
    }

    // ---- MADE stage (zS holds final z; B[0..1] = minf frags already in flight) ----
    {
        const f16* cb = ctxoutf + (size_t)4 * NHW * 384 + (size_t)hwq * 384;
        float tReg[2][4];
        {
            f16x8 a = *(const f16x8*)&zS[lr][lqw * 8];
            #pragma unroll
            for (int t = 0; t < 2; ++t) {
                float thw = (float)cb[(nt0 + t) * 16 + lr];
                f32x4 c = {thw, thw, thw, thw};
                c = __builtin_amdgcn_mfma_f32_16x16x32_f16(a, B[t], c, 0, 0, 0);
                #pragma unroll
                for (int r = 0; r < 4; ++r) {
                    tReg[t][r] = c[r];
                    tS[lqw * 4 + r][(nt0 + t) * 16 + lr] = (f16)fmaxf(c[r], 0.f);
                }
            }
            load8(mW1f, nt0, l, B);
        }
        barrier_lgkm();
        // W1 blk0
        {
            f32x4 a0 = vzero, a1 = vzero;
            gemm8(tS, lr, lqw, B, a0, a1);
            load8(mW2f, nt0, l, B);
            float bi0 = made_bb1[(nt0 + 0) * 16 + lr];
            float bi1 = made_bb1[(nt0 + 1) * 16 + lr];
            #pragma unroll
            for (int r = 0; r < 4; ++r) {
                uS[lqw * 4 + r][(nt0 + 0) * 16 + lr] = (f16)fmaxf(a0[r] + bi0, 0.f);
                uS[lqw * 4 + r][(nt0 + 1) * 16 + lr] = (f16)fmaxf(a1[r] + bi1, 0.f);
            }
        }
        barrier_lgkm();
        // W2 blk0
        {
            f32x4 a0 = vzero, a1 = vzero;
            gemm8(uS, lr, lqw, B, a0, a1);
            load8(mW1f + 16384, nt0, l, B);
            float bi0 = made_bb2[(nt0 + 0) * 16 + lr];
            float bi1 = made_bb2[(nt0 + 1) * 16 + lr];
            float g0 = (float)cb[128 + (nt0 + 0) * 16 + lr];
            float g1 = (float)cb[128 + (nt0 + 1) * 16 + lr];
            #pragma unroll
            for (int r = 0; r < 4; ++r) {
                tReg[0][r] += (a0[r] + bi0) * g0;
                tReg[1][r] += (a1[r] + bi1) * g1;
                tS[lqw * 4 + r][(nt0 + 0) * 16 + lr] = (f16)fmaxf(tReg[0][r], 0.f);
                tS[lqw * 4 + r][(nt0 + 1) * 16 + lr] = (f16)fmaxf(tReg[1][r], 0.f);
            }
        }
        barrier_lgkm();
        // W1 blk1
        {
            f32x4 a0 = vzero, a1 = vzero;
            gemm8(tS, lr, lqw, B, a0, a1);
            load8(mW2f + 16384, nt0, l, B);
            float bi0 = made_bb1[128 + (nt0 + 0) * 16 + lr];
            float bi1 = made_bb1[128 + (nt0 + 1) * 16 + lr];
            #pragma unroll
            for (int r = 0; r < 4; ++r) {
                uS[lqw * 4 + r][(nt0 + 0) * 16 + lr] = (f16)fmaxf(a0[r] + bi0, 0.f);
                uS[lqw * 4 + r][(nt0 + 1) * 16 + lr] = (f16)fmaxf(a1[r] + bi1, 0.f);
            }
        }
        barrier_lgkm();
        // W2 blk1
        {
            f32x4 a0 = vzero, a1 = vzero;
            gemm8(uS, lr, lqw, B, a0, a1);
            float bi0 = made_bb2[128 + (nt0 + 0) * 16 + lr];
            float bi1 = made_bb2[128 + (nt0 + 1) * 16 + lr];
            float g0 = (float)cb[256 + (nt0 + 0) * 16 + lr];
            float g1 = (float)cb[256 + (nt0 + 1) * 16 + lr];
            #pragma unroll
            for (int r = 0; r < 4; ++r) {
                tReg[0][r] += (a0[r] + bi0) * g0;
                tReg[1][r] += (a1[r] + bi1) * g1;
                tS[lqw * 4 + r][(nt0 + 0) * 16 + lr] = (f16)tReg[0][r];
                tS[lqw * 4 + r][(nt0 + 1) * 16 + lr] = (f16)tReg[1][r];
            }
        }
        barrier_lgkm();
        // MADE Wout (32 cols): waves 0-1
        if (w < 2) {
            f32x4 po = vzero;
            #pragma unroll
            for (int ks = 0; ks < 4; ++ks) {
                f16x8 a = *(const f16x8*)&tS[lr][ks * 32 + lqw * 8];
                f16x8 b = *(const f16x8*)(mWoutf + w * 2048 + ks * 512 + l * 8);
                po = __builtin_amdgcn_mfma_f32_16x16x32_f16(a, b, po, 0, 0, 0);
            }
            int n = w * 16 + lr;
            float bias = made_bout[n];
            #pragma unroll
            for (int r = 0; r < 4; ++r)
                pS[lqw * 4 + r][n] = (f16)(po[r] + bias);
        }
    }
    barrier_lgkm();
    // ---- Gaussian head ----
    {
        const int rw = tid >> 4, d = tid & 15;
        const int gm = m0 + rw, hw = gm >> 2, b = gm & 3;
        float ar0 = (float)pS[rw][2 * d];
        float ar1 = (float)pS[rw][2 * d + 1];
        float s = softplusf(ar0) + 0.001f;
        float zn = s * zO[rw][d] + ar1;
        float ls   = ehw[(size_t)hw * 32 + 16 + d];
        float mean = ehw[(size_t)hw * 32 + d];
        float diff = (zn - mean) * expf(-ls);
        float g = logf(s) - ls - 0.5f * diff * diff;
        g += __shfl_xor(g, 1);
        g += __shfl_xor(g, 2);
        g += __shfl_xor(g, 4);
        g += __shfl_xor(g, 8);
        if (d == 0)
            out[(size_t)b * NHW + hw] = lqS[rw] + g - 14.703016531274762f;
    }
}

extern "C" void kernel_launch(void* const* d_in, const int* in_sizes, int n_in,
                              void* d_out, int out_size, void* d_ws, size_t ws_size,
                              hipStream_t stream) {
    (void)in_sizes; (void)n_in; (void)out_size; (void)ws_size;
    const float* x         = (const float*)d_in[0];
    const float* made_W0   = (const float*)d_in[1];
    const float* made_b0   = (const float*)d_in[2];
    const float* made_ctxW = (const float*)d_in[3];
    const float* made_ctxb = (const float*)d_in[4];
    const float* made_bW1  = (const float*)d_in[5];
    const float* made_bb1  = (const float*)d_in[6];
    const float* made_bW2  = (const float*)d_in[7];
    const float* made_bb2  = (const float*)d_in[8];
    const float* made_bCW  = (const float*)d_in[9];
    const float* made_bCb  = (const float*)d_in[10];
    const float* made_Wout = (const float*)d_in[11];
    const float* made_bout = (const float*)d_in[12];
    const float* sp_Win    = (const float*)d_in[13];
    const float* sp_bin    = (const float*)d_in[14];
    const float* sp_bW1    = (const float*)d_in[15];
    const float* sp_bb1    = (const float*)d_in[16];
    const float* sp_bW2    = (const float*)d_in[17];
    const float* sp_bb2    = (const float*)d_in[18];
    const float* sp_bCW    = (const float*)d_in[19];
    const float* sp_bCb    = (const float*)d_in[20];
    const float* sp_Wout   = (const float*)d_in[21];
    const float* sp_bout   = (const float*)d_in[22];
    const float* sp_uw     = (const float*)d_in[23];
    const float* sp_uh     = (const float*)d_in[24];
    const float* sp_ud     = (const float*)d_in[25];
    const float* lu_lower  = (const float*)d_in[26];
    const float* lu_upper  = (const float*)d_in[27];
    const float* lu_udiag  = (const float*)d_in[28];
    const float* lu_bias   = (const float*)d_in[29];
    const int*   lu_perm   = (const int*)d_in[30];
    const float* enc_W1    = (const float*)d_in[31];
    const float* enc_b1    = (const float*)d_in[32];
    const float* enc_W2    = (const float*)d_in[33];
    const float* enc_b2    = (const float*)d_in[34];
    float* out = (float*)d_out;

    float* ws      = (float*)d_ws;
    float* ctx     = ws;                               // 9216*128 f32
    float* z       = ctx     + (size_t)NHW * 128;      // 36864*16
    float* thw_enc = z       + (size_t)NROWS * 16;     // 9216*128
    float* ehw     = thw_enc + (size_t)NHW * 128;      // 9216*32
    float* cpb     = ehw     + (size_t)NHW * 32;       // 5*384
    float* idk     = cpb     + 5 * 384;                // 4*8*48
    float* beff    = idk     + 1536;                   // 4*128
    float* luc     = beff    + 512;                    // 1 (pad 16)
    f16*   ctxoutf = (f16*)(luc + 16);                 // 5*9216*384 f16
    f16*   fW1f    = ctxoutf + (size_t)5 * NHW * 384;  // 8*16384
    f16*   fW2f    = fW1f    + 8 * 16384;              // 8*16384
    f16*   mW1f    = fW2f    + 8 * 16384;              // 2*16384
    f16*   mW2f    = mW1f    + 2 * 16384;              // 2*16384
    f16*   fWoutf  = mW2f    + 2 * 16384;              // 4*24576
    f16*   mWoutf  = fWoutf  + 4 * 24576;              // 4096
    f16*   weffF   = mWoutf  + 4096;                   // 4*4096
    f16*   mlutF   = weffF   + 4 * 4096;               // 4*512
    f16*   minf    = mlutF   + 4 * 512;                // 4096
    f16*   cfrag   = minf    + 4096;                   // 5*49152

    dim3 B(256);
    pack_kernel<<<dim3(960, 9), B, 0, stream>>>(
        sp_bW1, sp_bW2, made_bW1, made_bW2, sp_Wout, made_Wout, sp_Win, made_W0,
        sp_bCW, made_ctxW, made_bCW, sp_bin, sp_bCb, made_ctxb, made_b0, made_bCb,
        fW1f, fW2f, mW1f, mW2f, fWoutf, mWoutf, minf, cfrag, cpb);
    ctx_kernel<<<4608, B, 0, stream>>>(ctx);
    snorm_kernel<<<2304, B, 0, stream>>>(x, z);
    prep_kernel<<<1, 256, 0, stream>>>(sp_uw, sp_uh, sp_ud, sp_Win, lu_lower, lu_upper,
                                       lu_udiag, lu_perm, idk, weffF, mlutF, luc);
    beff_kernel<<<2, B, 0, stream>>>(sp_Win, lu_bias, beff);

    // ctx-dependent precomputes
    ctx_mfma<<<dim3(576, 5), B, 0, stream>>>(ctx, cfrag, cpb, ctxoutf);
    gemm_k<2><<<dim3(144, 2), B, 0, stream>>>(ctx, 128, enc_W1, 128, enc_b1, thw_enc, 128, NHW, 128, 128);
    gemm_k<0><<<dim3(144, 1), B, 0, stream>>>(thw_enc, 128, enc_W2, 128, enc_b2, ehw, 32, NHW, 32, 128);

    // merged pipeline (lgkm-only barriers + register prefetch)
    mega_all<<<2304, B, 0, stream>>>(z, ctxoutf, weffF, mlutF, beff, minf,
                                     fW1f, fW2f, mW1f, mW2f, fWoutf, mWoutf,
                                     sp_bb1, sp_bb2, made_bb1, made_bb2,
                                     sp_bout, made_bout,
                                     lu_bias, idk, luc, ehw, out);
}

// Round 13
// 279.825 us; speedup vs baseline: 1.3205x; 1.0974x over previous
//
#include <hip/hip_runtime.h>
#include <math.h>

#define NHW   9216     // 96*96
#define NROWS 36864    // NHW*4

typedef _Float16 f16;
typedef _Float16 f16x8 __attribute__((ext_vector_type(8)));
typedef float    f32x4 __attribute__((ext_vector_type(4)));

__device__ __forceinline__ float softplusf(float x) {
    return fmaxf(x, 0.f) + log1pf(expf(-fabsf(x)));
}

// LDS-only barrier: global loads into private VGPRs stay in flight across it.
__device__ __forceinline__ void barrier_lgkm() {
    __builtin_amdgcn_sched_barrier(0);
    asm volatile("s_waitcnt lgkmcnt(0)" ::: "memory");
    __builtin_amdgcn_s_barrier();
    __builtin_amdgcn_sched_barrier(0);
}

// ---------------- positional encoding ctx[hw][128] ----------------
__global__ __launch_bounds__(256) void ctx_kernel(float* __restrict__ ctx) {
    int e = blockIdx.x * 256 + threadIdx.x;
    if (e >= NHW * 128) return;
    int c  = e & 127;
    int hw = e >> 7;
    int i = hw / 96, j = hw % 96;
    int pos = (c < 64) ? i : j;
    int cc = c & 63;
    int k = cc >> 1;
    float invf = exp2f((float)k * -0.4152410118609203f);  // 10000^(-k/32)
    float v = (float)pos * invf;
    ctx[e] = (cc & 1) ? cosf(v) : sinf(v);
}

// ---------------- spatial_norm -> z[row][16], row = (i*96+j)*4+b ----------------
__global__ __launch_bounds__(256) void snorm_kernel(const float* __restrict__ x,
                                                    float* __restrict__ z) {
    int e = blockIdx.x * 256 + threadIdx.x;
    if (e >= NROWS * 16) return;
    int j = e % 96;
    int i = (e / 96) % 96;
    int s = (e / 9216) % 16;
    int b = e / (9216 * 16);
    float sum = 0.f;
    const float* xb = x + (size_t)((b * 16 + s) * 3) * 192 * 192;
    #pragma unroll
    for (int c = 0; c < 3; ++c) {
        const float* xc = xb + (size_t)c * 192 * 192;
        #pragma unroll
        for (int dh = -1; dh <= 1; ++dh) {
            int hh = 2 * i + dh;
            if (hh < 0 || hh >= 192) continue;
            const float* xr = xc + hh * 192;
            #pragma unroll
            for (int dw = -1; dw <= 1; ++dw) {
                int ww = 2 * j + dw;
                if (ww < 0 || ww >= 192) continue;
                float v = xr[ww];
                sum += v * v;
            }
        }
    }
    int row = (i * 96 + j) * 4 + b;
    z[(size_t)row * 16 + s] = sqrtf(sum);
}

// ---------------- knots helper ----------------
__device__ __forceinline__ void knots8(const float* __restrict__ u, float* c, float* w) {
    float mx = u[0];
    #pragma unroll
    for (int k = 1; k < 8; ++k) mx = fmaxf(mx, u[k]);
    float e[8]; float s = 0.f;
    #pragma unroll
    for (int k = 0; k < 8; ++k) { e[k] = expf(u[k] - mx); s += e[k]; }
    float inv = 1.f / s;
    c[0] = -3.f;
    float cum = 0.f;
    #pragma unroll
    for (int k = 0; k < 8; ++k) {
        float v = 0.001f + 0.992f * e[k] * inv;
        cum += v;
        c[k + 1] = cum * 6.f - 3.f;
    }
    c[8] = 3.f;
    #pragma unroll
    for (int k = 0; k < 8; ++k) w[k] = c[k + 1] - c[k];
}

// ---------------- prep: id-knots + LU folding (Weff/MluT frags) + luc ----------------
__global__ __launch_bounds__(256) void prep_kernel(const float* __restrict__ sp_uw,
                                                   const float* __restrict__ sp_uh,
                                                   const float* __restrict__ sp_ud,
                                                   const float* __restrict__ sp_Win,
                                                   const float* __restrict__ lu_lower,
                                                   const float* __restrict__ lu_upper,
                                                   const float* __restrict__ lu_udiag,
                                                   const int*   __restrict__ lu_perm,
                                                   float* __restrict__ idk,
                                                   f16*   __restrict__ weffF,
                                                   f16*   __restrict__ mlutF,
                                                   float* __restrict__ luc) {
    __shared__ float sMlu[4][16][16];
    int t = threadIdx.x;
    if (t < 64) {
        int s = t >> 4, d = t & 15;
        const float* L  = lu_lower + s * 256;
        const float* U  = lu_upper + s * 256;
        const float* ud = lu_udiag + s * 16;
        const int*   pm = lu_perm + s * 16;
        for (int c = 0; c < 16; ++c) {
            float m = 0.f;
            if (c > d)       m += U[d * 16 + c];
            else if (c == d) m += softplusf(ud[d]) + 0.001f;
            for (int e = 0; e < d && e <= c; ++e) {
                float u = (c > e) ? U[e * 16 + c] : (softplusf(ud[e]) + 0.001f);
                m += L[d * 16 + e] * u;
            }
            sMlu[s][d][pm[c]] = m;
        }
    } else if (t < 96) {
        int tt = t - 64;
        int s = tt >> 3, dim = tt & 7;
        float* o = idk + (s * 8 + dim) * 48;
        float c[9], w[8];
        knots8(sp_uw + s * 64 + dim * 8, c, w);
        #pragma unroll
        for (int k = 0; k < 9; ++k) o[k] = c[k];
        #pragma unroll
        for (int k = 0; k < 8; ++k) o[9 + k] = w[k];
        knots8(sp_uh + s * 64 + dim * 8, c, w);
        #pragma unroll
        for (int k = 0; k < 9; ++k) o[17 + k] = c[k];
        #pragma unroll
        for (int k = 0; k < 8; ++k) o[26 + k] = w[k];
        o[34] = 1.f; o[42] = 1.f;
        #pragma unroll
        for (int k = 0; k < 7; ++k) o[35 + k] = 0.001f + softplusf(sp_ud[s * 56 + dim * 7 + k]);
    } else if (t == 96) {
        float c0 = 0.f;
        for (int k = 0; k < 64; ++k)
            c0 += logf(softplusf(lu_udiag[k]) + 0.001f);
        luc[0] = c0;
    }
    __syncthreads();
    for (int e = t; e < 4 * 4096; e += 256) {
        int s = e >> 12, f = e & 4095;
        int nt = f >> 9, l = (f >> 3) & 63, j = f & 7;
        int n = nt * 16 + (l & 15), k = ((l >> 4) & 3) * 8 + j;
        float v = 0.f;
        if (k < 16) {
            #pragma unroll
            for (int p = 0; p < 8; ++p)
                v += sMlu[s][2 * p][k] * sp_Win[s * 17408 + n * 136 + p];
        }
        weffF[e] = (f16)v;
    }
    for (int e = t; e < 4 * 512; e += 256) {
        int s = e >> 9, f = e & 511;
        int l = f >> 3, j = f & 7;
        int n = l & 15, k = (l >> 4) * 8 + j;
        mlutF[e] = (k < 16) ? (f16)sMlu[s][n][k] : (f16)0.f;
    }
}

// beff[s][n] = sum_p lu_bias[s][2p] * Win[s][n][p]
__global__ __launch_bounds__(256) void beff_kernel(const float* __restrict__ sp_Win,
                                                   const float* __restrict__ lu_bias,
                                                   float* __restrict__ beff) {
    int e = blockIdx.x * 256 + threadIdx.x;
    if (e >= 4 * 128) return;
    int s = e >> 7, n = e & 127;
    float v = 0.f;
    #pragma unroll
    for (int p = 0; p < 8; ++p)
        v += lu_bias[s * 16 + 2 * p] * sp_Win[s * 17408 + n * 136 + p];
    beff[e] = v;
}

// ---------------- one-time weight pack kernel ----------------
__global__ __launch_bounds__(256) void pack_kernel(
    const float* __restrict__ sp_bW1, const float* __restrict__ sp_bW2,
    const float* __restrict__ made_bW1, const float* __restrict__ made_bW2,
    const float* __restrict__ sp_Wout, const float* __restrict__ made_Wout,
    const float* __restrict__ sp_Win, const float* __restrict__ made_W0,
    const float* __restrict__ sp_bCW, const float* __restrict__ made_ctxW,
    const float* __restrict__ made_bCW,
    const float* __restrict__ sp_bin, const float* __restrict__ sp_bCb,
    const float* __restrict__ made_ctxb, const float* __restrict__ made_b0,
    const float* __restrict__ made_bCb,
    const float* __restrict__ enc_W1, const float* __restrict__ enc_b1,
    const float* __restrict__ enc_W2, const float* __restrict__ enc_b2,
    f16* __restrict__ fW1f, f16* __restrict__ fW2f,
    f16* __restrict__ mW1f, f16* __restrict__ mW2f,
    f16* __restrict__ fWoutf, f16* __restrict__ mWoutf,
    f16* __restrict__ minf,
    f16* __restrict__ cfrag, float* __restrict__ cpb,
    f16* __restrict__ encW1f, f16* __restrict__ encW2f, float* __restrict__ epb)
{
    int cat = blockIdx.y;
    int e = blockIdx.x * 256 + threadIdx.x;
    switch (cat) {
    case 0: if (e < 8 * 16384) {
        int mtx = e >> 14, f = e & 16383;
        int nt = f >> 11, ks = (f >> 9) & 3, l = (f >> 3) & 63, j = f & 7;
        int n = nt * 16 + (l & 15), k = ks * 32 + ((l >> 4) & 3) * 8 + j;
        fW1f[e] = (f16)sp_bW1[mtx * 16384 + n * 128 + k];
    } break;
    case 1: if (e < 8 * 16384) {
        int mtx = e >> 14, f = e & 16383;
        int nt = f >> 11, ks = (f >> 9) & 3, l = (f >> 3) & 63, j = f & 7;
        int n = nt * 16 + (l & 15), k = ks * 32 + ((l >> 4) & 3) * 8 + j;
        fW2f[e] = (f16)sp_bW2[mtx * 16384 + n * 128 + k];
    } break;
    case 2: if (e < 2 * 16384) {
        int mtx = e >> 14, f = e & 16383;
        int nt = f >> 11, ks = (f >> 9) & 3, l = (f >> 3) & 63, j = f & 7;
        int n = nt * 16 + (l & 15), k = ks * 32 + ((l >> 4) & 3) * 8 + j;
        mW1f[e] = ((n % 15) >= (k % 15)) ? (f16)made_bW1[mtx * 16384 + n * 128 + k] : (f16)0.f;
    } break;
    case 3: if (e < 2 * 16384) {
        int mtx = e >> 14, f = e & 16383;
        int nt = f >> 11, ks = (f >> 9) & 3, l = (f >> 3) & 63, j = f & 7;
        int n = nt * 16 + (l & 15), k = ks * 32 + ((l >> 4) & 3) * 8 + j;
        mW2f[e] = ((n % 15) >= (k % 15)) ? (f16)made_bW2[mtx * 16384 + n * 128 + k] : (f16)0.f;
    } break;
    case 4: if (e < 4 * 24576) {
        int s = e / 24576, f = e % 24576;
        int nt = f >> 11, ks = (f >> 9) & 3, l = (f >> 3) & 63, j = f & 7;
        int n = nt * 16 + (l & 15), k = ks * 32 + ((l >> 4) & 3) * 8 + j;
        fWoutf[e] = (n < 184) ? (f16)sp_Wout[s * 23552 + n * 128 + k] : (f16)0.f;
    } break;
    case 5: if (e < 4096) {
        int f = e;
        int nt = f >> 11, ks = (f >> 9) & 3, l = (f >> 3) & 63, j = f & 7;
        int n = nt * 16 + (l & 15), k = ks * 32 + ((l >> 4) & 3) * 8 + j;
        mWoutf[e] = (((n & 15) > (k % 15)) && n < 32) ? (f16)made_Wout[n * 128 + k] : (f16)0.f;
    } break;
    case 6: if (e < 4096) {
        int f = e;
        int nt = f >> 9, l = (f >> 3) & 63, j = f & 7;
        int n = nt * 16 + (l & 15), k = ((l >> 4) & 3) * 8 + j;
        minf[e] = (k < 16 && (n % 15) >= k) ? (f16)made_W0[n * 16 + k] : (f16)0.f;
    } break;
    case 7: if (e < 5 * 49152) {
        int s = e / 49152, f = e % 49152;
        int nt = f >> 11, ks = (f >> 9) & 3, l = (f >> 3) & 63, j = f & 7;
        int n = nt * 16 + (l & 15), k = ks * 32 + ((l >> 4) & 3) * 8 + j;
        float v;
        if (s < 4) {
            if (n < 128)      v = sp_Win[s * 17408 + n * 136 + 8 + k];
            else if (n < 256) v = sp_bCW[(size_t)(s * 2 + 0) * 16384 + (n - 128) * 128 + k];
            else              v = sp_bCW[(size_t)(s * 2 + 1) * 16384 + (n - 256) * 128 + k];
        } else {
            if (n < 128)      v = made_ctxW[n * 128 + k];
            else if (n < 256) v = made_bCW[(n - 128) * 128 + k];
            else              v = made_bCW[16384 + (n - 256) * 128 + k];
        }
        cfrag[e] = (f16)v;
    } break;
    case 8: if (e < 5 * 384) {
        int s = e / 384, n = e % 384;
        float v;
        if (s < 4) {
            if (n < 128)      v = sp_bin[s * 128 + n];
            else if (n < 256) v = sp_bCb[(s * 2 + 0) * 128 + (n - 128)];
            else              v = sp_bCb[(s * 2 + 1) * 128 + (n - 256)];
        } else {
            if (n < 128)      v = made_ctxb[n] + made_b0[n];
            else if (n < 256) v = made_bCb[n - 128];
            else              v = made_bCb[128 + (n - 256)];
        }
        cpb[e] = v;
    } break;
    case 9: if (e < 16384) {
        int f = e;
        int nt = f >> 11, ks = (f >> 9) & 3, l = (f >> 3) & 63, j = f & 7;
        int n = nt * 16 + (l & 15), k = ks * 32 + ((l >> 4) & 3) * 8 + j;
        encW1f[e] = (f16)enc_W1[n * 128 + k];
    } break;
    case 10: if (e < 4096) {
        int f = e;
        int nt = f >> 11, ks = (f >> 9) & 3, l = (f >> 3) & 63, j = f & 7;
        int n = nt * 16 + (l & 15), k = ks * 32 + ((l >> 4) & 3) * 8 + j;
        encW2f[e] = (n < 32) ? (f16)enc_W2[n * 128 + k] : (f16)0.f;
    } break;
    case 11: if (e < 160) {
        epb[e] = (e < 128) ? enc_b1[e] : enc_b2[e - 128];
    } break;
    }
}

// ---------------- ctx-chain MFMA (s<5) + fused encoder (s==5) ----------------
__global__ __launch_bounds__(256) void ctx_mfma(
    const float* __restrict__ ctx, const f16* __restrict__ cfrag,
    const float* __restrict__ cpb,
    const f16* __restrict__ encW1f, const f16* __restrict__ encW2f,
    const float* __restrict__ epb,
    f16* __restrict__ ctxoutf, float* __restrict__ ehw)
{
    __shared__ alignas(16) f16 cS[16][136];
    __shared__ alignas(16) f16 hS[16][136];
    const int tid = threadIdx.x, w = tid >> 6, l = tid & 63;
    const int m0 = blockIdx.x * 16;
    const int s  = blockIdx.y;
    const int lr = l & 15, lq = l >> 4;
    #pragma unroll
    for (int it = 0; it < 2; ++it) {
        int e = tid + it * 256;
        int r = e >> 5, c4 = (e & 31) * 4;
        float4 v = *(const float4*)(ctx + (size_t)(m0 + r) * 128 + c4);
        cS[r][c4 + 0] = (f16)v.x; cS[r][c4 + 1] = (f16)v.y;
        cS[r][c4 + 2] = (f16)v.z; cS[r][c4 + 3] = (f16)v.w;
    }
    __syncthreads();
    const f32x4 vzero = {0.f, 0.f, 0.f, 0.f};
    if (s == 5) {
        // encoder: h = silu(ctx@W1+b1); ehw = h@W2+b2
        f32x4 acc0 = vzero, acc1 = vzero;
        #pragma unroll
        for (int ks = 0; ks < 4; ++ks) {
            f16x8 a = *(const f16x8*)&cS[lr][ks * 32 + lq * 8];
            f16x8 b0 = *(const f16x8*)(encW1f + (((w * 2 + 0) * 4 + ks) * 64 + l) * 8);
            f16x8 b1 = *(const f16x8*)(encW1f + (((w * 2 + 1) * 4 + ks) * 64 + l) * 8);
            acc0 = __builtin_amdgcn_mfma_f32_16x16x32_f16(a, b0, acc0, 0, 0, 0);
            acc1 = __builtin_amdgcn_mfma_f32_16x16x32_f16(a, b1, acc1, 0, 0, 0);
        }
        {
            int n0 = (w * 2 + 0) * 16 + lr, n1 = (w * 2 + 1) * 16 + lr;
            float bi0 = epb[n0], bi1 = epb[n1];
            #pragma unroll
            for (int r = 0; r < 4; ++r) {
                float v0 = acc0[r] + bi0, v1 = acc1[r] + bi1;
                hS[lq * 4 + r][n0] = (f16)(v0 / (1.f + expf(-v0)));
                hS[lq * 4 + r][n1] = (f16)(v1 / (1.f + expf(-v1)));
            }
        }
        __syncthreads();
        if (w < 2) {
            f32x4 po = vzero;
            #pragma unroll
            for (int ks = 0; ks < 4; ++ks) {
                f16x8 a = *(const f16x8*)&hS[lr][ks * 32 + lq * 8];
                f16x8 b = *(const f16x8*)(encW2f + ((w * 4 + ks) * 64 + l) * 8);
                po = __builtin_amdgcn_mfma_f32_16x16x32_f16(a, b, po, 0, 0, 0);
            }
            int n = w * 16 + lr;
            float bias = epb[128 + n];
            #pragma unroll
            for (int r = 0; r < 4; ++r)
                ehw[(size_t)(m0 + lq * 4 + r) * 32 + n] = po[r] + bias;
        }
        return;
    }
    f32x4 acc[6];
    #pragma unroll
    for (int q = 0; q < 6; ++q) acc[q] = vzero;
    const f16* wb = cfrag + (size_t)s * 49152;
    #pragma unroll
    for (int ks = 0; ks < 4; ++ks) {
        f16x8 a = *(const f16x8*)&cS[lr][ks * 32 + lq * 8];
        #pragma unroll
        for (int q = 0; q < 6; ++q) {
            int g = w * 6 + q;
            f16x8 b = *(const f16x8*)(wb + (size_t)((g * 4 + ks) * 64 + l) * 8);
            acc[q] = __builtin_amdgcn_mfma_f32_16x16x32_f16(a, b, acc[q], 0, 0, 0);
        }
    }
    #pragma unroll
    for (int q = 0; q < 6; ++q) {
        int g = w * 6 + q, n = g * 16 + lr;
        float bias = cpb[s * 384 + n];
        #pragma unroll
        for (int r = 0; r < 4; ++r) {
            float val = acc[q][r] + bias;
            if (n >= 128) val = 1.f / (1.f + expf(-val));
            ctxoutf[(size_t)s * NHW * 384 + (size_t)(m0 + lq * 4 + r) * 384 + n] = (f16)val;
        }
    }
}

// ---------------- rational-quadratic spline ----------------
__device__ __forceinline__ void rqs_core(float x, const float* cw, const float* wd,
                                         const float* ch, const float* hg, const float* dd,
                                         float& y, float& ld) {
    bool inside = (x >= -3.f) && (x <= 3.f);
    float xc = fminf(fmaxf(x, -3.f), 3.f);
    float cwk = cw[0], wk = wd[0], chk = ch[0], hk = hg[0], d0 = dd[0], d1 = dd[1];
    #pragma unroll
    for (int k = 1; k < 8; ++k) {
        if (xc >= cw[k]) { cwk = cw[k]; wk = wd[k]; chk = ch[k]; hk = hg[k]; d0 = dd[k]; d1 = dd[k + 1]; }
    }
    float dl = hk / wk;
    float th = (xc - cwk) / wk;
    float t1 = th * (1.f - th);
    float den = dl + (d0 + d1 - 2.f * dl) * t1;
    float yy = chk + hk * (dl * th * th + d0 * t1) / den;
    float om = 1.f - th;
    float dnum = dl * dl * (d1 * th * th + 2.f * dl * t1 + d0 * om * om);
    float lld = logf(dnum) - 2.f * logf(den);
    y  = inside ? yy : x;
    ld = inside ? lld : 0.f;
}

__device__ __forceinline__ void rqs1(float x,
                                     const float* __restrict__ uw,
                                     const float* __restrict__ uh,
                                     const float* __restrict__ ud,
                                     float& y, float& ld) {
    float cw[9], wd[8], ch[9], hg[8], dd[9];
    knots8(uw, cw, wd);
    knots8(uh, ch, hg);
    dd[0] = 1.f; dd[8] = 1.f;
    #pragma unroll
    for (int k = 0; k < 7; ++k) dd[k + 1] = 0.001f + softplusf(ud[k]);
    rqs_core(x, cw, wd, ch, hg, dd, y, ld);
}

__device__ __forceinline__ void rqs1_pre(float x, const float* __restrict__ kn,
                                         float& y, float& ld) {
    float cw[9], wd[8], ch[9], hg[8], dd[9];
    #pragma unroll
    for (int k = 0; k < 9; ++k) cw[k] = kn[k];
    #pragma unroll
    for (int k = 0; k < 8; ++k) wd[k] = kn[9 + k];
    #pragma unroll
    for (int k = 0; k < 9; ++k) ch[k] = kn[17 + k];
    #pragma unroll
    for (int k = 0; k < 8; ++k) hg[k] = kn[26 + k];
    #pragma unroll
    for (int k = 0; k < 9; ++k) dd[k] = kn[34 + k];
    rqs_core(x, cw, wd, ch, hg, dd, y, ld);
}

// ---------------- prefetch helpers ----------------
__device__ __forceinline__ void load8(const f16* __restrict__ w, int nt0, int l,
                                      f16x8 B[8]) {
    #pragma unroll
    for (int q = 0; q < 2; ++q)
        #pragma unroll
        for (int ks = 0; ks < 4; ++ks)
            B[q * 4 + ks] = *(const f16x8*)(w + (nt0 + q) * 2048 + ks * 512 + l * 8);
}

__device__ __forceinline__ void gemm8(const f16 (*__restrict__ S)[136], int lr, int lqw,
                                      const f16x8 B[8], f32x4& a0, f32x4& a1) {
    #pragma unroll
    for (int ks = 0; ks < 4; ++ks) {
        f16x8 a = *(const f16x8*)&S[lr][ks * 32 + lqw * 8];
        a0 = __builtin_amdgcn_mfma_f32_16x16x32_f16(a, B[ks], a0, 0, 0, 0);
        a1 = __builtin_amdgcn_mfma_f32_16x16x32_f16(a, B[4 + ks], a1, 0, 0, 0);
    }
}

// ---------------- merged pipeline: lgkm barriers + prefetch + hoisted scalars ----------------
__global__ __launch_bounds__(256) void mega_all(
    const float* __restrict__ zg,
    const f16*  __restrict__ ctxoutf,   // [5][9216][384]
    const f16*  __restrict__ weffF,     // [4][4096]
    const f16*  __restrict__ mlutF,     // [4][512]
    const float* __restrict__ beffv,    // [4][128]
    const f16*  __restrict__ minf,      // [4096]
    const f16*  __restrict__ fW1f,      // [4][2][16384]
    const f16*  __restrict__ fW2f,
    const f16*  __restrict__ mW1f,      // [2][16384]
    const f16*  __restrict__ mW2f,
    const f16*  __restrict__ fWoutf,    // [4][24576]
    const f16*  __restrict__ mWoutf,    // [4096]
    const float* __restrict__ sp_bb1,   // [4][2][128]
    const float* __restrict__ sp_bb2,
    const float* __restrict__ made_bb1, // [2][128]
    const float* __restrict__ made_bb2,
    const float* __restrict__ sp_bout,  // [4][184]
    const float* __restrict__ made_bout,// [32]
    const float* __restrict__ lu_bias,  // [4][16]
    const float* __restrict__ idk,      // [4][8][48]
    const float* __restrict__ luc,      // [1]
    const float* __restrict__ ehw,      // [9216][32]
    float* __restrict__ out)            // [4][9216]
{
    __shared__ alignas(16) f16 tS[16][136];
    __shared__ alignas(16) f16 uS[16][136];
    __shared__ alignas(16) f16 zS[16][32];
    __shared__ alignas(16) f16 pS[16][196];
    __shared__ float zlu[16][17];
    __shared__ float zO[16][17];
    __shared__ float lqS[16];
    const int tid = threadIdx.x;
    const int w   = tid >> 6;
    const int l   = tid & 63;
    const int lr  = l & 15;
    const int lqw = l >> 4;
    const int m0  = blockIdx.x * 16;
    const int hwq = (m0 >> 2) + lqw;
    const int nt0 = w * 2;
    const int r2  = tid >> 4, d2 = tid & 15;
    const f32x4 vzero = {0.f, 0.f, 0.f, 0.f};

    zS[r2][d2] = (f16)zg[(size_t)(m0 + r2) * 16 + d2];
    zS[r2][16 + d2] = (f16)0.f;
    if (tid < 16) lqS[tid] = luc[0];

    f16x8 B[8];
    f16x8 bml;
    B[0] = *(const f16x8*)(weffF + 3 * 4096 + ((nt0 + 0) * 64 + l) * 8);
    B[1] = *(const f16x8*)(weffF + 3 * 4096 + ((nt0 + 1) * 64 + l) * 8);
    bml  = *(const f16x8*)(mlutF + 3 * 512 + l * 8);
    barrier_lgkm();

    const int n0q = (w + 0) * 16 + lr, n1q = (w + 4) * 16 + lr, n2q = (w + 8) * 16 + lr;

    for (int i = 3; i >= 0; --i) {
        const f16* cb = ctxoutf + (size_t)i * NHW * 384 + (size_t)hwq * 384;
        float tReg[2][4];
        // ---- hoist per-step scalars (long lead before use) ----
        float g10 = (float)cb[128 + (nt0 + 0) * 16 + lr];
        float g11 = (float)cb[128 + (nt0 + 1) * 16 + lr];
        float g20 = (float)cb[256 + (nt0 + 0) * 16 + lr];
        float g21 = (float)cb[256 + (nt0 + 1) * 16 + lr];
        const float* bb1p = sp_bb1 + i * 256;
        const float* bb2p = sp_bb2 + i * 256;
        float bi10 = bb1p[(nt0 + 0) * 16 + lr], bi11 = bb1p[(nt0 + 1) * 16 + lr];
        float bi20 = bb2p[(nt0 + 0) * 16 + lr], bi21 = bb2p[(nt0 + 1) * 16 + lr];
        float bi30 = bb1p[128 + (nt0 + 0) * 16 + lr], bi31 = bb1p[128 + (nt0 + 1) * 16 + lr];
        float bi40 = bb2p[128 + (nt0 + 0) * 16 + lr], bi41 = bb2p[128 + (nt0 + 1) * 16 + lr];
        const float* bo = sp_bout + i * 184;
        float b0v = bo[n0q], b1v = bo[n1q];
        float b2v = (n2q < 184) ? bo[n2q] : 0.f;
        // ---- IN: t = thw + beff + z@Weff ; wave0 also z_lu ----
        {
            f16x8 a = *(const f16x8*)&zS[lr][lqw * 8];
            if (w == 0) {
                float bl = lu_bias[i * 16 + lr];
                f32x4 c = {bl, bl, bl, bl};
                c = __builtin_amdgcn_mfma_f32_16x16x32_f16(a, bml, c, 0, 0, 0);
                #pragma unroll
                for (int r = 0; r < 4; ++r)
                    zlu[lqw * 4 + r][lr] = c[r];
            }
            #pragma unroll
            for (int t = 0; t < 2; ++t) {
                int n = (nt0 + t) * 16 + lr;
                float ci = (float)cb[n] + beffv[i * 128 + n];
                f32x4 c = {ci, ci, ci, ci};
                c = __builtin_amdgcn_mfma_f32_16x16x32_f16(a, B[t], c, 0, 0, 0);
                #pragma unroll
                for (int r = 0; r < 4; ++r) {
                    tReg[t][r] = c[r];
                    tS[lqw * 4 + r][(nt0 + t) * 16 + lr] = (f16)fmaxf(c[r], 0.f);
                }
            }
            load8(fW1f + (size_t)i * 32768, nt0, l, B);
        }
        barrier_lgkm();
        // ---- W1 blk0 ----
        {
            f32x4 a0 = vzero, a1 = vzero;
            gemm8(tS, lr, lqw, B, a0, a1);
            load8(fW2f + (size_t)i * 32768, nt0, l, B);
            #pragma unroll
            for (int r = 0; r < 4; ++r) {
                uS[lqw * 4 + r][(nt0 + 0) * 16 + lr] = (f16)fmaxf(a0[r] + bi10, 0.f);
                uS[lqw * 4 + r][(nt0 + 1) * 16 + lr] = (f16)fmaxf(a1[r] + bi11, 0.f);
            }
        }
        barrier_lgkm();
        // ---- W2 blk0 ----
        {
            f32x4 a0 = vzero, a1 = vzero;
            gemm8(uS, lr, lqw, B, a0, a1);
            load8(fW1f + (size_t)i * 32768 + 16384, nt0, l, B);
            #pragma unroll
            for (int r = 0; r < 4; ++r) {
                tReg[0][r] += (a0[r] + bi20) * g10;
                tReg[1][r] += (a1[r] + bi21) * g11;
                tS[lqw * 4 + r][(nt0 + 0) * 16 + lr] = (f16)fmaxf(tReg[0][r], 0.f);
                tS[lqw * 4 + r][(nt0 + 1) * 16 + lr] = (f16)fmaxf(tReg[1][r], 0.f);
            }
        }
        barrier_lgkm();
        // ---- W1 blk1 ----
        {
            f32x4 a0 = vzero, a1 = vzero;
            gemm8(tS, lr, lqw, B, a0, a1);
            load8(fW2f + (size_t)i * 32768 + 16384, nt0, l, B);
            #pragma unroll
            for (int r = 0; r < 4; ++r) {
                uS[lqw * 4 + r][(nt0 + 0) * 16 + lr] = (f16)fmaxf(a0[r] + bi30, 0.f);
                uS[lqw * 4 + r][(nt0 + 1) * 16 + lr] = (f16)fmaxf(a1[r] + bi31, 0.f);
            }
        }
        barrier_lgkm();
        // ---- W2 blk1 ----
        {
            f32x4 a0 = vzero, a1 = vzero;
            gemm8(uS, lr, lqw, B, a0, a1);
            {   // prefetch Wout frags nt = w, w+4
                const f16* wo = fWoutf + (size_t)i * 24576;
                #pragma unroll
                for (int t2 = 0; t2 < 2; ++t2)
                    #pragma unroll
                    for (int ks = 0; ks < 4; ++ks)
                        B[t2 * 4 + ks] = *(const f16x8*)(wo + (w + t2 * 4) * 2048 + ks * 512 + l * 8);
            }
            #pragma unroll
            for (int r = 0; r < 4; ++r) {
                tReg[0][r] += (a0[r] + bi40) * g20;
                tReg[1][r] += (a1[r] + bi41) * g21;
                tS[lqw * 4 + r][(nt0 + 0) * 16 + lr] = (f16)tReg[0][r];
                tS[lqw * 4 + r][(nt0 + 1) * 16 + lr] = (f16)tReg[1][r];
            }
        }
        barrier_lgkm();
        // ---- WOUT -> pS ----
        {
            f32x4 po0 = vzero, po1 = vzero, po2 = vzero;
            const f16* wo = fWoutf + (size_t)i * 24576;
            #pragma unroll
            for (int ks = 0; ks < 4; ++ks) {
                f16x8 a = *(const f16x8*)&tS[lr][ks * 32 + lqw * 8];
                po0 = __builtin_amdgcn_mfma_f32_16x16x32_f16(a, B[ks], po0, 0, 0, 0);
                po1 = __builtin_amdgcn_mfma_f32_16x16x32_f16(a, B[4 + ks], po1, 0, 0, 0);
                f16x8 b2 = *(const f16x8*)(wo + (w + 8) * 2048 + ks * 512 + l * 8);
                po2 = __builtin_amdgcn_mfma_f32_16x16x32_f16(a, b2, po2, 0, 0, 0);
            }
            if (i > 0) {
                B[0] = *(const f16x8*)(weffF + (i - 1) * 4096 + ((nt0 + 0) * 64 + l) * 8);
                B[1] = *(const f16x8*)(weffF + (i - 1) * 4096 + ((nt0 + 1) * 64 + l) * 8);
                bml  = *(const f16x8*)(mlutF + (i - 1) * 512 + l * 8);
            } else {
                B[0] = *(const f16x8*)(minf + ((nt0 + 0) * 64 + l) * 8);
                B[1] = *(const f16x8*)(minf + ((nt0 + 1) * 64 + l) * 8);
            }
            #pragma unroll
            for (int r = 0; r < 4; ++r) {
                pS[lqw * 4 + r][n0q] = (f16)(po0[r] + b0v);
                pS[lqw * 4 + r][n1q] = (f16)(po1[r] + b1v);
                if (n2q < 184) pS[lqw * 4 + r][n2q] = (f16)(po2[r] + b2v);
            }
        }
        barrier_lgkm();
        // ---- SPLINE ----
        {
            const int task = tid >> 4, rw = tid & 15;
            float y, ldv;
            if (task < 8) {
                const int dim = task;
                const float is = 0.08838834764831845f;
                float uw[8], uh[8], udv[7];
                const f16* pr = &pS[rw][dim * 23];
                #pragma unroll
                for (int k = 0; k < 8; ++k) { uw[k] = (float)pr[k] * is; uh[k] = (float)pr[8 + k] * is; }
                #pragma unroll
                for (int k = 0; k < 7; ++k) udv[k] = (float)pr[16 + k];
                float x = zlu[rw][2 * dim + 1];
                rqs1(x, uw, uh, udv, y, ldv);
                zO[rw][2 * dim + 1] = y;
                zS[rw][2 * dim + 1] = (f16)y;
            } else {
                const int dim = task - 8;
                float x = zlu[rw][2 * dim];
                rqs1_pre(x, idk + i * 384 + dim * 48, y, ldv);
                zO[rw][2 * dim] = y;
                zS[rw][2 * dim] = (f16)y;
            }
            atomicAdd(&lqS[rw], ldv);
        }
        barrier_lgkm();
    }

    // ---- MADE stage ----
    {
        const f16* cb = ctxoutf + (size_t)4 * NHW * 384 + (size_t)hwq * 384;
        float tReg[2][4];
        // hoisted scalars
        float g10 = (float)cb[128 + (nt0 + 0) * 16 + lr];
        float g11 = (float)cb[128 + (nt0 + 1) * 16 + lr];
        float g20 = (float)cb[256 + (nt0 + 0) * 16 + lr];
        float g21 = (float)cb[256 + (nt0 + 1) * 16 + lr];
        float bi10 = made_bb1[(nt0 + 0) * 16 + lr], bi11 = made_bb1[(nt0 + 1) * 16 + lr];
        float bi20 = made_bb2[(nt0 + 0) * 16 + lr], bi21 = made_bb2[(nt0 + 1) * 16 + lr];
        float bi30 = made_bb1[128 + (nt0 + 0) * 16 + lr], bi31 = made_bb1[128 + (nt0 + 1) * 16 + lr];
        float bi40 = made_bb2[128 + (nt0 + 0) * 16 + lr], bi41 = made_bb2[128 + (nt0 + 1) * 16 + lr];
        {
            f16x8 a = *(const f16x8*)&zS[lr][lqw * 8];
            #pragma unroll
            for (int t = 0; t < 2; ++t) {
                float thw = (float)cb[(nt0 + t) * 16 + lr];
                f32x4 c = {thw, thw, thw, thw};
                c = __builtin_amdgcn_mfma_f32_16x16x32_f16(a, B[t], c, 0, 0, 0);
                #pragma unroll
                for (int r = 0; r < 4; ++r) {
                    tReg[t][r] = c[r];
                    tS[lqw * 4 + r][(nt0 + t) * 16 + lr] = (f16)fmaxf(c[r], 0.f);
                }
            }
            load8(mW1f, nt0, l, B);
        }
        barrier_lgkm();
        {
            f32x4 a0 = vzero, a1 = vzero;
            gemm8(tS, lr, lqw, B, a0, a1);
            load8(mW2f, nt0, l, B);
            #pragma unroll
            for (int r = 0; r < 4; ++r) {
                uS[lqw * 4 + r][(nt0 + 0) * 16 + lr] = (f16)fmaxf(a0[r] + bi10, 0.f);
                uS[lqw * 4 + r][(nt0 + 1) * 16 + lr] = (f16)fmaxf(a1[r] + bi11, 0.f);
            }
        }
        barrier_lgkm();
        {
            f32x4 a0 = vzero, a1 = vzero;
            gemm8(uS, lr, lqw, B, a0, a1);
            load8(mW1f + 16384, nt0, l, B);
            #pragma unroll
            for (int r = 0; r < 4; ++r) {
                tReg[0][r] += (a0[r] + bi20) * g10;
                tReg[1][r] += (a1[r] + bi21) * g11;
                tS[lqw * 4 + r][(nt0 + 0) * 16 + lr] = (f16)fmaxf(tReg[0][r], 0.f);
                tS[lqw * 4 + r][(nt0 + 1) * 16 + lr] = (f16)fmaxf(tReg[1][r], 0.f);
            }
        }
        barrier_lgkm();
        {
            f32x4 a0 = vzero, a1 = vzero;
            gemm8(tS, lr, lqw, B, a0, a1);
            load8(mW2f + 16384, nt0, l, B);
            #pragma unroll
            for (int r = 0; r < 4; ++r) {
                uS[lqw * 4 + r][(nt0 + 0) * 16 + lr] = (f16)fmaxf(a0[r] + bi30, 0.f);
                uS[lqw * 4 + r][(nt0 + 1) * 16 + lr] = (f16)fmaxf(a1[r] + bi31, 0.f);
            }
        }
        barrier_lgkm();
        {
            f32x4 a0 = vzero, a1 = vzero;
            gemm8(uS, lr, lqw, B, a0, a1);
            #pragma unroll
            for (int r = 0; r < 4; ++r) {
                tReg[0][r] += (a0[r] + bi40) * g20;
                tReg[1][r] += (a1[r] + bi41) * g21;
                tS[lqw * 4 + r][(nt0 + 0) * 16 + lr] = (f16)tReg[0][r];
                tS[lqw * 4 + r][(nt0 + 1) * 16 + lr] = (f16)tReg[1][r];
            }
        }
        barrier_lgkm();
        if (w < 2) {
            f32x4 po = vzero;
            #pragma unroll
            for (int ks = 0; ks < 4; ++ks) {
                f16x8 a = *(const f16x8*)&tS[lr][ks * 32 + lqw * 8];
                f16x8 b = *(const f16x8*)(mWoutf + w * 2048 + ks * 512 + l * 8);
                po = __builtin_amdgcn_mfma_f32_16x16x32_f16(a, b, po, 0, 0, 0);
            }
            int n = w * 16 + lr;
            float bias = made_bout[n];
            #pragma unroll
            for (int r = 0; r < 4; ++r)
                pS[lqw * 4 + r][n] = (f16)(po[r] + bias);
        }
    }
    barrier_lgkm();
    // ---- Gaussian head ----
    {
        const int rw = tid >> 4, d = tid & 15;
        const int gm = m0 + rw, hw = gm >> 2, b = gm & 3;
        float ar0 = (float)pS[rw][2 * d];
        float ar1 = (float)pS[rw][2 * d + 1];
        float s = softplusf(ar0) + 0.001f;
        float zn = s * zO[rw][d] + ar1;
        float ls   = ehw[(size_t)hw * 32 + 16 + d];
        float mean = ehw[(size_t)hw * 32 + d];
        float diff = (zn - mean) * expf(-ls);
        float g = logf(s) - ls - 0.5f * diff * diff;
        g += __shfl_xor(g, 1);
        g += __shfl_xor(g, 2);
        g += __shfl_xor(g, 4);
        g += __shfl_xor(g, 8);
        if (d == 0)
            out[(size_t)b * NHW + hw] = lqS[rw] + g - 14.703016531274762f;
    }
}

extern "C" void kernel_launch(void* const* d_in, const int* in_sizes, int n_in,
                              void* d_out, int out_size, void* d_ws, size_t ws_size,
                              hipStream_t stream) {
    (void)in_sizes; (void)n_in; (void)out_size; (void)ws_size;
    const float* x         = (const float*)d_in[0];
    const float* made_W0   = (const float*)d_in[1];
    const float* made_b0   = (const float*)d_in[2];
    const float* made_ctxW = (const float*)d_in[3];
    const float* made_ctxb = (const float*)d_in[4];
    const float* made_bW1  = (const float*)d_in[5];
    const float* made_bb1  = (const float*)d_in[6];
    const float* made_bW2  = (const float*)d_in[7];
    const float* made_bb2  = (const float*)d_in[8];
    const float* made_bCW  = (const float*)d_in[9];
    const float* made_bCb  = (const float*)d_in[10];
    const float* made_Wout = (const float*)d_in[11];
    const float* made_bout = (const float*)d_in[12];
    const float* sp_Win    = (const float*)d_in[13];
    const float* sp_bin    = (const float*)d_in[14];
    const float* sp_bW1    = (const float*)d_in[15];
    const float* sp_bb1    = (const float*)d_in[16];
    const float* sp_bW2    = (const float*)d_in[17];
    const float* sp_bb2    = (const float*)d_in[18];
    const float* sp_bCW    = (const float*)d_in[19];
    const float* sp_bCb    = (const float*)d_in[20];
    const float* sp_Wout   = (const float*)d_in[21];
    const float* sp_bout   = (const float*)d_in[22];
    const float* sp_uw     = (const float*)d_in[23];
    const float* sp_uh     = (const float*)d_in[24];
    const float* sp_ud     = (const float*)d_in[25];
    const float* lu_lower  = (const float*)d_in[26];
    const float* lu_upper  = (const float*)d_in[27];
    const float* lu_udiag  = (const float*)d_in[28];
    const float* lu_bias   = (const float*)d_in[29];
    const int*   lu_perm   = (const int*)d_in[30];
    const float* enc_W1    = (const float*)d_in[31];
    const float* enc_b1    = (const float*)d_in[32];
    const float* enc_W2    = (const float*)d_in[33];
    const float* enc_b2    = (const float*)d_in[34];
    float* out = (float*)d_out;

    float* ws      = (float*)d_ws;
    float* ctx     = ws;                               // 9216*128 f32
    float* z       = ctx     + (size_t)NHW * 128;      // 36864*16
    float* ehw     = z       + (size_t)NROWS * 16;     // 9216*32
    float* cpb     = ehw     + (size_t)NHW * 32;       // 5*384
    float* epb     = cpb     + 5 * 384;                // 160 (pad 192)
    float* idk     = epb     + 192;                    // 4*8*48
    float* beff    = idk     + 1536;                   // 4*128
    float* luc     = beff    + 512;                    // 1 (pad 16)
    f16*   ctxoutf = (f16*)(luc + 16);                 // 5*9216*384 f16
    f16*   fW1f    = ctxoutf + (size_t)5 * NHW * 384;  // 8*16384
    f16*   fW2f    = fW1f    + 8 * 16384;              // 8*16384
    f16*   mW1f    = fW2f    + 8 * 16384;              // 2*16384
    f16*   mW2f    = mW1f    + 2 * 16384;              // 2*16384
    f16*   fWoutf  = mW2f    + 2 * 16384;              // 4*24576
    f16*   mWoutf  = fWoutf  + 4 * 24576;              // 4096
    f16*   weffF   = mWoutf  + 4096;                   // 4*4096
    f16*   mlutF   = weffF   + 4 * 4096;               // 4*512
    f16*   minf    = mlutF   + 4 * 512;                // 4096
    f16*   encW1f  = minf    + 4096;                   // 16384
    f16*   encW2f  = encW1f  + 16384;                  // 4096
    f16*   cfrag   = encW2f  + 4096;                   // 5*49152

    dim3 B(256);
    pack_kernel<<<dim3(960, 12), B, 0, stream>>>(
        sp_bW1, sp_bW2, made_bW1, made_bW2, sp_Wout, made_Wout, sp_Win, made_W0,
        sp_bCW, made_ctxW, made_bCW, sp_bin, sp_bCb, made_ctxb, made_b0, made_bCb,
        enc_W1, enc_b1, enc_W2, enc_b2,
        fW1f, fW2f, mW1f, mW2f, fWoutf, mWoutf, minf, cfrag, cpb,
        encW1f, encW2f, epb);
    ctx_kernel<<<4608, B, 0, stream>>>(ctx);
    snorm_kernel<<<2304, B, 0, stream>>>(x, z);
    prep_kernel<<<1, 256, 0, stream>>>(sp_uw, sp_uh, sp_ud, sp_Win, lu_lower, lu_upper,
                                       lu_udiag, lu_perm, idk, weffF, mlutF, luc);
    beff_kernel<<<2, B, 0, stream>>>(sp_Win, lu_bias, beff);

    // ctx-dependent precomputes (encoder fused as slice 5)
    ctx_mfma<<<dim3(576, 6), B, 0, stream>>>(ctx, cfrag, cpb, encW1f, encW2f, epb,
                                             ctxoutf, ehw);

    // merged pipeline
    mega_all<<<2304, B, 0, stream>>>(z, ctxoutf, weffF, mlutF, beff, minf,
                                     fW1f, fW2f, mW1f, mW2f, fWoutf, mWoutf,
                                     sp_bb1, sp_bb2, made_bb1, made_bb2,
                                     sp_bout, made_bout,
                                     lu_bias, idk, luc, ehw, out);
}

// Round 14
// 273.257 us; speedup vs baseline: 1.3522x; 1.0240x over previous
//
#include <hip/hip_runtime.h>
#include <math.h>

#define NHW   9216     // 96*96
#define NROWS 36864    // NHW*4

typedef _Float16 f16;
typedef _Float16 f16x8 __attribute__((ext_vector_type(8)));
typedef float    f32x4 __attribute__((ext_vector_type(4)));

__device__ __forceinline__ float softplusf(float x) {
    return fmaxf(x, 0.f) + log1pf(expf(-fabsf(x)));
}

// LDS-only barrier: global loads into private VGPRs stay in flight across it.
__device__ __forceinline__ void barrier_lgkm() {
    __builtin_amdgcn_sched_barrier(0);
    asm volatile("s_waitcnt lgkmcnt(0)" ::: "memory");
    __builtin_amdgcn_s_barrier();
    __builtin_amdgcn_sched_barrier(0);
}

// ---------------- spatial_norm -> z[row][16], row = (i*96+j)*4+b ----------------
__global__ __launch_bounds__(256) void snorm_kernel(const float* __restrict__ x,
                                                    float* __restrict__ z) {
    int e = blockIdx.x * 256 + threadIdx.x;
    if (e >= NROWS * 16) return;
    int j = e % 96;
    int i = (e / 96) % 96;
    int s = (e / 9216) % 16;
    int b = e / (9216 * 16);
    float sum = 0.f;
    const float* xb = x + (size_t)((b * 16 + s) * 3) * 192 * 192;
    #pragma unroll
    for (int c = 0; c < 3; ++c) {
        const float* xc = xb + (size_t)c * 192 * 192;
        #pragma unroll
        for (int dh = -1; dh <= 1; ++dh) {
            int hh = 2 * i + dh;
            if (hh < 0 || hh >= 192) continue;
            const float* xr = xc + hh * 192;
            #pragma unroll
            for (int dw = -1; dw <= 1; ++dw) {
                int ww = 2 * j + dw;
                if (ww < 0 || ww >= 192) continue;
                float v = xr[ww];
                sum += v * v;
            }
        }
    }
    int row = (i * 96 + j) * 4 + b;
    z[(size_t)row * 16 + s] = sqrtf(sum);
}

// ---------------- knots helper ----------------
__device__ __forceinline__ void knots8(const float* __restrict__ u, float* c, float* w) {
    float mx = u[0];
    #pragma unroll
    for (int k = 1; k < 8; ++k) mx = fmaxf(mx, u[k]);
    float e[8]; float s = 0.f;
    #pragma unroll
    for (int k = 0; k < 8; ++k) { e[k] = expf(u[k] - mx); s += e[k]; }
    float inv = 1.f / s;
    c[0] = -3.f;
    float cum = 0.f;
    #pragma unroll
    for (int k = 0; k < 8; ++k) {
        float v = 0.001f + 0.992f * e[k] * inv;
        cum += v;
        c[k + 1] = cum * 6.f - 3.f;
    }
    c[8] = 3.f;
    #pragma unroll
    for (int k = 0; k < 8; ++k) w[k] = c[k + 1] - c[k];
}

// ---------------- prep: id-knots + LU folding (Weff/MluT frags) + beff + luc ----------------
__global__ __launch_bounds__(256) void prep_kernel(const float* __restrict__ sp_uw,
                                                   const float* __restrict__ sp_uh,
                                                   const float* __restrict__ sp_ud,
                                                   const float* __restrict__ sp_Win,
                                                   const float* __restrict__ lu_lower,
                                                   const float* __restrict__ lu_upper,
                                                   const float* __restrict__ lu_udiag,
                                                   const float* __restrict__ lu_bias,
                                                   const int*   __restrict__ lu_perm,
                                                   float* __restrict__ idk,
                                                   f16*   __restrict__ weffF,
                                                   f16*   __restrict__ mlutF,
                                                   float* __restrict__ beff,
                                                   float* __restrict__ luc) {
    __shared__ float sMlu[4][16][16];
    int t = threadIdx.x;
    if (t < 64) {
        int s = t >> 4, d = t & 15;
        const float* L  = lu_lower + s * 256;
        const float* U  = lu_upper + s * 256;
        const float* ud = lu_udiag + s * 16;
        const int*   pm = lu_perm + s * 16;
        for (int c = 0; c < 16; ++c) {
            float m = 0.f;
            if (c > d)       m += U[d * 16 + c];
            else if (c == d) m += softplusf(ud[d]) + 0.001f;
            for (int e = 0; e < d && e <= c; ++e) {
                float u = (c > e) ? U[e * 16 + c] : (softplusf(ud[e]) + 0.001f);
                m += L[d * 16 + e] * u;
            }
            sMlu[s][d][pm[c]] = m;
        }
    } else if (t < 96) {
        int tt = t - 64;
        int s = tt >> 3, dim = tt & 7;
        float* o = idk + (s * 8 + dim) * 48;
        float c[9], w[8];
        knots8(sp_uw + s * 64 + dim * 8, c, w);
        #pragma unroll
        for (int k = 0; k < 9; ++k) o[k] = c[k];
        #pragma unroll
        for (int k = 0; k < 8; ++k) o[9 + k] = w[k];
        knots8(sp_uh + s * 64 + dim * 8, c, w);
        #pragma unroll
        for (int k = 0; k < 9; ++k) o[17 + k] = c[k];
        #pragma unroll
        for (int k = 0; k < 8; ++k) o[26 + k] = w[k];
        o[34] = 1.f; o[42] = 1.f;
        #pragma unroll
        for (int k = 0; k < 7; ++k) o[35 + k] = 0.001f + softplusf(sp_ud[s * 56 + dim * 7 + k]);
    } else if (t == 96) {
        float c0 = 0.f;
        for (int k = 0; k < 64; ++k)
            c0 += logf(softplusf(lu_udiag[k]) + 0.001f);
        luc[0] = c0;
    }
    __syncthreads();
    for (int e = t; e < 4 * 4096; e += 256) {
        int s = e >> 12, f = e & 4095;
        int nt = f >> 9, l = (f >> 3) & 63, j = f & 7;
        int n = nt * 16 + (l & 15), k = ((l >> 4) & 3) * 8 + j;
        float v = 0.f;
        if (k < 16) {
            #pragma unroll
            for (int p = 0; p < 8; ++p)
                v += sMlu[s][2 * p][k] * sp_Win[s * 17408 + n * 136 + p];
        }
        weffF[e] = (f16)v;
    }
    for (int e = t; e < 4 * 512; e += 256) {
        int s = e >> 9, f = e & 511;
        int l = f >> 3, j = f & 7;
        int n = l & 15, k = (l >> 4) * 8 + j;
        mlutF[e] = (k < 16) ? (f16)sMlu[s][n][k] : (f16)0.f;
    }
    for (int e = t; e < 4 * 128; e += 256) {
        int s = e >> 7, n = e & 127;
        float v = 0.f;
        #pragma unroll
        for (int p = 0; p < 8; ++p)
            v += lu_bias[s * 16 + 2 * p] * sp_Win[s * 17408 + n * 136 + p];
        beff[e] = v;
    }
}

// ---------------- one-time weight pack kernel ----------------
__global__ __launch_bounds__(256) void pack_kernel(
    const float* __restrict__ sp_bW1, const float* __restrict__ sp_bW2,
    const float* __restrict__ made_bW1, const float* __restrict__ made_bW2,
    const float* __restrict__ sp_Wout, const float* __restrict__ made_Wout,
    const float* __restrict__ sp_Win, const float* __restrict__ made_W0,
    const float* __restrict__ sp_bCW, const float* __restrict__ made_ctxW,
    const float* __restrict__ made_bCW,
    const float* __restrict__ sp_bin, const float* __restrict__ sp_bCb,
    const float* __restrict__ made_ctxb, const float* __restrict__ made_b0,
    const float* __restrict__ made_bCb,
    const float* __restrict__ enc_W1, const float* __restrict__ enc_b1,
    const float* __restrict__ enc_W2, const float* __restrict__ enc_b2,
    f16* __restrict__ fW1f, f16* __restrict__ fW2f,
    f16* __restrict__ mW1f, f16* __restrict__ mW2f,
    f16* __restrict__ fWoutf, f16* __restrict__ mWoutf,
    f16* __restrict__ minf,
    f16* __restrict__ cfrag, float* __restrict__ cpb,
    f16* __restrict__ encW1f, f16* __restrict__ encW2f, float* __restrict__ epb)
{
    int cat = blockIdx.y;
    int e = blockIdx.x * 256 + threadIdx.x;
    switch (cat) {
    case 0: if (e < 8 * 16384) {
        int mtx = e >> 14, f = e & 16383;
        int nt = f >> 11, ks = (f >> 9) & 3, l = (f >> 3) & 63, j = f & 7;
        int n = nt * 16 + (l & 15), k = ks * 32 + ((l >> 4) & 3) * 8 + j;
        fW1f[e] = (f16)sp_bW1[mtx * 16384 + n * 128 + k];
    } break;
    case 1: if (e < 8 * 16384) {
        int mtx = e >> 14, f = e & 16383;
        int nt = f >> 11, ks = (f >> 9) & 3, l = (f >> 3) & 63, j = f & 7;
        int n = nt * 16 + (l & 15), k = ks * 32 + ((l >> 4) & 3) * 8 + j;
        fW2f[e] = (f16)sp_bW2[mtx * 16384 + n * 128 + k];
    } break;
    case 2: if (e < 2 * 16384) {
        int mtx = e >> 14, f = e & 16383;
        int nt = f >> 11, ks = (f >> 9) & 3, l = (f >> 3) & 63, j = f & 7;
        int n = nt * 16 + (l & 15), k = ks * 32 + ((l >> 4) & 3) * 8 + j;
        mW1f[e] = ((n % 15) >= (k % 15)) ? (f16)made_bW1[mtx * 16384 + n * 128 + k] : (f16)0.f;
    } break;
    case 3: if (e < 2 * 16384) {
        int mtx = e >> 14, f = e & 16383;
        int nt = f >> 11, ks = (f >> 9) & 3, l = (f >> 3) & 63, j = f & 7;
        int n = nt * 16 + (l & 15), k = ks * 32 + ((l >> 4) & 3) * 8 + j;
        mW2f[e] = ((n % 15) >= (k % 15)) ? (f16)made_bW2[mtx * 16384 + n * 128 + k] : (f16)0.f;
    } break;
    case 4: if (e < 4 * 24576) {
        int s = e / 24576, f = e % 24576;
        int nt = f >> 11, ks = (f >> 9) & 3, l = (f >> 3) & 63, j = f & 7;
        int n = nt * 16 + (l & 15), k = ks * 32 + ((l >> 4) & 3) * 8 + j;
        fWoutf[e] = (n < 184) ? (f16)sp_Wout[s * 23552 + n * 128 + k] : (f16)0.f;
    } break;
    case 5: if (e < 4096) {
        int f = e;
        int nt = f >> 11, ks = (f >> 9) & 3, l = (f >> 3) & 63, j = f & 7;
        int n = nt * 16 + (l & 15), k = ks * 32 + ((l >> 4) & 3) * 8 + j;
        mWoutf[e] = (((n & 15) > (k % 15)) && n < 32) ? (f16)made_Wout[n * 128 + k] : (f16)0.f;
    } break;
    case 6: if (e < 4096) {
        int f = e;
        int nt = f >> 9, l = (f >> 3) & 63, j = f & 7;
        int n = nt * 16 + (l & 15), k = ((l >> 4) & 3) * 8 + j;
        minf[e] = (k < 16 && (n % 15) >= k) ? (f16)made_W0[n * 16 + k] : (f16)0.f;
    } break;
    case 7: if (e < 5 * 49152) {
        int s = e / 49152, f = e % 49152;
        int nt = f >> 11, ks = (f >> 9) & 3, l = (f >> 3) & 63, j = f & 7;
        int n = nt * 16 + (l & 15), k = ks * 32 + ((l >> 4) & 3) * 8 + j;
        float v;
        if (s < 4) {
            if (n < 128)      v = sp_Win[s * 17408 + n * 136 + 8 + k];
            else if (n < 256) v = sp_bCW[(size_t)(s * 2 + 0) * 16384 + (n - 128) * 128 + k];
            else              v = sp_bCW[(size_t)(s * 2 + 1) * 16384 + (n - 256) * 128 + k];
        } else {
            if (n < 128)      v = made_ctxW[n * 128 + k];
            else if (n < 256) v = made_bCW[(n - 128) * 128 + k];
            else              v = made_bCW[16384 + (n - 256) * 128 + k];
        }
        cfrag[e] = (f16)v;
    } break;
    case 8: if (e < 5 * 384) {
        int s = e / 384, n = e % 384;
        float v;
        if (s < 4) {
            if (n < 128)      v = sp_bin[s * 128 + n];
            else if (n < 256) v = sp_bCb[(s * 2 + 0) * 128 + (n - 128)];
            else              v = sp_bCb[(s * 2 + 1) * 128 + (n - 256)];
        } else {
            if (n < 128)      v = made_ctxb[n] + made_b0[n];
            else if (n < 256) v = made_bCb[n - 128];
            else              v = made_bCb[128 + (n - 256)];
        }
        cpb[e] = v;
    } break;
    case 9: if (e < 16384) {
        int f = e;
        int nt = f >> 11, ks = (f >> 9) & 3, l = (f >> 3) & 63, j = f & 7;
        int n = nt * 16 + (l & 15), k = ks * 32 + ((l >> 4) & 3) * 8 + j;
        encW1f[e] = (f16)enc_W1[n * 128 + k];
    } break;
    case 10: if (e < 4096) {
        int f = e;
        int nt = f >> 11, ks = (f >> 9) & 3, l = (f >> 3) & 63, j = f & 7;
        int n = nt * 16 + (l & 15), k = ks * 32 + ((l >> 4) & 3) * 8 + j;
        encW2f[e] = (n < 32) ? (f16)enc_W2[n * 128 + k] : (f16)0.f;
    } break;
    case 11: if (e < 160) {
        epb[e] = (e < 128) ? enc_b1[e] : enc_b2[e - 128];
    } break;
    }
}

// ---------------- ctx-chain MFMA (s<5) + fused encoder (s==5), ctx computed inline ----------------
__global__ __launch_bounds__(256) void ctx_mfma(
    const f16* __restrict__ cfrag,
    const float* __restrict__ cpb,
    const f16* __restrict__ encW1f, const f16* __restrict__ encW2f,
    const float* __restrict__ epb,
    f16* __restrict__ ctxoutf, float* __restrict__ ehw)
{
    __shared__ alignas(16) f16 cS[16][136];
    __shared__ alignas(16) f16 hS[16][136];
    const int tid = threadIdx.x, w = tid >> 6, l = tid & 63;
    const int m0 = blockIdx.x * 16;
    const int s  = blockIdx.y;
    const int lr = l & 15, lq = l >> 4;
    // inline positional encoding (no global ctx buffer)
    #pragma unroll
    for (int it = 0; it < 2; ++it) {
        int e = tid + it * 256;
        int r = e >> 5, c4 = (e & 31) * 4;
        int hw = m0 + r;
        int ii = hw / 96, jj = hw % 96;
        #pragma unroll
        for (int q = 0; q < 4; ++q) {
            int c = c4 + q;
            int pos = (c < 64) ? ii : jj;
            int cc = c & 63;
            int k = cc >> 1;
            float invf = exp2f((float)k * -0.4152410118609203f);  // 10000^(-k/32)
            float v = (float)pos * invf;
            cS[r][c] = (f16)((cc & 1) ? cosf(v) : sinf(v));
        }
    }
    __syncthreads();
    const f32x4 vzero = {0.f, 0.f, 0.f, 0.f};
    if (s == 5) {
        f32x4 acc0 = vzero, acc1 = vzero;
        #pragma unroll
        for (int ks = 0; ks < 4; ++ks) {
            f16x8 a = *(const f16x8*)&cS[lr][ks * 32 + lq * 8];
            f16x8 b0 = *(const f16x8*)(encW1f + (((w * 2 + 0) * 4 + ks) * 64 + l) * 8);
            f16x8 b1 = *(const f16x8*)(encW1f + (((w * 2 + 1) * 4 + ks) * 64 + l) * 8);
            acc0 = __builtin_amdgcn_mfma_f32_16x16x32_f16(a, b0, acc0, 0, 0, 0);
            acc1 = __builtin_amdgcn_mfma_f32_16x16x32_f16(a, b1, acc1, 0, 0, 0);
        }
        {
            int n0 = (w * 2 + 0) * 16 + lr, n1 = (w * 2 + 1) * 16 + lr;
            float bi0 = epb[n0], bi1 = epb[n1];
            #pragma unroll
            for (int r = 0; r < 4; ++r) {
                float v0 = acc0[r] + bi0, v1 = acc1[r] + bi1;
                hS[lq * 4 + r][n0] = (f16)(v0 / (1.f + expf(-v0)));
                hS[lq * 4 + r][n1] = (f16)(v1 / (1.f + expf(-v1)));
            }
        }
        __syncthreads();
        if (w < 2) {
            f32x4 po = vzero;
            #pragma unroll
            for (int ks = 0; ks < 4; ++ks) {
                f16x8 a = *(const f16x8*)&hS[lr][ks * 32 + lq * 8];
                f16x8 b = *(const f16x8*)(encW2f + ((w * 4 + ks) * 64 + l) * 8);
                po = __builtin_amdgcn_mfma_f32_16x16x32_f16(a, b, po, 0, 0, 0);
            }
            int n = w * 16 + lr;
            float bias = epb[128 + n];
            #pragma unroll
            for (int r = 0; r < 4; ++r)
                ehw[(size_t)(m0 + lq * 4 + r) * 32 + n] = po[r] + bias;
        }
        return;
    }
    f32x4 acc[6];
    #pragma unroll
    for (int q = 0; q < 6; ++q) acc[q] = vzero;
    const f16* wb = cfrag + (size_t)s * 49152;
    #pragma unroll
    for (int ks = 0; ks < 4; ++ks) {
        f16x8 a = *(const f16x8*)&cS[lr][ks * 32 + lq * 8];
        #pragma unroll
        for (int q = 0; q < 6; ++q) {
            int g = w * 6 + q;
            f16x8 b = *(const f16x8*)(wb + (size_t)((g * 4 + ks) * 64 + l) * 8);
            acc[q] = __builtin_amdgcn_mfma_f32_16x16x32_f16(a, b, acc[q], 0, 0, 0);
        }
    }
    #pragma unroll
    for (int q = 0; q < 6; ++q) {
        int g = w * 6 + q, n = g * 16 + lr;
        float bias = cpb[s * 384 + n];
        #pragma unroll
        for (int r = 0; r < 4; ++r) {
            float val = acc[q][r] + bias;
            if (n >= 128) val = 1.f / (1.f + expf(-val));
            ctxoutf[(size_t)s * NHW * 384 + (size_t)(m0 + lq * 4 + r) * 384 + n] = (f16)val;
        }
    }
}

// ---------------- rational-quadratic spline ----------------
__device__ __forceinline__ void rqs_core(float x, const float* cw, const float* wd,
                                         const float* ch, const float* hg, const float* dd,
                                         float& y, float& ld) {
    bool inside = (x >= -3.f) && (x <= 3.f);
    float xc = fminf(fmaxf(x, -3.f), 3.f);
    float cwk = cw[0], wk = wd[0], chk = ch[0], hk = hg[0], d0 = dd[0], d1 = dd[1];
    #pragma unroll
    for (int k = 1; k < 8; ++k) {
        if (xc >= cw[k]) { cwk = cw[k]; wk = wd[k]; chk = ch[k]; hk = hg[k]; d0 = dd[k]; d1 = dd[k + 1]; }
    }
    float dl = hk / wk;
    float th = (xc - cwk) / wk;
    float t1 = th * (1.f - th);
    float den = dl + (d0 + d1 - 2.f * dl) * t1;
    float yy = chk + hk * (dl * th * th + d0 * t1) / den;
    float om = 1.f - th;
    float dnum = dl * dl * (d1 * th * th + 2.f * dl * t1 + d0 * om * om);
    float lld = logf(dnum) - 2.f * logf(den);
    y  = inside ? yy : x;
    ld = inside ? lld : 0.f;
}

__device__ __forceinline__ void rqs1(float x,
                                     const float* __restrict__ uw,
                                     const float* __restrict__ uh,
                                     const float* __restrict__ ud,
                                     float& y, float& ld) {
    float cw[9], wd[8], ch[9], hg[8], dd[9];
    knots8(uw, cw, wd);
    knots8(uh, ch, hg);
    dd[0] = 1.f; dd[8] = 1.f;
    #pragma unroll
    for (int k = 0; k < 7; ++k) dd[k + 1] = 0.001f + softplusf(ud[k]);
    rqs_core(x, cw, wd, ch, hg, dd, y, ld);
}

__device__ __forceinline__ void rqs1_pre(float x, const float* __restrict__ kn,
                                         float& y, float& ld) {
    float cw[9], wd[8], ch[9], hg[8], dd[9];
    #pragma unroll
    for (int k = 0; k < 9; ++k) cw[k] = kn[k];
    #pragma unroll
    for (int k = 0; k < 8; ++k) wd[k] = kn[9 + k];
    #pragma unroll
    for (int k = 0; k < 9; ++k) ch[k] = kn[17 + k];
    #pragma unroll
    for (int k = 0; k < 8; ++k) hg[k] = kn[26 + k];
    #pragma unroll
    for (int k = 0; k < 9; ++k) dd[k] = kn[34 + k];
    rqs_core(x, cw, wd, ch, hg, dd, y, ld);
}

// ---------------- prefetch helpers ----------------
__device__ __forceinline__ void load8(const f16* __restrict__ w, int nt0, int l,
                                      f16x8 B[8]) {
    #pragma unroll
    for (int q = 0; q < 2; ++q)
        #pragma unroll
        for (int ks = 0; ks < 4; ++ks)
            B[q * 4 + ks] = *(const f16x8*)(w + (nt0 + q) * 2048 + ks * 512 + l * 8);
}

__device__ __forceinline__ void gemm8(const f16 (*__restrict__ S)[136], int lr, int lqw,
                                      const f16x8 B[8], f32x4& a0, f32x4& a1) {
    #pragma unroll
    for (int ks = 0; ks < 4; ++ks) {
        f16x8 a = *(const f16x8*)&S[lr][ks * 32 + lqw * 8];
        a0 = __builtin_amdgcn_mfma_f32_16x16x32_f16(a, B[ks], a0, 0, 0, 0);
        a1 = __builtin_amdgcn_mfma_f32_16x16x32_f16(a, B[4 + ks], a1, 0, 0, 0);
    }
}

// ---------------- merged pipeline: lgkm barriers + prefetch + register logq ----------------
__global__ __launch_bounds__(256) void mega_all(
    const float* __restrict__ zg,
    const f16*  __restrict__ ctxoutf,   // [5][9216][384]
    const f16*  __restrict__ weffF,     // [4][4096]
    const f16*  __restrict__ mlutF,     // [4][512]
    const float* __restrict__ beffv,    // [4][128]
    const f16*  __restrict__ minf,      // [4096]
    const f16*  __restrict__ fW1f,      // [4][2][16384]
    const f16*  __restrict__ fW2f,
    const f16*  __restrict__ mW1f,      // [2][16384]
    const f16*  __restrict__ mW2f,
    const f16*  __restrict__ fWoutf,    // [4][24576]
    const f16*  __restrict__ mWoutf,    // [4096]
    const float* __restrict__ sp_bb1,   // [4][2][128]
    const float* __restrict__ sp_bb2,
    const float* __restrict__ made_bb1, // [2][128]
    const float* __restrict__ made_bb2,
    const float* __restrict__ sp_bout,  // [4][184]
    const float* __restrict__ made_bout,// [32]
    const float* __restrict__ lu_bias,  // [4][16]
    const float* __restrict__ idk,      // [4][8][48]
    const float* __restrict__ luc,      // [1]
    const float* __restrict__ ehw,      // [9216][32]
    float* __restrict__ out)            // [4][9216]
{
    __shared__ alignas(16) f16 tS[16][136];
    __shared__ alignas(16) f16 uS[16][136];
    __shared__ alignas(16) f16 zS[16][32];
    __shared__ alignas(16) f16 pS[16][196];
    __shared__ float zlu[16][17];
    __shared__ float zO[16][17];
    __shared__ float ldS[16][17];   // per-(task,row) logq partials, reduced in Gaussian head
    const int tid = threadIdx.x;
    const int w   = tid >> 6;
    const int l   = tid & 63;
    const int lr  = l & 15;
    const int lqw = l >> 4;
    const int m0  = blockIdx.x * 16;
    const int hwq = (m0 >> 2) + lqw;
    const int nt0 = w * 2;
    const int r2  = tid >> 4, d2 = tid & 15;
    const f32x4 vzero = {0.f, 0.f, 0.f, 0.f};

    zS[r2][d2] = (f16)zg[(size_t)(m0 + r2) * 16 + d2];
    zS[r2][16 + d2] = (f16)0.f;
    float luc0 = luc[0];
    float ldAcc = 0.f;

    f16x8 B[8];
    f16x8 bml;
    B[0] = *(const f16x8*)(weffF + 3 * 4096 + ((nt0 + 0) * 64 + l) * 8);
    B[1] = *(const f16x8*)(weffF + 3 * 4096 + ((nt0 + 1) * 64 + l) * 8);
    bml  = *(const f16x8*)(mlutF + 3 * 512 + l * 8);
    barrier_lgkm();

    const int n0q = (w + 0) * 16 + lr, n1q = (w + 4) * 16 + lr, n2q = (w + 8) * 16 + lr;

    for (int i = 3; i >= 0; --i) {
        const f16* cb = ctxoutf + (size_t)i * NHW * 384 + (size_t)hwq * 384;
        float tReg[2][4];
        float g10 = (float)cb[128 + (nt0 + 0) * 16 + lr];
        float g11 = (float)cb[128 + (nt0 + 1) * 16 + lr];
        float g20 = (float)cb[256 + (nt0 + 0) * 16 + lr];
        float g21 = (float)cb[256 + (nt0 + 1) * 16 + lr];
        const float* bb1p = sp_bb1 + i * 256;
        const float* bb2p = sp_bb2 + i * 256;
        float bi10 = bb1p[(nt0 + 0) * 16 + lr], bi11 = bb1p[(nt0 + 1) * 16 + lr];
        float bi20 = bb2p[(nt0 + 0) * 16 + lr], bi21 = bb2p[(nt0 + 1) * 16 + lr];
        float bi30 = bb1p[128 + (nt0 + 0) * 16 + lr], bi31 = bb1p[128 + (nt0 + 1) * 16 + lr];
        float bi40 = bb2p[128 + (nt0 + 0) * 16 + lr], bi41 = bb2p[128 + (nt0 + 1) * 16 + lr];
        const float* bo = sp_bout + i * 184;
        float b0v = bo[n0q], b1v = bo[n1q];
        float b2v = (n2q < 184) ? bo[n2q] : 0.f;
        // ---- IN ----
        {
            f16x8 a = *(const f16x8*)&zS[lr][lqw * 8];
            if (w == 0) {
                float bl = lu_bias[i * 16 + lr];
                f32x4 c = {bl, bl, bl, bl};
                c = __builtin_amdgcn_mfma_f32_16x16x32_f16(a, bml, c, 0, 0, 0);
                #pragma unroll
                for (int r = 0; r < 4; ++r)
                    zlu[lqw * 4 + r][lr] = c[r];
            }
            #pragma unroll
            for (int t = 0; t < 2; ++t) {
                int n = (nt0 + t) * 16 + lr;
                float ci = (float)cb[n] + beffv[i * 128 + n];
                f32x4 c = {ci, ci, ci, ci};
                c = __builtin_amdgcn_mfma_f32_16x16x32_f16(a, B[t], c, 0, 0, 0);
                #pragma unroll
                for (int r = 0; r < 4; ++r) {
                    tReg[t][r] = c[r];
                    tS[lqw * 4 + r][(nt0 + t) * 16 + lr] = (f16)fmaxf(c[r], 0.f);
                }
            }
            load8(fW1f + (size_t)i * 32768, nt0, l, B);
        }
        barrier_lgkm();
        // ---- W1 blk0 ----
        {
            f32x4 a0 = vzero, a1 = vzero;
            gemm8(tS, lr, lqw, B, a0, a1);
            load8(fW2f + (size_t)i * 32768, nt0, l, B);
            #pragma unroll
            for (int r = 0; r < 4; ++r) {
                uS[lqw * 4 + r][(nt0 + 0) * 16 + lr] = (f16)fmaxf(a0[r] + bi10, 0.f);
                uS[lqw * 4 + r][(nt0 + 1) * 16 + lr] = (f16)fmaxf(a1[r] + bi11, 0.f);
            }
        }
        barrier_lgkm();
        // ---- W2 blk0 ----
        {
            f32x4 a0 = vzero, a1 = vzero;
            gemm8(uS, lr, lqw, B, a0, a1);
            load8(fW1f + (size_t)i * 32768 + 16384, nt0, l, B);
            #pragma unroll
            for (int r = 0; r < 4; ++r) {
                tReg[0][r] += (a0[r] + bi20) * g10;
                tReg[1][r] += (a1[r] + bi21) * g11;
                tS[lqw * 4 + r][(nt0 + 0) * 16 + lr] = (f16)fmaxf(tReg[0][r], 0.f);
                tS[lqw * 4 + r][(nt0 + 1) * 16 + lr] = (f16)fmaxf(tReg[1][r], 0.f);
            }
        }
        barrier_lgkm();
        // ---- W1 blk1 ----
        {
            f32x4 a0 = vzero, a1 = vzero;
            gemm8(tS, lr, lqw, B, a0, a1);
            load8(fW2f + (size_t)i * 32768 + 16384, nt0, l, B);
            #pragma unroll
            for (int r = 0; r < 4; ++r) {
                uS[lqw * 4 + r][(nt0 + 0) * 16 + lr] = (f16)fmaxf(a0[r] + bi30, 0.f);
                uS[lqw * 4 + r][(nt0 + 1) * 16 + lr] = (f16)fmaxf(a1[r] + bi31, 0.f);
            }
        }
        barrier_lgkm();
        // ---- W2 blk1 ----
        {
            f32x4 a0 = vzero, a1 = vzero;
            gemm8(uS, lr, lqw, B, a0, a1);
            {
                const f16* wo = fWoutf + (size_t)i * 24576;
                #pragma unroll
                for (int t2 = 0; t2 < 2; ++t2)
                    #pragma unroll
                    for (int ks = 0; ks < 4; ++ks)
                        B[t2 * 4 + ks] = *(const f16x8*)(wo + (w + t2 * 4) * 2048 + ks * 512 + l * 8);
            }
            #pragma unroll
            for (int r = 0; r < 4; ++r) {
                tReg[0][r] += (a0[r] + bi40) * g20;
                tReg[1][r] += (a1[r] + bi41) * g21;
                tS[lqw * 4 + r][(nt0 + 0) * 16 + lr] = (f16)tReg[0][r];
                tS[lqw * 4 + r][(nt0 + 1) * 16 + lr] = (f16)tReg[1][r];
            }
        }
        barrier_lgkm();
        // ---- WOUT -> pS ----
        {
            f32x4 po0 = vzero, po1 = vzero, po2 = vzero;
            const f16* wo = fWoutf + (size_t)i * 24576;
            #pragma unroll
            for (int ks = 0; ks < 4; ++ks) {
                f16x8 a = *(const f16x8*)&tS[lr][ks * 32 + lqw * 8];
                po0 = __builtin_amdgcn_mfma_f32_16x16x32_f16(a, B[ks], po0, 0, 0, 0);
                po1 = __builtin_amdgcn_mfma_f32_16x16x32_f16(a, B[4 + ks], po1, 0, 0, 0);
                f16x8 b2 = *(const f16x8*)(wo + (w + 8) * 2048 + ks * 512 + l * 8);
                po2 = __builtin_amdgcn_mfma_f32_16x16x32_f16(a, b2, po2, 0, 0, 0);
            }
            if (i > 0) {
                B[0] = *(const f16x8*)(weffF + (i - 1) * 4096 + ((nt0 + 0) * 64 + l) * 8);
                B[1] = *(const f16x8*)(weffF + (i - 1) * 4096 + ((nt0 + 1) * 64 + l) * 8);
                bml  = *(const f16x8*)(mlutF + (i - 1) * 512 + l * 8);
            } else {
                B[0] = *(const f16x8*)(minf + ((nt0 + 0) * 64 + l) * 8);
                B[1] = *(const f16x8*)(minf + ((nt0 + 1) * 64 + l) * 8);
            }
            #pragma unroll
            for (int r = 0; r < 4; ++r) {
                pS[lqw * 4 + r][n0q] = (f16)(po0[r] + b0v);
                pS[lqw * 4 + r][n1q] = (f16)(po1[r] + b1v);
                if (n2q < 184) pS[lqw * 4 + r][n2q] = (f16)(po2[r] + b2v);
            }
        }
        barrier_lgkm();
        // ---- SPLINE (logq partial kept in register ldAcc) ----
        {
            const int task = tid >> 4, rw = tid & 15;
            float y, ldv;
            if (task < 8) {
                const int dim = task;
                const float is = 0.08838834764831845f;
                float uw[8], uh[8], udv[7];
                const f16* pr = &pS[rw][dim * 23];
                #pragma unroll
                for (int k = 0; k < 8; ++k) { uw[k] = (float)pr[k] * is; uh[k] = (float)pr[8 + k] * is; }
                #pragma unroll
                for (int k = 0; k < 7; ++k) udv[k] = (float)pr[16 + k];
                float x = zlu[rw][2 * dim + 1];
                rqs1(x, uw, uh, udv, y, ldv);
                zO[rw][2 * dim + 1] = y;
                zS[rw][2 * dim + 1] = (f16)y;
            } else {
                const int dim = task - 8;
                float x = zlu[rw][2 * dim];
                rqs1_pre(x, idk + i * 384 + dim * 48, y, ldv);
                zO[rw][2 * dim] = y;
                zS[rw][2 * dim] = (f16)y;
            }
            ldAcc += ldv;
        }
        barrier_lgkm();
    }

    // publish logq partials (consumed after the next barrier, in the Gaussian head)
    ldS[tid >> 4][tid & 15] = ldAcc;

    // ---- MADE stage ----
    {
        const f16* cb = ctxoutf + (size_t)4 * NHW * 384 + (size_t)hwq * 384;
        float tReg[2][4];
        float g10 = (float)cb[128 + (nt0 + 0) * 16 + lr];
        float g11 = (float)cb[128 + (nt0 + 1) * 16 + lr];
        float g20 = (float)cb[256 + (nt0 + 0) * 16 + lr];
        float g21 = (float)cb[256 + (nt0 + 1) * 16 + lr];
        float bi10 = made_bb1[(nt0 + 0) * 16 + lr], bi11 = made_bb1[(nt0 + 1) * 16 + lr];
        float bi20 = made_bb2[(nt0 + 0) * 16 + lr], bi21 = made_bb2[(nt0 + 1) * 16 + lr];
        float bi30 = made_bb1[128 + (nt0 + 0) * 16 + lr], bi31 = made_bb1[128 + (nt0 + 1) * 16 + lr];
        float bi40 = made_bb2[128 + (nt0 + 0) * 16 + lr], bi41 = made_bb2[128 + (nt0 + 1) * 16 + lr];
        {
            f16x8 a = *(const f16x8*)&zS[lr][lqw * 8];
            #pragma unroll
            for (int t = 0; t < 2; ++t) {
                float thw = (float)cb[(nt0 + t) * 16 + lr];
                f32x4 c = {thw, thw, thw, thw};
                c = __builtin_amdgcn_mfma_f32_16x16x32_f16(a, B[t], c, 0, 0, 0);
                #pragma unroll
                for (int r = 0; r < 4; ++r) {
                    tReg[t][r] = c[r];
                    tS[lqw * 4 + r][(nt0 + t) * 16 + lr] = (f16)fmaxf(c[r], 0.f);
                }
            }
            load8(mW1f, nt0, l, B);
        }
        barrier_lgkm();
        {
            f32x4 a0 = vzero, a1 = vzero;
            gemm8(tS, lr, lqw, B, a0, a1);
            load8(mW2f, nt0, l, B);
            #pragma unroll
            for (int r = 0; r < 4; ++r) {
                uS[lqw * 4 + r][(nt0 + 0) * 16 + lr] = (f16)fmaxf(a0[r] + bi10, 0.f);
                uS[lqw * 4 + r][(nt0 + 1) * 16 + lr] = (f16)fmaxf(a1[r] + bi11, 0.f);
            }
        }
        barrier_lgkm();
        {
            f32x4 a0 = vzero, a1 = vzero;
            gemm8(uS, lr, lqw, B, a0, a1);
            load8(mW1f + 16384, nt0, l, B);
            #pragma unroll
            for (int r = 0; r < 4; ++r) {
                tReg[0][r] += (a0[r] + bi20) * g10;
                tReg[1][r] += (a1[r] + bi21) * g11;
                tS[lqw * 4 + r][(nt0 + 0) * 16 + lr] = (f16)fmaxf(tReg[0][r], 0.f);
                tS[lqw * 4 + r][(nt0 + 1) * 16 + lr] = (f16)fmaxf(tReg[1][r], 0.f);
            }
        }
        barrier_lgkm();
        {
            f32x4 a0 = vzero, a1 = vzero;
            gemm8(tS, lr, lqw, B, a0, a1);
            load8(mW2f + 16384, nt0, l, B);
            #pragma unroll
            for (int r = 0; r < 4; ++r) {
                uS[lqw * 4 + r][(nt0 + 0) * 16 + lr] = (f16)fmaxf(a0[r] + bi30, 0.f);
                uS[lqw * 4 + r][(nt0 + 1) * 16 + lr] = (f16)fmaxf(a1[r] + bi31, 0.f);
            }
        }
        barrier_lgkm();
        {
            f32x4 a0 = vzero, a1 = vzero;
            gemm8(uS, lr, lqw, B, a0, a1);
            #pragma unroll
            for (int r = 0; r < 4; ++r) {
                tReg[0][r] += (a0[r] + bi40) * g20;
                tReg[1][r] += (a1[r] + bi41) * g21;
                tS[lqw * 4 + r][(nt0 + 0) * 16 + lr] = (f16)tReg[0][r];
                tS[lqw * 4 + r][(nt0 + 1) * 16 + lr] = (f16)tReg[1][r];
            }
        }
        barrier_lgkm();
        if (w < 2) {
            f32x4 po = vzero;
            #pragma unroll
            for (int ks = 0; ks < 4; ++ks) {
                f16x8 a = *(const f16x8*)&tS[lr][ks * 32 + lqw * 8];
                f16x8 b = *(const f16x8*)(mWoutf + w * 2048 + ks * 512 + l * 8);
                po = __builtin_amdgcn_mfma_f32_16x16x32_f16(a, b, po, 0, 0, 0);
            }
            int n = w * 16 + lr;
            float bias = made_bout[n];
            #pragma unroll
            for (int r = 0; r < 4; ++r)
                pS[lqw * 4 + r][n] = (f16)(po[r] + bias);
        }
    }
    barrier_lgkm();
    // ---- Gaussian head (folds logq reduction: each d-lane adds ldS[d][rw]) ----
    {
        const int rw = tid >> 4, d = tid & 15;
        const int gm = m0 + rw, hw = gm >> 2, b = gm & 3;
        float ar0 = (float)pS[rw][2 * d];
        float ar1 = (float)pS[rw][2 * d + 1];
        float s = softplusf(ar0) + 0.001f;
        float zn = s * zO[rw][d] + ar1;
        float ls   = ehw[(size_t)hw * 32 + 16 + d];
        float mean = ehw[(size_t)hw * 32 + d];
        float diff = (zn - mean) * expf(-ls);
        float g = logf(s) - ls - 0.5f * diff * diff + ldS[d][rw];
        g += __shfl_xor(g, 1);
        g += __shfl_xor(g, 2);
        g += __shfl_xor(g, 4);
        g += __shfl_xor(g, 8);
        if (d == 0)
            out[(size_t)b * NHW + hw] = g + luc0 - 14.703016531274762f;
    }
}

extern "C" void kernel_launch(void* const* d_in, const int* in_sizes, int n_in,
                              void* d_out, int out_size, void* d_ws, size_t ws_size,
                              hipStream_t stream) {
    (void)in_sizes; (void)n_in; (void)out_size; (void)ws_size;
    const float* x         = (const float*)d_in[0];
    const float* made_W0   = (const float*)d_in[1];
    const float* made_b0   = (const float*)d_in[2];
    const float* made_ctxW = (const float*)d_in[3];
    const float* made_ctxb = (const float*)d_in[4];
    const float* made_bW1  = (const float*)d_in[5];
    const float* made_bb1  = (const float*)d_in[6];
    const float* made_bW2  = (const float*)d_in[7];
    const float* made_bb2  = (const float*)d_in[8];
    const float* made_bCW  = (const float*)d_in[9];
    const float* made_bCb  = (const float*)d_in[10];
    const float* made_Wout = (const float*)d_in[11];
    const float* made_bout = (const float*)d_in[12];
    const float* sp_Win    = (const float*)d_in[13];
    const float* sp_bin    = (const float*)d_in[14];
    const float* sp_bW1    = (const float*)d_in[15];
    const float* sp_bb1    = (const float*)d_in[16];
    const float* sp_bW2    = (const float*)d_in[17];
    const float* sp_bb2    = (const float*)d_in[18];
    const float* sp_bCW    = (const float*)d_in[19];
    const float* sp_bCb    = (const float*)d_in[20];
    const float* sp_Wout   = (const float*)d_in[21];
    const float* sp_bout   = (const float*)d_in[22];
    const float* sp_uw     = (const float*)d_in[23];
    const float* sp_uh     = (const float*)d_in[24];
    const float* sp_ud     = (const float*)d_in[25];
    const float* lu_lower  = (const float*)d_in[26];
    const float* lu_upper  = (const float*)d_in[27];
    const float* lu_udiag  = (const float*)d_in[28];
    const float* lu_bias   = (const float*)d_in[29];
    const int*   lu_perm   = (const int*)d_in[30];
    const float* enc_W1    = (const float*)d_in[31];
    const float* enc_b1    = (const float*)d_in[32];
    const float* enc_W2    = (const float*)d_in[33];
    const float* enc_b2    = (const float*)d_in[34];
    float* out = (float*)d_out;

    float* ws      = (float*)d_ws;
    float* z       = ws;                               // 36864*16
    float* ehw     = z       + (size_t)NROWS * 16;     // 9216*32
    float* cpb     = ehw     + (size_t)NHW * 32;       // 5*384
    float* epb     = cpb     + 5 * 384;                // 160 (pad 192)
    float* idk     = epb     + 192;                    // 4*8*48
    float* beff    = idk     + 1536;                   // 4*128
    float* luc     = beff    + 512;                    // 1 (pad 16)
    f16*   ctxoutf = (f16*)(luc + 16);                 // 5*9216*384 f16
    f16*   fW1f    = ctxoutf + (size_t)5 * NHW * 384;  // 8*16384
    f16*   fW2f    = fW1f    + 8 * 16384;              // 8*16384
    f16*   mW1f    = fW2f    + 8 * 16384;              // 2*16384
    f16*   mW2f    = mW1f    + 2 * 16384;              // 2*16384
    f16*   fWoutf  = mW2f    + 2 * 16384;              // 4*24576
    f16*   mWoutf  = fWoutf  + 4 * 24576;              // 4096
    f16*   weffF   = mWoutf  + 4096;                   // 4*4096
    f16*   mlutF   = weffF   + 4 * 4096;               // 4*512
    f16*   minf    = mlutF   + 4 * 512;                // 4096
    f16*   encW1f  = minf    + 4096;                   // 16384
    f16*   encW2f  = encW1f  + 16384;                  // 4096
    f16*   cfrag   = encW2f  + 4096;                   // 5*49152

    dim3 B(256);
    pack_kernel<<<dim3(960, 12), B, 0, stream>>>(
        sp_bW1, sp_bW2, made_bW1, made_bW2, sp_Wout, made_Wout, sp_Win, made_W0,
        sp_bCW, made_ctxW, made_bCW, sp_bin, sp_bCb, made_ctxb, made_b0, made_bCb,
        enc_W1, enc_b1, enc_W2, enc_b2,
        fW1f, fW2f, mW1f, mW2f, fWoutf, mWoutf, minf, cfrag, cpb,
        encW1f, encW2f, epb);
    snorm_kernel<<<2304, B, 0, stream>>>(x, z);
    prep_kernel<<<1, 256, 0, stream>>>(sp_uw, sp_uh, sp_ud, sp_Win, lu_lower, lu_upper,
                                       lu_udiag, lu_bias, lu_perm, idk, weffF, mlutF,
                                       beff, luc);

    // ctx-dependent precomputes (positional encoding inline; encoder as slice 5)
    ctx_mfma<<<dim3(576, 6), B, 0, stream>>>(cfrag, cpb, encW1f, encW2f, epb,
                                             ctxoutf, ehw);

    // merged pipeline
    mega_all<<<2304, B, 0, stream>>>(z, ctxoutf, weffF, mlutF, beff, minf,
                                     fW1f, fW2f, mW1f, mW2f, fWoutf, mWoutf,
                                     sp_bb1, sp_bb2, made_bb1, made_bb2,
                                     sp_bout, made_bout,
                                     lu_bias, idk, luc, ehw, out);
}